// Round 10
// baseline (441.587 us; speedup 1.0000x reference)
//
#include <hip/hip_runtime.h>
#include <hip/hip_bf16.h>

#define NN   10000
#define NP   10048          // 157*64 padded rows
#define HID  256
#define BN_EPS 1e-5f
#define NPH  ((size_t)NP * 256)

typedef __bf16 bf16x4 __attribute__((ext_vector_type(4)));
typedef __bf16 bf16x8 __attribute__((ext_vector_type(8)));
typedef float  f32x4  __attribute__((ext_vector_type(4)));

__device__ __forceinline__ void gl_lds16(const void* gptr, void* lptr) {
    __builtin_amdgcn_global_load_lds(
        (const __attribute__((address_space(1))) void*)gptr,
        (__attribute__((address_space(3))) void*)lptr,
        16, 0, 0);
}

// ------------------------------------------------------------------
// Merged: cnt-zero + tile-counter-zero + i64-layout detect (blocks 0..39)
// and weight hi/lo splits (blocks 40..3019).
__global__ void prep_split(const int* __restrict__ e, unsigned* __restrict__ cnt,
                           unsigned* __restrict__ flag, unsigned* __restrict__ tcnt,
                           const float* __restrict__ in_W, const float* __restrict__ gcn_W,
                           const float* __restrict__ c1_W, const float* __restrict__ c2_W,
                           const float* __restrict__ c3_W,
                           __bf16* __restrict__ wih, __bf16* __restrict__ wil,
                           __bf16* __restrict__ gwh, __bf16* __restrict__ gwl,
                           __bf16* __restrict__ c1h, __bf16* __restrict__ c1l,
                           __bf16* __restrict__ c2h, __bf16* __restrict__ c2l,
                           __bf16* __restrict__ c3h, __bf16* __restrict__ c3l) {
    if (blockIdx.x < 40) {
        int i = blockIdx.x * 256 + threadIdx.x;
        if (i < NN) cnt[i] = 0u;
        if (blockIdx.x == 0) {
            if (threadIdx.x < 157) tcnt[threadIdx.x] = 0u;
            __shared__ int nz;
            if (threadIdx.x == 0) nz = 0;
            __syncthreads();
            if (e[2 * threadIdx.x + 1] != 0) nz = 1;
            __syncthreads();
            if (threadIdx.x == 0) *flag = (nz == 0) ? 1u : 0u;  // 1 => int64 layout
        }
        return;
    }
    int idx = (blockIdx.x - 40) * 256 + threadIdx.x;
    float v; __bf16 *dh, *dl; int o;
    if (idx < 524288)      { v = in_W[idx];          dh = wih; dl = wil; o = idx; }
    else if (idx < 720896) { o = idx - 524288; v = gcn_W[o]; dh = gwh; dl = gwl; }
    else if (idx < 753664) { o = idx - 720896; v = c1_W[o];  dh = c1h; dl = c1l; }
    else if (idx < 761856) { o = idx - 753664; v = c2_W[o];  dh = c2h; dl = c2l; }
    else                   { o = idx - 761856; int r = o >> 6, c = o & 63;
                             v = (r < 10) ? c3_W[r * 64 + c] : 0.0f; dh = c3h; dl = c3l; }
    __bf16 h = (__bf16)v;
    dh[o] = h;
    dl[o] = (__bf16)(v - (float)h);
}

__device__ __forceinline__ int edge_val(const int* e, unsigned f, long idx) {
    return f ? e[2 * idx] : e[idx];
}

__global__ void count_edges(const int* __restrict__ e, const unsigned* __restrict__ flag,
                            unsigned* __restrict__ cnt, int E) {
    int i = blockIdx.x * blockDim.x + threadIdx.x;
    if (i >= E) return;
    unsigned f = *flag;
    atomicAdd(&cnt[edge_val(e, f, (long)E + i)], 1u);
}

__global__ void scan_dinv(const unsigned* __restrict__ cnt, unsigned* __restrict__ off,
                          unsigned* __restrict__ cur, float* __restrict__ dinv, int n) {
    __shared__ unsigned partial[256];
    int t = threadIdx.x;
    int chunk = (n + 255) / 256;
    int lo = t * chunk;
    int hi = lo + chunk; if (hi > n) hi = n; if (lo > n) lo = n;
    unsigned s = 0;
    for (int i = lo; i < hi; ++i) s += cnt[i];
    partial[t] = s;
    __syncthreads();
    for (int d = 1; d < 256; d <<= 1) {
        unsigned v = (t >= d) ? partial[t - d] : 0u;
        __syncthreads();
        partial[t] += v;
        __syncthreads();
    }
    unsigned base = (t == 0) ? 0u : partial[t - 1];
    for (int i = lo; i < hi; ++i) {
        off[i] = base; cur[i] = base;
        dinv[i] = rsqrtf((float)cnt[i] + 1.0f);
        base += cnt[i];
    }
    if (t == 255) off[n] = base;
}

__global__ void fill_csr(const int* __restrict__ e, const unsigned* __restrict__ flag,
                         unsigned* __restrict__ cur, int* __restrict__ csr_src, int E) {
    int i = blockIdx.x * blockDim.x + threadIdx.x;
    if (i >= E) return;
    unsigned f = *flag;
    int src = edge_val(e, f, (long)i);
    int dst = edge_val(e, f, (long)E + i);
    unsigned pos = atomicAdd(&cur[dst], 1u);
    csr_src[pos] = src;
}

// ------------------------------------------------------------------
// Input projection (measured-best structure, ~80 us) with FUSED epilogue:
// BM=64 x BN=256, split-K=4, 2-phase pipelined, double-buffered LDS.
// All z-blocks store their partial slice; the last-arriving block per M-tile
// (device-scope atomic counter) reduces the 4 slices + bias + relu and emits
// the bf16 hi/lo planes. No spin-waits -> dispatch-order independent.
#define IPZ 4
#define IPKC 512
__global__ __launch_bounds__(256) void inproj_gemm(
    const float* __restrict__ A,
    const __bf16* __restrict__ Bh, const __bf16* __restrict__ Bl,
    float* __restrict__ P, unsigned* __restrict__ tcnt,
    const float* __restrict__ bias,
    __bf16* __restrict__ hhi, __bf16* __restrict__ hlo)
{
    __shared__ __align__(16) __bf16 sAh[2][2048], sAl[2][2048];
    __shared__ __align__(16) __bf16 sBh[2][8192], sBl[2][8192];

    const int tid = threadIdx.x, wid = tid >> 6, lane = tid & 63;
    const int fr = lane & 15, fq = lane >> 4;
    const int bm = blockIdx.x * 64;
    const int kbase = blockIdx.z * IPKC;
    const int wn = wid * 64;

    f32x4 acc[4][4] = {};

    const int rs = tid >> 2, cq = tid & 3;
    const int gr = min(bm + rs, NN - 1);
    const float* aptr = A + (size_t)gr * 2048 + cq * 8;
    const int scA = rs * 32 + ((cq ^ ((rs >> 1) & 3)) << 3);
    const int brow_l = lane >> 2, bch = lane & 3;

    float av[8];
    int cur = 0;

    {   // prologue: stage tile 0
        float4 v0 = *(const float4*)(aptr + kbase);
        float4 v1 = *(const float4*)(aptr + kbase + 4);
        av[0]=v0.x; av[1]=v0.y; av[2]=v0.z; av[3]=v0.w;
        av[4]=v1.x; av[5]=v1.y; av[6]=v1.z; av[7]=v1.w;
#pragma unroll
        for (int j = 0; j < 4; ++j) {
            int slice = wid * 4 + j;
            int row = slice * 16 + brow_l;
            int lc = bch ^ ((row >> 1) & 3);
            size_t goff = (size_t)row * 2048 + kbase + lc * 8;
            gl_lds16(Bh + goff, &sBh[0][slice * 512]);
            gl_lds16(Bl + goff, &sBl[0][slice * 512]);
        }
        bf16x8 hv, lv;
#pragma unroll
        for (int j = 0; j < 8; ++j) {
            __bf16 h = (__bf16)av[j];
            hv[j] = h; lv[j] = (__bf16)(av[j] - (float)h);
        }
        *(bf16x8*)&sAh[0][scA] = hv;
        *(bf16x8*)&sAl[0][scA] = lv;
    }
    __syncthreads();

    for (int kt = 0; kt < IPKC / 32; ++kt) {
        const bool more = (kt + 1) < IPKC / 32;
        const int nk = kbase + (kt + 1) * 32;
        if (more) {
            float4 v0 = *(const float4*)(aptr + nk);
            float4 v1 = *(const float4*)(aptr + nk + 4);
            av[0]=v0.x; av[1]=v0.y; av[2]=v0.z; av[3]=v0.w;
            av[4]=v1.x; av[5]=v1.y; av[6]=v1.z; av[7]=v1.w;
#pragma unroll
            for (int j = 0; j < 4; ++j) {
                int slice = wid * 4 + j;
                int row = slice * 16 + brow_l;
                int lc = bch ^ ((row >> 1) & 3);
                size_t goff = (size_t)row * 2048 + nk + lc * 8;
                gl_lds16(Bh + goff, &sBh[cur ^ 1][slice * 512]);
                gl_lds16(Bl + goff, &sBl[cur ^ 1][slice * 512]);
            }
        }
        bf16x8 bh[4], bl[4];
#pragma unroll
        for (int ni = 0; ni < 4; ++ni) {
            int r = wn + ni * 16 + fr;
            int e = r * 32 + ((fq ^ ((r >> 1) & 3)) << 3);
            bh[ni] = *(const bf16x8*)&sBh[cur][e];
            bl[ni] = *(const bf16x8*)&sBl[cur][e];
        }
#pragma unroll
        for (int mi = 0; mi < 4; ++mi) {
            int r = mi * 16 + fr;
            int e = r * 32 + ((fq ^ ((r >> 1) & 3)) << 3);
            bf16x8 ah = *(const bf16x8*)&sAh[cur][e];
            bf16x8 al = *(const bf16x8*)&sAl[cur][e];
#pragma unroll
            for (int ni = 0; ni < 4; ++ni) {
                acc[mi][ni] = __builtin_amdgcn_mfma_f32_16x16x32_bf16(ah, bh[ni], acc[mi][ni], 0, 0, 0);
                acc[mi][ni] = __builtin_amdgcn_mfma_f32_16x16x32_bf16(ah, bl[ni], acc[mi][ni], 0, 0, 0);
                acc[mi][ni] = __builtin_amdgcn_mfma_f32_16x16x32_bf16(al, bh[ni], acc[mi][ni], 0, 0, 0);
            }
        }
        if (more) {
            bf16x8 hv, lv;
#pragma unroll
            for (int j = 0; j < 8; ++j) {
                __bf16 h = (__bf16)av[j];
                hv[j] = h; lv[j] = (__bf16)(av[j] - (float)h);
            }
            *(bf16x8*)&sAh[cur ^ 1][scA] = hv;
            *(bf16x8*)&sAl[cur ^ 1][scA] = lv;
        }
        __syncthreads();
        cur ^= 1;
    }

    // ---- store this z-slice's partial ----
    float* Pz = P + (size_t)blockIdx.z * NPH;
#pragma unroll
    for (int mi = 0; mi < 4; ++mi) {
        int row0 = bm + mi * 16 + fq * 4;
#pragma unroll
        for (int ni = 0; ni < 4; ++ni) {
            int col = wn + ni * 16 + fr;
#pragma unroll
            for (int r = 0; r < 4; ++r)
                Pz[(size_t)(row0 + r) * 256 + col] = acc[mi][ni][r];
        }
    }

    // ---- fused epilogue: last-arriving z-block per tile reduces ----
    __threadfence();
    __shared__ unsigned arrival;
    if (tid == 0) arrival = atomicAdd(&tcnt[blockIdx.x], 1u);
    __syncthreads();
    if (arrival == IPZ - 1) {
        __threadfence();
#pragma unroll
        for (int it = 0; it < 16; ++it) {
            int e4 = (it * 256 + tid) * 4;          // 0..16383 within tile
            int row = e4 >> 8, col = e4 & 255;
            size_t gidx = (size_t)(bm + row) * 256 + col;
            float v[4] = {0, 0, 0, 0};
            if (bm + row < NN) {
                const float* p = P + gidx;
                float4 a0 = *(const float4*)(p);
                float4 a1 = *(const float4*)(p + NPH);
                float4 a2 = *(const float4*)(p + 2 * NPH);
                float4 a3 = *(const float4*)(p + 3 * NPH);
                v[0] = fmaxf(a0.x + a1.x + a2.x + a3.x + bias[col + 0], 0.0f);
                v[1] = fmaxf(a0.y + a1.y + a2.y + a3.y + bias[col + 1], 0.0f);
                v[2] = fmaxf(a0.z + a1.z + a2.z + a3.z + bias[col + 2], 0.0f);
                v[3] = fmaxf(a0.w + a1.w + a2.w + a3.w + bias[col + 3], 0.0f);
            }
            bf16x4 hv, lv;
#pragma unroll
            for (int j = 0; j < 4; ++j) {
                __bf16 h = (__bf16)v[j];
                hv[j] = h; lv[j] = (__bf16)(v[j] - (float)h);
            }
            *(bf16x4*)&hhi[gidx] = hv;
            *(bf16x4*)&hlo[gidx] = lv;
        }
    }
}

// ------------------------------------------------------------------
// Layer GEMM (K=256): no LDS, per-lane direct fragment loads.
// Epilogue pre-scales each output row by dinv[row]  ->  hws = (h @ W^T) * dinv
__global__ __launch_bounds__(256) void gemm_layer(
    const __bf16* __restrict__ Ah, const __bf16* __restrict__ Al,
    const __bf16* __restrict__ Bh, const __bf16* __restrict__ Bl,
    const float* __restrict__ dinv, float* __restrict__ Cf)
{
    const int tid = threadIdx.x, wid = tid >> 6, lane = tid & 63;
    const int fr = lane & 15, fq = lane >> 4;
    const int wr = wid >> 1, wc = wid & 1;
    const int bm = blockIdx.x * 64, bn = blockIdx.y * 64;

    f32x4 acc[2][2] = {};
    size_t ra[2], rb[2];
#pragma unroll
    for (int mi = 0; mi < 2; ++mi) ra[mi] = (size_t)(bm + wr * 32 + mi * 16 + fr) * 256 + fq * 8;
#pragma unroll
    for (int ni = 0; ni < 2; ++ni) rb[ni] = (size_t)(bn + wc * 32 + ni * 16 + fr) * 256 + fq * 8;

#pragma unroll
    for (int kt = 0; kt < 8; ++kt) {
        bf16x8 ah[2], al[2], bh[2], bl[2];
#pragma unroll
        for (int mi = 0; mi < 2; ++mi) {
            ah[mi] = *(const bf16x8*)(Ah + ra[mi] + kt * 32);
            al[mi] = *(const bf16x8*)(Al + ra[mi] + kt * 32);
        }
#pragma unroll
        for (int ni = 0; ni < 2; ++ni) {
            bh[ni] = *(const bf16x8*)(Bh + rb[ni] + kt * 32);
            bl[ni] = *(const bf16x8*)(Bl + rb[ni] + kt * 32);
        }
#pragma unroll
        for (int mi = 0; mi < 2; ++mi)
#pragma unroll
            for (int ni = 0; ni < 2; ++ni) {
                acc[mi][ni] = __builtin_amdgcn_mfma_f32_16x16x32_bf16(ah[mi], bh[ni], acc[mi][ni], 0, 0, 0);
                acc[mi][ni] = __builtin_amdgcn_mfma_f32_16x16x32_bf16(ah[mi], bl[ni], acc[mi][ni], 0, 0, 0);
                acc[mi][ni] = __builtin_amdgcn_mfma_f32_16x16x32_bf16(al[mi], bh[ni], acc[mi][ni], 0, 0, 0);
            }
    }

    float dv[2][4];
#pragma unroll
    for (int mi = 0; mi < 2; ++mi)
#pragma unroll
        for (int r = 0; r < 4; ++r) {
            int row = bm + wr * 32 + mi * 16 + fq * 4 + r;
            dv[mi][r] = (row < NN) ? dinv[row] : 0.0f;
        }

#pragma unroll
    for (int mi = 0; mi < 2; ++mi)
#pragma unroll
        for (int ni = 0; ni < 2; ++ni) {
            int col = bn + wc * 32 + ni * 16 + fr;
#pragma unroll
            for (int r = 0; r < 4; ++r) {
                int row = bm + wr * 32 + mi * 16 + fq * 4 + r;
                if (row < NN) Cf[(size_t)row * 256 + col] = acc[mi][ni][r] * dv[mi][r];
            }
        }
}

// ------------------------------------------------------------------
// XCD-pinned, feature-chunked GCN aggregate (v4: 8-way ILP).
// 4 chunks of 64 features; per-chunk gather set = 2.56 MB < 4 MB per-XCD L2;
// chunk = xcd>>1. 16 lanes/node, f32x4/lane. 8 independent accumulators keep
// 8 gathers in flight per lane (latency-bound fix).
__global__ __launch_bounds__(256) void gcn_aggregate(
    const float* __restrict__ hws, const float* __restrict__ res,
    const float* __restrict__ dinv, const unsigned* __restrict__ off,
    const int* __restrict__ csr,
    const float* __restrict__ bias, const float* __restrict__ gamma,
    const float* __restrict__ beta, const float* __restrict__ mean,
    const float* __restrict__ var,
    float* __restrict__ hf, __bf16* __restrict__ hhi, __bf16* __restrict__ hlo)
{
    const int xcd = blockIdx.x & 7;
    const int chunk = xcd >> 1;                       // 0..3
    const int nb = (blockIdx.x >> 3) * 2 + (xcd & 1); // node-block 0..625
    if (nb >= 625) return;                            // 625*16 = 10000 exactly

    const int tid = threadIdx.x;
    const int g = tid >> 4;                           // node-in-block 0..15
    const int q = tid & 15;                           // feature lane 0..15
    const int node = nb * 16 + g;
    const int f = chunk * 64 + q * 4;
    const size_t rowb = (size_t)node * HID + f;

    const float dn = dinv[node];
    const unsigned j0 = off[node], j1 = off[node + 1];

    f32x4 a0 = *(const f32x4*)(hws + rowb);           // self term (pre-scaled)
    f32x4 a1 = {0.f,0.f,0.f,0.f}, a2 = {0.f,0.f,0.f,0.f}, a3 = {0.f,0.f,0.f,0.f};
    f32x4 a4 = {0.f,0.f,0.f,0.f}, a5 = {0.f,0.f,0.f,0.f};
    f32x4 a6 = {0.f,0.f,0.f,0.f}, a7 = {0.f,0.f,0.f,0.f};

    unsigned j = j0;
    for (; j + 8 <= j1; j += 8) {
        int s0 = csr[j + 0];
        int s1 = csr[j + 1];
        int s2 = csr[j + 2];
        int s3 = csr[j + 3];
        int s4 = csr[j + 4];
        int s5 = csr[j + 5];
        int s6 = csr[j + 6];
        int s7 = csr[j + 7];
        a0 += *(const f32x4*)(hws + (size_t)s0 * HID + f);
        a1 += *(const f32x4*)(hws + (size_t)s1 * HID + f);
        a2 += *(const f32x4*)(hws + (size_t)s2 * HID + f);
        a3 += *(const f32x4*)(hws + (size_t)s3 * HID + f);
        a4 += *(const f32x4*)(hws + (size_t)s4 * HID + f);
        a5 += *(const f32x4*)(hws + (size_t)s5 * HID + f);
        a6 += *(const f32x4*)(hws + (size_t)s6 * HID + f);
        a7 += *(const f32x4*)(hws + (size_t)s7 * HID + f);
    }
    for (; j + 4 <= j1; j += 4) {
        int s0 = csr[j + 0];
        int s1 = csr[j + 1];
        int s2 = csr[j + 2];
        int s3 = csr[j + 3];
        a1 += *(const f32x4*)(hws + (size_t)s0 * HID + f);
        a2 += *(const f32x4*)(hws + (size_t)s1 * HID + f);
        a3 += *(const f32x4*)(hws + (size_t)s2 * HID + f);
        a4 += *(const f32x4*)(hws + (size_t)s3 * HID + f);
    }
    for (; j < j1; ++j) {
        int s = csr[j];
        a5 += *(const f32x4*)(hws + (size_t)s * HID + f);
    }
    f32x4 acc = ((a0 + a1) + (a2 + a3)) + ((a4 + a5) + (a6 + a7));

    f32x4 b4  = *(const f32x4*)(bias + f);
    f32x4 m4  = *(const f32x4*)(mean + f);
    f32x4 v4  = *(const f32x4*)(var + f);
    f32x4 g4  = *(const f32x4*)(gamma + f);
    f32x4 be4 = *(const f32x4*)(beta + f);
    f32x4 r4 = {0.0f, 0.0f, 0.0f, 0.0f};
    if (res) r4 = *(const f32x4*)(res + rowb);

    f32x4 o;
    bf16x4 hv, lv;
#pragma unroll
    for (int jj = 0; jj < 4; ++jj) {
        float t = dn * acc[jj] + b4[jj];
        t = (t - m4[jj]) * rsqrtf(v4[jj] + BN_EPS) * g4[jj] + be4[jj];
        t = fmaxf(t, 0.0f);
        t += r4[jj];
        o[jj] = t;
        __bf16 h = (__bf16)t;
        hv[jj] = h; lv[jj] = (__bf16)(t - (float)h);
    }
    if (hf) *(f32x4*)(hf + rowb) = o;
    *(bf16x4*)&hhi[rowb] = hv;
    *(bf16x4*)&hlo[rowb] = lv;
}

// ------------------------------------------------------------------
// Fused classifier: 32-row tile, h -> O1(LDS) -> O2(LDS) -> logits.
__global__ __launch_bounds__(256) void classifier(
    const __bf16* __restrict__ Ah, const __bf16* __restrict__ Al,
    const __bf16* __restrict__ c1h, const __bf16* __restrict__ c1l, const float* __restrict__ b1,
    const __bf16* __restrict__ c2h, const __bf16* __restrict__ c2l, const float* __restrict__ b2,
    const __bf16* __restrict__ c3h, const __bf16* __restrict__ c3l, const float* __restrict__ b3,
    float* __restrict__ out)
{
    __shared__ __align__(16) float sO1[32][132];
    __shared__ __align__(16) float sO2[32][68];

    const int tid = threadIdx.x, wid = tid >> 6, lane = tid & 63;
    const int fr = lane & 15, fq = lane >> 4;
    const int bm = blockIdx.x * 32;

    // ---- stage 1: O1 = relu(h @ c1^T + b1)   M=32 N=128 K=256
    {
        f32x4 acc[2][2] = {};
        size_t ra[2], rb[2];
#pragma unroll
        for (int mi = 0; mi < 2; ++mi) ra[mi] = (size_t)(bm + mi * 16 + fr) * 256 + fq * 8;
#pragma unroll
        for (int ni = 0; ni < 2; ++ni) rb[ni] = (size_t)(wid * 32 + ni * 16 + fr) * 256 + fq * 8;
#pragma unroll
        for (int kt = 0; kt < 8; ++kt) {
            bf16x8 ah[2], al[2], bh[2], bl[2];
#pragma unroll
            for (int mi = 0; mi < 2; ++mi) {
                ah[mi] = *(const bf16x8*)(Ah + ra[mi] + kt * 32);
                al[mi] = *(const bf16x8*)(Al + ra[mi] + kt * 32);
            }
#pragma unroll
            for (int ni = 0; ni < 2; ++ni) {
                bh[ni] = *(const bf16x8*)(c1h + rb[ni] + kt * 32);
                bl[ni] = *(const bf16x8*)(c1l + rb[ni] + kt * 32);
            }
#pragma unroll
            for (int mi = 0; mi < 2; ++mi)
#pragma unroll
                for (int ni = 0; ni < 2; ++ni) {
                    acc[mi][ni] = __builtin_amdgcn_mfma_f32_16x16x32_bf16(ah[mi], bh[ni], acc[mi][ni], 0, 0, 0);
                    acc[mi][ni] = __builtin_amdgcn_mfma_f32_16x16x32_bf16(ah[mi], bl[ni], acc[mi][ni], 0, 0, 0);
                    acc[mi][ni] = __builtin_amdgcn_mfma_f32_16x16x32_bf16(al[mi], bh[ni], acc[mi][ni], 0, 0, 0);
                }
        }
#pragma unroll
        for (int mi = 0; mi < 2; ++mi)
#pragma unroll
            for (int ni = 0; ni < 2; ++ni) {
                int col = wid * 32 + ni * 16 + fr;
                float bb = b1[col];
#pragma unroll
                for (int r = 0; r < 4; ++r)
                    sO1[mi * 16 + fq * 4 + r][col] = fmaxf(acc[mi][ni][r] + bb, 0.0f);
            }
    }
    __syncthreads();

    // ---- stage 2: O2 = relu(O1 @ c2^T + b2)   M=32 N=64 K=128
    {
        f32x4 acc[2] = {};
#pragma unroll
        for (int kt = 0; kt < 4; ++kt) {
            bf16x8 ah[2], al[2];
#pragma unroll
            for (int mi = 0; mi < 2; ++mi) {
                const float* p = &sO1[mi * 16 + fr][kt * 32 + fq * 8];
                f32x4 v0 = *(const f32x4*)p;
                f32x4 v1 = *(const f32x4*)(p + 4);
                float vv[8] = {v0[0], v0[1], v0[2], v0[3], v1[0], v1[1], v1[2], v1[3]};
#pragma unroll
                for (int j = 0; j < 8; ++j) {
                    __bf16 h = (__bf16)vv[j];
                    ah[mi][j] = h; al[mi][j] = (__bf16)(vv[j] - (float)h);
                }
            }
            size_t rb = (size_t)(wid * 16 + fr) * 128 + kt * 32 + fq * 8;
            bf16x8 bh = *(const bf16x8*)(c2h + rb);
            bf16x8 bl = *(const bf16x8*)(c2l + rb);
#pragma unroll
            for (int mi = 0; mi < 2; ++mi) {
                acc[mi] = __builtin_amdgcn_mfma_f32_16x16x32_bf16(ah[mi], bh, acc[mi], 0, 0, 0);
                acc[mi] = __builtin_amdgcn_mfma_f32_16x16x32_bf16(ah[mi], bl, acc[mi], 0, 0, 0);
                acc[mi] = __builtin_amdgcn_mfma_f32_16x16x32_bf16(al[mi], bh, acc[mi], 0, 0, 0);
            }
        }
        int col = wid * 16 + fr;
        float bb = b2[col];
#pragma unroll
        for (int mi = 0; mi < 2; ++mi)
#pragma unroll
            for (int r = 0; r < 4; ++r)
                sO2[mi * 16 + fq * 4 + r][col] = fmaxf(acc[mi][r] + bb, 0.0f);
    }
    __syncthreads();

    // ---- stage 3: logits = O2 @ c3^T + b3
    if (wid < 2) {
        f32x4 acc = {};
#pragma unroll
        for (int kt = 0; kt < 2; ++kt) {
            const float* p = &sO2[wid * 16 + fr][kt * 32 + fq * 8];
            f32x4 v0 = *(const f32x4*)p;
            f32x4 v1 = *(const f32x4*)(p + 4);
            float vv[8] = {v0[0], v0[1], v0[2], v0[3], v1[0], v1[1], v1[2], v1[3]};
            bf16x8 ah, al;
#pragma unroll
            for (int j = 0; j < 8; ++j) {
                __bf16 h = (__bf16)vv[j];
                ah[j] = h; al[j] = (__bf16)(vv[j] - (float)h);
            }
            size_t rb = (size_t)fr * 64 + kt * 32 + fq * 8;
            bf16x8 bh = *(const bf16x8*)(c3h + rb);
            bf16x8 bl = *(const bf16x8*)(c3l + rb);
            acc = __builtin_amdgcn_mfma_f32_16x16x32_bf16(ah, bh, acc, 0, 0, 0);
            acc = __builtin_amdgcn_mfma_f32_16x16x32_bf16(ah, bl, acc, 0, 0, 0);
            acc = __builtin_amdgcn_mfma_f32_16x16x32_bf16(al, bh, acc, 0, 0, 0);
        }
        if (fr < 10) {
            float bb = b3[fr];
#pragma unroll
            for (int r = 0; r < 4; ++r) {
                int row = bm + wid * 16 + fq * 4 + r;
                if (row < NN) out[(size_t)row * 10 + fr] = acc[r] + bb;
            }
        }
    }
}

// ------------------------------------------------------------------
extern "C" void kernel_launch(void* const* d_in, const int* in_sizes, int n_in,
                              void* d_out, int out_size, void* d_ws, size_t ws_size,
                              hipStream_t stream)
{
    const float* x     = (const float*)d_in[0];
    const int*   eidx  = (const int*)d_in[1];
    const float* in_W  = (const float*)d_in[2];
    const float* in_b  = (const float*)d_in[3];
    const float* gcn_W = (const float*)d_in[4];
    const float* gcn_b = (const float*)d_in[5];
    const float* bn_g  = (const float*)d_in[6];
    const float* bn_be = (const float*)d_in[7];
    const float* bn_m  = (const float*)d_in[8];
    const float* bn_v  = (const float*)d_in[9];
    const float* c1_W  = (const float*)d_in[10];
    const float* c1_b  = (const float*)d_in[11];
    const float* c2_W  = (const float*)d_in[12];
    const float* c2_b  = (const float*)d_in[13];
    const float* c3_W  = (const float*)d_in[14];
    const float* c3_b  = (const float*)d_in[15];
    float* out = (float*)d_out;

    const int E = in_sizes[1] / 2;
    float* ws = (float*)d_ws;

    // ---- workspace layout ----
    float*  P   = ws;                 // 4 slices of NPH f32 (reused as h1,h2,hws)
    float*  h1  = P;
    float*  h2  = P + NPH;
    float*  hws = P + 2 * NPH;
    __bf16* hhi = (__bf16*)(P + 4 * NPH);
    __bf16* hlo = hhi + NPH;
    __bf16* wih = hlo + NPH;          // 256x2048
    __bf16* wil = wih + 524288;
    __bf16* gwh = wil + 524288;       // 768x256
    __bf16* gwl = gwh + 196608;
    __bf16* c1h = gwl + 196608;       // 128x256
    __bf16* c1l = c1h + 32768;
    __bf16* c2h = c1l + 32768;        // 64x128
    __bf16* c2l = c2h + 8192;
    __bf16* c3h = c2l + 8192;         // 16x64 (10 real rows)
    __bf16* c3l = c3h + 1024;
    float*    dinv = (float*)(c3l + 1024);
    unsigned* cnt  = (unsigned*)(dinv + NN);
    unsigned* off  = cnt + NN;
    unsigned* cur  = off + NN + 1;
    unsigned* flag = cur + NN;
    unsigned* tcnt = flag + 4;        // 157 tile counters
    int*      csr  = (int*)(tcnt + 160);

    // ---- graph prep + weight splits (merged first launch) ----
    prep_split<<<3020, 256, 0, stream>>>(eidx, cnt, flag, tcnt,
                                         in_W, gcn_W, c1_W, c2_W, c3_W,
                                         wih, wil, gwh, gwl, c1h, c1l, c2h, c2l, c3h, c3l);
    count_edges<<<(E + 255) / 256, 256, 0, stream>>>(eidx, flag, cnt, E);
    scan_dinv<<<1, 256, 0, stream>>>(cnt, off, cur, dinv, NN);
    fill_csr<<<(E + 255) / 256, 256, 0, stream>>>(eidx, flag, cur, csr, E);

    // ---- input projection (epilogue fused via last-block reduce) ----
    inproj_gemm<<<dim3(NP / 64, 1, IPZ), 256, 0, stream>>>(x, wih, wil, P, tcnt,
                                                           in_b, hhi, hlo);

    // ---- 3 GCN layers ----
    for (int i = 0; i < 3; ++i) {
        gemm_layer<<<dim3(NP / 64, 4), 256, 0, stream>>>(
            hhi, hlo, gwh + (size_t)i * 65536, gwl + (size_t)i * 65536, dinv, hws);
        const float* res = (i == 0) ? nullptr : (i == 1 ? h1 : h2);
        float* hf = (i == 0) ? h1 : (i == 1 ? h2 : nullptr);
        gcn_aggregate<<<2504, 256, 0, stream>>>(
            hws, res, dinv, off, csr,
            gcn_b + i * HID, bn_g + i * HID, bn_be + i * HID,
            bn_m + i * HID, bn_v + i * HID, hf, hhi, hlo);
    }

    // ---- fused classifier ----
    classifier<<<NP / 32, 256, 0, stream>>>(hhi, hlo, c1h, c1l, c1_b,
                                            c2h, c2l, c2_b, c3h, c3l, c3_b, out);
}

// Round 11
// 325.701 us; speedup vs baseline: 1.3558x; 1.3558x over previous
//
#include <hip/hip_runtime.h>
#include <hip/hip_bf16.h>

#define NN   10000
#define NP   10048          // 157*64 padded rows
#define HID  256
#define BN_EPS 1e-5f
#define NPH  ((size_t)NP * 256)

typedef __bf16 bf16x4 __attribute__((ext_vector_type(4)));
typedef __bf16 bf16x8 __attribute__((ext_vector_type(8)));
typedef float  f32x4  __attribute__((ext_vector_type(4)));

__device__ __forceinline__ void gl_lds16(const void* gptr, void* lptr) {
    __builtin_amdgcn_global_load_lds(
        (const __attribute__((address_space(1))) void*)gptr,
        (__attribute__((address_space(3))) void*)lptr,
        16, 0, 0);
}

// ------------------------------------------------------------------
// Merged: cnt-zero + i64-layout detect (blocks 0..39) and weight hi/lo
// splits (blocks 40..3019).
__global__ void prep_split(const int* __restrict__ e, unsigned* __restrict__ cnt,
                           unsigned* __restrict__ flag,
                           const float* __restrict__ in_W, const float* __restrict__ gcn_W,
                           const float* __restrict__ c1_W, const float* __restrict__ c2_W,
                           const float* __restrict__ c3_W,
                           __bf16* __restrict__ wih, __bf16* __restrict__ wil,
                           __bf16* __restrict__ gwh, __bf16* __restrict__ gwl,
                           __bf16* __restrict__ c1h, __bf16* __restrict__ c1l,
                           __bf16* __restrict__ c2h, __bf16* __restrict__ c2l,
                           __bf16* __restrict__ c3h, __bf16* __restrict__ c3l) {
    if (blockIdx.x < 40) {
        int i = blockIdx.x * 256 + threadIdx.x;
        if (i < NN) cnt[i] = 0u;
        if (blockIdx.x == 0) {
            __shared__ int nz;
            if (threadIdx.x == 0) nz = 0;
            __syncthreads();
            if (e[2 * threadIdx.x + 1] != 0) nz = 1;
            __syncthreads();
            if (threadIdx.x == 0) *flag = (nz == 0) ? 1u : 0u;  // 1 => int64 layout
        }
        return;
    }
    int idx = (blockIdx.x - 40) * 256 + threadIdx.x;
    float v; __bf16 *dh, *dl; int o;
    if (idx < 524288)      { v = in_W[idx];          dh = wih; dl = wil; o = idx; }
    else if (idx < 720896) { o = idx - 524288; v = gcn_W[o]; dh = gwh; dl = gwl; }
    else if (idx < 753664) { o = idx - 720896; v = c1_W[o];  dh = c1h; dl = c1l; }
    else if (idx < 761856) { o = idx - 753664; v = c2_W[o];  dh = c2h; dl = c2l; }
    else                   { o = idx - 761856; int r = o >> 6, c = o & 63;
                             v = (r < 10) ? c3_W[r * 64 + c] : 0.0f; dh = c3h; dl = c3l; }
    __bf16 h = (__bf16)v;
    dh[o] = h;
    dl[o] = (__bf16)(v - (float)h);
}

__device__ __forceinline__ int edge_val(const int* e, unsigned f, long idx) {
    return f ? e[2 * idx] : e[idx];
}

__global__ void count_edges(const int* __restrict__ e, const unsigned* __restrict__ flag,
                            unsigned* __restrict__ cnt, int E) {
    int i = blockIdx.x * blockDim.x + threadIdx.x;
    if (i >= E) return;
    unsigned f = *flag;
    atomicAdd(&cnt[edge_val(e, f, (long)E + i)], 1u);
}

__global__ void scan_dinv(const unsigned* __restrict__ cnt, unsigned* __restrict__ off,
                          unsigned* __restrict__ cur, float* __restrict__ dinv, int n) {
    __shared__ unsigned partial[256];
    int t = threadIdx.x;
    int chunk = (n + 255) / 256;
    int lo = t * chunk;
    int hi = lo + chunk; if (hi > n) hi = n; if (lo > n) lo = n;
    unsigned s = 0;
    for (int i = lo; i < hi; ++i) s += cnt[i];
    partial[t] = s;
    __syncthreads();
    for (int d = 1; d < 256; d <<= 1) {
        unsigned v = (t >= d) ? partial[t - d] : 0u;
        __syncthreads();
        partial[t] += v;
        __syncthreads();
    }
    unsigned base = (t == 0) ? 0u : partial[t - 1];
    for (int i = lo; i < hi; ++i) {
        off[i] = base; cur[i] = base;
        dinv[i] = rsqrtf((float)cnt[i] + 1.0f);
        base += cnt[i];
    }
    if (t == 255) off[n] = base;
}

__global__ void fill_csr(const int* __restrict__ e, const unsigned* __restrict__ flag,
                         unsigned* __restrict__ cur, int* __restrict__ csr_src, int E) {
    int i = blockIdx.x * blockDim.x + threadIdx.x;
    if (i >= E) return;
    unsigned f = *flag;
    int src = edge_val(e, f, (long)i);
    int dst = edge_val(e, f, (long)E + i);
    unsigned pos = atomicAdd(&cur[dst], 1u);
    csr_src[pos] = src;
}

// ------------------------------------------------------------------
// Input projection (measured-best variant, ~80 us): BM=64 x BN=256,
// split-K=4, 2-phase pipelined, double-buffered LDS; B hi+lo via
// global_load_lds; A fp32 loads issued early / converted late.
#define IPZ 4
#define IPKC 512
__global__ __launch_bounds__(256) void inproj_gemm(
    const float* __restrict__ A,
    const __bf16* __restrict__ Bh, const __bf16* __restrict__ Bl,
    float* __restrict__ P)
{
    __shared__ __align__(16) __bf16 sAh[2][2048], sAl[2][2048];
    __shared__ __align__(16) __bf16 sBh[2][8192], sBl[2][8192];

    const int tid = threadIdx.x, wid = tid >> 6, lane = tid & 63;
    const int fr = lane & 15, fq = lane >> 4;
    const int bm = blockIdx.x * 64;
    const int kbase = blockIdx.z * IPKC;
    const int wn = wid * 64;

    f32x4 acc[4][4] = {};

    const int rs = tid >> 2, cq = tid & 3;
    const int gr = min(bm + rs, NN - 1);
    const float* aptr = A + (size_t)gr * 2048 + cq * 8;
    const int scA = rs * 32 + ((cq ^ ((rs >> 1) & 3)) << 3);
    const int brow_l = lane >> 2, bch = lane & 3;

    float av[8];
    int cur = 0;

    {   // prologue: stage tile 0
        float4 v0 = *(const float4*)(aptr + kbase);
        float4 v1 = *(const float4*)(aptr + kbase + 4);
        av[0]=v0.x; av[1]=v0.y; av[2]=v0.z; av[3]=v0.w;
        av[4]=v1.x; av[5]=v1.y; av[6]=v1.z; av[7]=v1.w;
#pragma unroll
        for (int j = 0; j < 4; ++j) {
            int slice = wid * 4 + j;
            int row = slice * 16 + brow_l;
            int lc = bch ^ ((row >> 1) & 3);
            size_t goff = (size_t)row * 2048 + kbase + lc * 8;
            gl_lds16(Bh + goff, &sBh[0][slice * 512]);
            gl_lds16(Bl + goff, &sBl[0][slice * 512]);
        }
        bf16x8 hv, lv;
#pragma unroll
        for (int j = 0; j < 8; ++j) {
            __bf16 h = (__bf16)av[j];
            hv[j] = h; lv[j] = (__bf16)(av[j] - (float)h);
        }
        *(bf16x8*)&sAh[0][scA] = hv;
        *(bf16x8*)&sAl[0][scA] = lv;
    }
    __syncthreads();

    for (int kt = 0; kt < IPKC / 32; ++kt) {
        const bool more = (kt + 1) < IPKC / 32;
        const int nk = kbase + (kt + 1) * 32;
        if (more) {
            float4 v0 = *(const float4*)(aptr + nk);
            float4 v1 = *(const float4*)(aptr + nk + 4);
            av[0]=v0.x; av[1]=v0.y; av[2]=v0.z; av[3]=v0.w;
            av[4]=v1.x; av[5]=v1.y; av[6]=v1.z; av[7]=v1.w;
#pragma unroll
            for (int j = 0; j < 4; ++j) {
                int slice = wid * 4 + j;
                int row = slice * 16 + brow_l;
                int lc = bch ^ ((row >> 1) & 3);
                size_t goff = (size_t)row * 2048 + nk + lc * 8;
                gl_lds16(Bh + goff, &sBh[cur ^ 1][slice * 512]);
                gl_lds16(Bl + goff, &sBl[cur ^ 1][slice * 512]);
            }
        }
        bf16x8 bh[4], bl[4];
#pragma unroll
        for (int ni = 0; ni < 4; ++ni) {
            int r = wn + ni * 16 + fr;
            int e = r * 32 + ((fq ^ ((r >> 1) & 3)) << 3);
            bh[ni] = *(const bf16x8*)&sBh[cur][e];
            bl[ni] = *(const bf16x8*)&sBl[cur][e];
        }
#pragma unroll
        for (int mi = 0; mi < 4; ++mi) {
            int r = mi * 16 + fr;
            int e = r * 32 + ((fq ^ ((r >> 1) & 3)) << 3);
            bf16x8 ah = *(const bf16x8*)&sAh[cur][e];
            bf16x8 al = *(const bf16x8*)&sAl[cur][e];
#pragma unroll
            for (int ni = 0; ni < 4; ++ni) {
                acc[mi][ni] = __builtin_amdgcn_mfma_f32_16x16x32_bf16(ah, bh[ni], acc[mi][ni], 0, 0, 0);
                acc[mi][ni] = __builtin_amdgcn_mfma_f32_16x16x32_bf16(ah, bl[ni], acc[mi][ni], 0, 0, 0);
                acc[mi][ni] = __builtin_amdgcn_mfma_f32_16x16x32_bf16(al, bh[ni], acc[mi][ni], 0, 0, 0);
            }
        }
        if (more) {
            bf16x8 hv, lv;
#pragma unroll
            for (int j = 0; j < 8; ++j) {
                __bf16 h = (__bf16)av[j];
                hv[j] = h; lv[j] = (__bf16)(av[j] - (float)h);
            }
            *(bf16x8*)&sAh[cur ^ 1][scA] = hv;
            *(bf16x8*)&sAl[cur ^ 1][scA] = lv;
        }
        __syncthreads();
        cur ^= 1;
    }

    float* Pz = P + (size_t)blockIdx.z * NPH;
#pragma unroll
    for (int mi = 0; mi < 4; ++mi) {
        int row0 = bm + mi * 16 + fq * 4;
#pragma unroll
        for (int ni = 0; ni < 4; ++ni) {
            int col = wn + ni * 16 + fr;
#pragma unroll
            for (int r = 0; r < 4; ++r)
                Pz[(size_t)(row0 + r) * 256 + col] = acc[mi][ni][r];
        }
    }
}

// reduce 4 partials + bias + relu -> bf16 hi/lo planes (zero pad rows)
__global__ void inproj_epi(const float* __restrict__ P, const float* __restrict__ b,
                           __bf16* __restrict__ hhi, __bf16* __restrict__ hlo) {
    int t = blockIdx.x * 256 + threadIdx.x;
    size_t idx = (size_t)t * 4;
    int row = (int)(idx >> 8), col = (int)(idx & 255);
    float v[4] = {0, 0, 0, 0};
    if (row < NN) {
        const float* p = P + idx;
        float4 a0 = *(const float4*)(p);
        float4 a1 = *(const float4*)(p + NPH);
        float4 a2 = *(const float4*)(p + 2 * NPH);
        float4 a3 = *(const float4*)(p + 3 * NPH);
        v[0] = fmaxf(a0.x + a1.x + a2.x + a3.x + b[col + 0], 0.0f);
        v[1] = fmaxf(a0.y + a1.y + a2.y + a3.y + b[col + 1], 0.0f);
        v[2] = fmaxf(a0.z + a1.z + a2.z + a3.z + b[col + 2], 0.0f);
        v[3] = fmaxf(a0.w + a1.w + a2.w + a3.w + b[col + 3], 0.0f);
    }
    bf16x4 hv, lv;
#pragma unroll
    for (int j = 0; j < 4; ++j) {
        __bf16 h = (__bf16)v[j];
        hv[j] = h; lv[j] = (__bf16)(v[j] - (float)h);
    }
    *(bf16x4*)&hhi[idx] = hv;
    *(bf16x4*)&hlo[idx] = lv;
}

// ------------------------------------------------------------------
// Layer GEMM (K=256): no LDS, per-lane direct fragment loads.
// Epilogue pre-scales each output row by dinv[row]  ->  hws = (h @ W^T) * dinv
__global__ __launch_bounds__(256) void gemm_layer(
    const __bf16* __restrict__ Ah, const __bf16* __restrict__ Al,
    const __bf16* __restrict__ Bh, const __bf16* __restrict__ Bl,
    const float* __restrict__ dinv, float* __restrict__ Cf)
{
    const int tid = threadIdx.x, wid = tid >> 6, lane = tid & 63;
    const int fr = lane & 15, fq = lane >> 4;
    const int wr = wid >> 1, wc = wid & 1;
    const int bm = blockIdx.x * 64, bn = blockIdx.y * 64;

    f32x4 acc[2][2] = {};
    size_t ra[2], rb[2];
#pragma unroll
    for (int mi = 0; mi < 2; ++mi) ra[mi] = (size_t)(bm + wr * 32 + mi * 16 + fr) * 256 + fq * 8;
#pragma unroll
    for (int ni = 0; ni < 2; ++ni) rb[ni] = (size_t)(bn + wc * 32 + ni * 16 + fr) * 256 + fq * 8;

#pragma unroll
    for (int kt = 0; kt < 8; ++kt) {
        bf16x8 ah[2], al[2], bh[2], bl[2];
#pragma unroll
        for (int mi = 0; mi < 2; ++mi) {
            ah[mi] = *(const bf16x8*)(Ah + ra[mi] + kt * 32);
            al[mi] = *(const bf16x8*)(Al + ra[mi] + kt * 32);
        }
#pragma unroll
        for (int ni = 0; ni < 2; ++ni) {
            bh[ni] = *(const bf16x8*)(Bh + rb[ni] + kt * 32);
            bl[ni] = *(const bf16x8*)(Bl + rb[ni] + kt * 32);
        }
#pragma unroll
        for (int mi = 0; mi < 2; ++mi)
#pragma unroll
            for (int ni = 0; ni < 2; ++ni) {
                acc[mi][ni] = __builtin_amdgcn_mfma_f32_16x16x32_bf16(ah[mi], bh[ni], acc[mi][ni], 0, 0, 0);
                acc[mi][ni] = __builtin_amdgcn_mfma_f32_16x16x32_bf16(ah[mi], bl[ni], acc[mi][ni], 0, 0, 0);
                acc[mi][ni] = __builtin_amdgcn_mfma_f32_16x16x32_bf16(al[mi], bh[ni], acc[mi][ni], 0, 0, 0);
            }
    }

    float dv[2][4];
#pragma unroll
    for (int mi = 0; mi < 2; ++mi)
#pragma unroll
        for (int r = 0; r < 4; ++r) {
            int row = bm + wr * 32 + mi * 16 + fq * 4 + r;
            dv[mi][r] = (row < NN) ? dinv[row] : 0.0f;
        }

#pragma unroll
    for (int mi = 0; mi < 2; ++mi)
#pragma unroll
        for (int ni = 0; ni < 2; ++ni) {
            int col = bn + wc * 32 + ni * 16 + fr;
#pragma unroll
            for (int r = 0; r < 4; ++r) {
                int row = bm + wr * 32 + mi * 16 + fq * 4 + r;
                if (row < NN) Cf[(size_t)row * 256 + col] = acc[mi][ni][r] * dv[mi][r];
            }
        }
}

// ------------------------------------------------------------------
// XCD-pinned, feature-chunked GCN aggregate (v4: 8-way ILP).
// 4 chunks of 64 features; per-chunk gather set = 2.56 MB < 4 MB per-XCD L2;
// chunk = xcd>>1. 16 lanes/node, f32x4/lane. 8 independent accumulators keep
// 8 gathers in flight per lane (latency-bound fix).
__global__ __launch_bounds__(256) void gcn_aggregate(
    const float* __restrict__ hws, const float* __restrict__ res,
    const float* __restrict__ dinv, const unsigned* __restrict__ off,
    const int* __restrict__ csr,
    const float* __restrict__ bias, const float* __restrict__ gamma,
    const float* __restrict__ beta, const float* __restrict__ mean,
    const float* __restrict__ var,
    float* __restrict__ hf, __bf16* __restrict__ hhi, __bf16* __restrict__ hlo)
{
    const int xcd = blockIdx.x & 7;
    const int chunk = xcd >> 1;                       // 0..3
    const int nb = (blockIdx.x >> 3) * 2 + (xcd & 1); // node-block 0..625
    if (nb >= 625) return;                            // 625*16 = 10000 exactly

    const int tid = threadIdx.x;
    const int g = tid >> 4;                           // node-in-block 0..15
    const int q = tid & 15;                           // feature lane 0..15
    const int node = nb * 16 + g;
    const int f = chunk * 64 + q * 4;
    const size_t rowb = (size_t)node * HID + f;

    const float dn = dinv[node];
    const unsigned j0 = off[node], j1 = off[node + 1];

    f32x4 a0 = *(const f32x4*)(hws + rowb);           // self term (pre-scaled)
    f32x4 a1 = {0.f,0.f,0.f,0.f}, a2 = {0.f,0.f,0.f,0.f}, a3 = {0.f,0.f,0.f,0.f};
    f32x4 a4 = {0.f,0.f,0.f,0.f}, a5 = {0.f,0.f,0.f,0.f};
    f32x4 a6 = {0.f,0.f,0.f,0.f}, a7 = {0.f,0.f,0.f,0.f};

    unsigned j = j0;
    for (; j + 8 <= j1; j += 8) {
        int s0 = csr[j + 0];
        int s1 = csr[j + 1];
        int s2 = csr[j + 2];
        int s3 = csr[j + 3];
        int s4 = csr[j + 4];
        int s5 = csr[j + 5];
        int s6 = csr[j + 6];
        int s7 = csr[j + 7];
        a0 += *(const f32x4*)(hws + (size_t)s0 * HID + f);
        a1 += *(const f32x4*)(hws + (size_t)s1 * HID + f);
        a2 += *(const f32x4*)(hws + (size_t)s2 * HID + f);
        a3 += *(const f32x4*)(hws + (size_t)s3 * HID + f);
        a4 += *(const f32x4*)(hws + (size_t)s4 * HID + f);
        a5 += *(const f32x4*)(hws + (size_t)s5 * HID + f);
        a6 += *(const f32x4*)(hws + (size_t)s6 * HID + f);
        a7 += *(const f32x4*)(hws + (size_t)s7 * HID + f);
    }
    for (; j + 4 <= j1; j += 4) {
        int s0 = csr[j + 0];
        int s1 = csr[j + 1];
        int s2 = csr[j + 2];
        int s3 = csr[j + 3];
        a1 += *(const f32x4*)(hws + (size_t)s0 * HID + f);
        a2 += *(const f32x4*)(hws + (size_t)s1 * HID + f);
        a3 += *(const f32x4*)(hws + (size_t)s2 * HID + f);
        a4 += *(const f32x4*)(hws + (size_t)s3 * HID + f);
    }
    for (; j < j1; ++j) {
        int s = csr[j];
        a5 += *(const f32x4*)(hws + (size_t)s * HID + f);
    }
    f32x4 acc = ((a0 + a1) + (a2 + a3)) + ((a4 + a5) + (a6 + a7));

    f32x4 b4  = *(const f32x4*)(bias + f);
    f32x4 m4  = *(const f32x4*)(mean + f);
    f32x4 v4  = *(const f32x4*)(var + f);
    f32x4 g4  = *(const f32x4*)(gamma + f);
    f32x4 be4 = *(const f32x4*)(beta + f);
    f32x4 r4 = {0.0f, 0.0f, 0.0f, 0.0f};
    if (res) r4 = *(const f32x4*)(res + rowb);

    f32x4 o;
    bf16x4 hv, lv;
#pragma unroll
    for (int jj = 0; jj < 4; ++jj) {
        float t = dn * acc[jj] + b4[jj];
        t = (t - m4[jj]) * rsqrtf(v4[jj] + BN_EPS) * g4[jj] + be4[jj];
        t = fmaxf(t, 0.0f);
        t += r4[jj];
        o[jj] = t;
        __bf16 h = (__bf16)t;
        hv[jj] = h; lv[jj] = (__bf16)(t - (float)h);
    }
    if (hf) *(f32x4*)(hf + rowb) = o;
    *(bf16x4*)&hhi[rowb] = hv;
    *(bf16x4*)&hlo[rowb] = lv;
}

// ------------------------------------------------------------------
// Fused classifier: 32-row tile, h -> O1(LDS) -> O2(LDS) -> logits.
__global__ __launch_bounds__(256) void classifier(
    const __bf16* __restrict__ Ah, const __bf16* __restrict__ Al,
    const __bf16* __restrict__ c1h, const __bf16* __restrict__ c1l, const float* __restrict__ b1,
    const __bf16* __restrict__ c2h, const __bf16* __restrict__ c2l, const float* __restrict__ b2,
    const __bf16* __restrict__ c3h, const __bf16* __restrict__ c3l, const float* __restrict__ b3,
    float* __restrict__ out)
{
    __shared__ __align__(16) float sO1[32][132];
    __shared__ __align__(16) float sO2[32][68];

    const int tid = threadIdx.x, wid = tid >> 6, lane = tid & 63;
    const int fr = lane & 15, fq = lane >> 4;
    const int bm = blockIdx.x * 32;

    // ---- stage 1: O1 = relu(h @ c1^T + b1)   M=32 N=128 K=256
    {
        f32x4 acc[2][2] = {};
        size_t ra[2], rb[2];
#pragma unroll
        for (int mi = 0; mi < 2; ++mi) ra[mi] = (size_t)(bm + mi * 16 + fr) * 256 + fq * 8;
#pragma unroll
        for (int ni = 0; ni < 2; ++ni) rb[ni] = (size_t)(wid * 32 + ni * 16 + fr) * 256 + fq * 8;
#pragma unroll
        for (int kt = 0; kt < 8; ++kt) {
            bf16x8 ah[2], al[2], bh[2], bl[2];
#pragma unroll
            for (int mi = 0; mi < 2; ++mi) {
                ah[mi] = *(const bf16x8*)(Ah + ra[mi] + kt * 32);
                al[mi] = *(const bf16x8*)(Al + ra[mi] + kt * 32);
            }
#pragma unroll
            for (int ni = 0; ni < 2; ++ni) {
                bh[ni] = *(const bf16x8*)(c1h + rb[ni] + kt * 32);
                bl[ni] = *(const bf16x8*)(c1l + rb[ni] + kt * 32);
            }
#pragma unroll
            for (int mi = 0; mi < 2; ++mi)
#pragma unroll
                for (int ni = 0; ni < 2; ++ni) {
                    acc[mi][ni] = __builtin_amdgcn_mfma_f32_16x16x32_bf16(ah[mi], bh[ni], acc[mi][ni], 0, 0, 0);
                    acc[mi][ni] = __builtin_amdgcn_mfma_f32_16x16x32_bf16(ah[mi], bl[ni], acc[mi][ni], 0, 0, 0);
                    acc[mi][ni] = __builtin_amdgcn_mfma_f32_16x16x32_bf16(al[mi], bh[ni], acc[mi][ni], 0, 0, 0);
                }
        }
#pragma unroll
        for (int mi = 0; mi < 2; ++mi)
#pragma unroll
            for (int ni = 0; ni < 2; ++ni) {
                int col = wid * 32 + ni * 16 + fr;
                float bb = b1[col];
#pragma unroll
                for (int r = 0; r < 4; ++r)
                    sO1[mi * 16 + fq * 4 + r][col] = fmaxf(acc[mi][ni][r] + bb, 0.0f);
            }
    }
    __syncthreads();

    // ---- stage 2: O2 = relu(O1 @ c2^T + b2)   M=32 N=64 K=128
    {
        f32x4 acc[2] = {};
#pragma unroll
        for (int kt = 0; kt < 4; ++kt) {
            bf16x8 ah[2], al[2];
#pragma unroll
            for (int mi = 0; mi < 2; ++mi) {
                const float* p = &sO1[mi * 16 + fr][kt * 32 + fq * 8];
                f32x4 v0 = *(const f32x4*)p;
                f32x4 v1 = *(const f32x4*)(p + 4);
                float vv[8] = {v0[0], v0[1], v0[2], v0[3], v1[0], v1[1], v1[2], v1[3]};
#pragma unroll
                for (int j = 0; j < 8; ++j) {
                    __bf16 h = (__bf16)vv[j];
                    ah[mi][j] = h; al[mi][j] = (__bf16)(vv[j] - (float)h);
                }
            }
            size_t rb = (size_t)(wid * 16 + fr) * 128 + kt * 32 + fq * 8;
            bf16x8 bh = *(const bf16x8*)(c2h + rb);
            bf16x8 bl = *(const bf16x8*)(c2l + rb);
#pragma unroll
            for (int mi = 0; mi < 2; ++mi) {
                acc[mi] = __builtin_amdgcn_mfma_f32_16x16x32_bf16(ah[mi], bh, acc[mi], 0, 0, 0);
                acc[mi] = __builtin_amdgcn_mfma_f32_16x16x32_bf16(ah[mi], bl, acc[mi], 0, 0, 0);
                acc[mi] = __builtin_amdgcn_mfma_f32_16x16x32_bf16(al[mi], bh, acc[mi], 0, 0, 0);
            }
        }
        int col = wid * 16 + fr;
        float bb = b2[col];
#pragma unroll
        for (int mi = 0; mi < 2; ++mi)
#pragma unroll
            for (int r = 0; r < 4; ++r)
                sO2[mi * 16 + fq * 4 + r][col] = fmaxf(acc[mi][r] + bb, 0.0f);
    }
    __syncthreads();

    // ---- stage 3: logits = O2 @ c3^T + b3
    if (wid < 2) {
        f32x4 acc = {};
#pragma unroll
        for (int kt = 0; kt < 2; ++kt) {
            const float* p = &sO2[wid * 16 + fr][kt * 32 + fq * 8];
            f32x4 v0 = *(const f32x4*)p;
            f32x4 v1 = *(const f32x4*)(p + 4);
            float vv[8] = {v0[0], v0[1], v0[2], v0[3], v1[0], v1[1], v1[2], v1[3]};
            bf16x8 ah, al;
#pragma unroll
            for (int j = 0; j < 8; ++j) {
                __bf16 h = (__bf16)vv[j];
                ah[j] = h; al[j] = (__bf16)(vv[j] - (float)h);
            }
            size_t rb = (size_t)fr * 64 + kt * 32 + fq * 8;
            bf16x8 bh = *(const bf16x8*)(c3h + rb);
            bf16x8 bl = *(const bf16x8*)(c3l + rb);
            acc = __builtin_amdgcn_mfma_f32_16x16x32_bf16(ah, bh, acc, 0, 0, 0);
            acc = __builtin_amdgcn_mfma_f32_16x16x32_bf16(ah, bl, acc, 0, 0, 0);
            acc = __builtin_amdgcn_mfma_f32_16x16x32_bf16(al, bh, acc, 0, 0, 0);
        }
        if (fr < 10) {
            float bb = b3[fr];
#pragma unroll
            for (int r = 0; r < 4; ++r) {
                int row = bm + wid * 16 + fq * 4 + r;
                if (row < NN) out[(size_t)row * 10 + fr] = acc[r] + bb;
            }
        }
    }
}

// ------------------------------------------------------------------
extern "C" void kernel_launch(void* const* d_in, const int* in_sizes, int n_in,
                              void* d_out, int out_size, void* d_ws, size_t ws_size,
                              hipStream_t stream)
{
    const float* x     = (const float*)d_in[0];
    const int*   eidx  = (const int*)d_in[1];
    const float* in_W  = (const float*)d_in[2];
    const float* in_b  = (const float*)d_in[3];
    const float* gcn_W = (const float*)d_in[4];
    const float* gcn_b = (const float*)d_in[5];
    const float* bn_g  = (const float*)d_in[6];
    const float* bn_be = (const float*)d_in[7];
    const float* bn_m  = (const float*)d_in[8];
    const float* bn_v  = (const float*)d_in[9];
    const float* c1_W  = (const float*)d_in[10];
    const float* c1_b  = (const float*)d_in[11];
    const float* c2_W  = (const float*)d_in[12];
    const float* c2_b  = (const float*)d_in[13];
    const float* c3_W  = (const float*)d_in[14];
    const float* c3_b  = (const float*)d_in[15];
    float* out = (float*)d_out;

    const int E = in_sizes[1] / 2;
    float* ws = (float*)d_ws;

    // ---- workspace layout ----
    float*  P   = ws;                 // 4 slices of NPH f32 (reused as h1,h2,hws)
    float*  h1  = P;
    float*  h2  = P + NPH;
    float*  hws = P + 2 * NPH;
    __bf16* hhi = (__bf16*)(P + 4 * NPH);
    __bf16* hlo = hhi + NPH;
    __bf16* wih = hlo + NPH;          // 256x2048
    __bf16* wil = wih + 524288;
    __bf16* gwh = wil + 524288;       // 768x256
    __bf16* gwl = gwh + 196608;
    __bf16* c1h = gwl + 196608;       // 128x256
    __bf16* c1l = c1h + 32768;
    __bf16* c2h = c1l + 32768;        // 64x128
    __bf16* c2l = c2h + 8192;
    __bf16* c3h = c2l + 8192;         // 16x64 (10 real rows)
    __bf16* c3l = c3h + 1024;
    float*    dinv = (float*)(c3l + 1024);
    unsigned* cnt  = (unsigned*)(dinv + NN);
    unsigned* off  = cnt + NN;
    unsigned* cur  = off + NN + 1;
    unsigned* flag = cur + NN;
    int*      csr  = (int*)(flag + 4);

    // ---- graph prep + weight splits (merged first launch) ----
    prep_split<<<3020, 256, 0, stream>>>(eidx, cnt, flag, in_W, gcn_W, c1_W, c2_W, c3_W,
                                         wih, wil, gwh, gwl, c1h, c1l, c2h, c2l, c3h, c3l);
    count_edges<<<(E + 255) / 256, 256, 0, stream>>>(eidx, flag, cnt, E);
    scan_dinv<<<1, 256, 0, stream>>>(cnt, off, cur, dinv, NN);
    fill_csr<<<(E + 255) / 256, 256, 0, stream>>>(eidx, flag, cur, csr, E);

    // ---- input projection ----
    inproj_gemm<<<dim3(NP / 64, 1, IPZ), 256, 0, stream>>>(x, wih, wil, P);
    inproj_epi<<<(int)(NPH / 1024), 256, 0, stream>>>(P, in_b, hhi, hlo);

    // ---- 3 GCN layers ----
    for (int i = 0; i < 3; ++i) {
        gemm_layer<<<dim3(NP / 64, 4), 256, 0, stream>>>(
            hhi, hlo, gwh + (size_t)i * 65536, gwl + (size_t)i * 65536, dinv, hws);
        const float* res = (i == 0) ? nullptr : (i == 1 ? h1 : h2);
        float* hf = (i == 0) ? h1 : (i == 1 ? h2 : nullptr);
        gcn_aggregate<<<2504, 256, 0, stream>>>(
            hws, res, dinv, off, csr,
            gcn_b + i * HID, bn_g + i * HID, bn_be + i * HID,
            bn_m + i * HID, bn_v + i * HID, hf, hhi, hlo);
    }

    // ---- fused classifier ----
    classifier<<<NP / 32, 256, 0, stream>>>(hhi, hlo, c1h, c1l, c1_b,
                                            c2h, c2l, c2_b, c3h, c3l, c3_b, out);
}

// Round 12
// 277.555 us; speedup vs baseline: 1.5910x; 1.1735x over previous
//
#include <hip/hip_runtime.h>
#include <hip/hip_bf16.h>

#define NN   10000
#define NP   10048          // 157*64 padded rows
#define HID  256
#define BN_EPS 1e-5f
#define NPH  ((size_t)NP * 256)

typedef _Float16 f16x4 __attribute__((ext_vector_type(4)));
typedef _Float16 f16x8 __attribute__((ext_vector_type(8)));
typedef float    f32x4 __attribute__((ext_vector_type(4)));

__device__ __forceinline__ void gl_lds16(const void* gptr, void* lptr) {
    __builtin_amdgcn_global_load_lds(
        (const __attribute__((address_space(1))) void*)gptr,
        (__attribute__((address_space(3))) void*)lptr,
        16, 0, 0);
}

// ------------------------------------------------------------------
// Merged: cnt-zero + i64-layout detect (blocks 0..39) and weight fp16
// conversion (single plane per weight; blocks 40..3019).
__global__ void prep_split(const int* __restrict__ e, unsigned* __restrict__ cnt,
                           unsigned* __restrict__ flag,
                           const float* __restrict__ in_W, const float* __restrict__ gcn_W,
                           const float* __restrict__ c1_W, const float* __restrict__ c2_W,
                           const float* __restrict__ c3_W,
                           _Float16* __restrict__ wi, _Float16* __restrict__ gw,
                           _Float16* __restrict__ c1, _Float16* __restrict__ c2,
                           _Float16* __restrict__ c3) {
    if (blockIdx.x < 40) {
        int i = blockIdx.x * 256 + threadIdx.x;
        if (i < NN) cnt[i] = 0u;
        if (blockIdx.x == 0) {
            __shared__ int nz;
            if (threadIdx.x == 0) nz = 0;
            __syncthreads();
            if (e[2 * threadIdx.x + 1] != 0) nz = 1;
            __syncthreads();
            if (threadIdx.x == 0) *flag = (nz == 0) ? 1u : 0u;  // 1 => int64 layout
        }
        return;
    }
    int idx = (blockIdx.x - 40) * 256 + threadIdx.x;
    float v; _Float16* d; int o;
    if (idx < 524288)      { v = in_W[idx];          d = wi; o = idx; }
    else if (idx < 720896) { o = idx - 524288; v = gcn_W[o]; d = gw; }
    else if (idx < 753664) { o = idx - 720896; v = c1_W[o];  d = c1; }
    else if (idx < 761856) { o = idx - 753664; v = c2_W[o];  d = c2; }
    else                   { o = idx - 761856; int r = o >> 6, c = o & 63;
                             v = (r < 10) ? c3_W[r * 64 + c] : 0.0f; d = c3; }
    d[o] = (_Float16)v;
}

__device__ __forceinline__ int edge_val(const int* e, unsigned f, long idx) {
    return f ? e[2 * idx] : e[idx];
}

__global__ void count_edges(const int* __restrict__ e, const unsigned* __restrict__ flag,
                            unsigned* __restrict__ cnt, int E) {
    int i = blockIdx.x * blockDim.x + threadIdx.x;
    if (i >= E) return;
    unsigned f = *flag;
    atomicAdd(&cnt[edge_val(e, f, (long)E + i)], 1u);
}

__global__ void scan_dinv(const unsigned* __restrict__ cnt, unsigned* __restrict__ off,
                          unsigned* __restrict__ cur, float* __restrict__ dinv, int n) {
    __shared__ unsigned partial[256];
    int t = threadIdx.x;
    int chunk = (n + 255) / 256;
    int lo = t * chunk;
    int hi = lo + chunk; if (hi > n) hi = n; if (lo > n) lo = n;
    unsigned s = 0;
    for (int i = lo; i < hi; ++i) s += cnt[i];
    partial[t] = s;
    __syncthreads();
    for (int d = 1; d < 256; d <<= 1) {
        unsigned v = (t >= d) ? partial[t - d] : 0u;
        __syncthreads();
        partial[t] += v;
        __syncthreads();
    }
    unsigned base = (t == 0) ? 0u : partial[t - 1];
    for (int i = lo; i < hi; ++i) {
        off[i] = base; cur[i] = base;
        dinv[i] = rsqrtf((float)cnt[i] + 1.0f);
        base += cnt[i];
    }
    if (t == 255) off[n] = base;
}

__global__ void fill_csr(const int* __restrict__ e, const unsigned* __restrict__ flag,
                         unsigned* __restrict__ cur, int* __restrict__ csr_src, int E) {
    int i = blockIdx.x * blockDim.x + threadIdx.x;
    if (i >= E) return;
    unsigned f = *flag;
    int src = edge_val(e, f, (long)i);
    int dst = edge_val(e, f, (long)E + i);
    unsigned pos = atomicAdd(&cur[dst], 1u);
    csr_src[pos] = src;
}

// ------------------------------------------------------------------
// Input projection: BM=64 x BN=256, split-K=4, 2-phase pipelined, dbuf LDS.
// A(x) split fp16 hi/lo in-kernel (exact to 2^-22); B = single fp16 plane via
// global_load_lds. 2 MFMA passes/frag (Ah*B + Al*B). LDS 48 KB -> 3 blk/CU.
#define IPZ 4
#define IPKC 512
__global__ __launch_bounds__(256) void inproj_gemm(
    const float* __restrict__ A,
    const _Float16* __restrict__ B,
    float* __restrict__ P)
{
    __shared__ __align__(16) _Float16 sAh[2][2048], sAl[2][2048];
    __shared__ __align__(16) _Float16 sB[2][8192];

    const int tid = threadIdx.x, wid = tid >> 6, lane = tid & 63;
    const int fr = lane & 15, fq = lane >> 4;
    const int bm = blockIdx.x * 64;
    const int kbase = blockIdx.z * IPKC;
    const int wn = wid * 64;

    f32x4 acc[4][4] = {};

    const int rs = tid >> 2, cq = tid & 3;
    const int gr = min(bm + rs, NN - 1);
    const float* aptr = A + (size_t)gr * 2048 + cq * 8;
    const int scA = rs * 32 + ((cq ^ ((rs >> 1) & 3)) << 3);
    const int brow_l = lane >> 2, bch = lane & 3;

    float av[8];
    int cur = 0;

    {   // prologue: stage tile 0
        float4 v0 = *(const float4*)(aptr + kbase);
        float4 v1 = *(const float4*)(aptr + kbase + 4);
        av[0]=v0.x; av[1]=v0.y; av[2]=v0.z; av[3]=v0.w;
        av[4]=v1.x; av[5]=v1.y; av[6]=v1.z; av[7]=v1.w;
#pragma unroll
        for (int j = 0; j < 4; ++j) {
            int slice = wid * 4 + j;
            int row = slice * 16 + brow_l;
            int lc = bch ^ ((row >> 1) & 3);
            gl_lds16(B + (size_t)row * 2048 + kbase + lc * 8, &sB[0][slice * 512]);
        }
        f16x8 hv, lv;
#pragma unroll
        for (int j = 0; j < 8; ++j) {
            _Float16 h = (_Float16)av[j];
            hv[j] = h; lv[j] = (_Float16)(av[j] - (float)h);
        }
        *(f16x8*)&sAh[0][scA] = hv;
        *(f16x8*)&sAl[0][scA] = lv;
    }
    __syncthreads();

    for (int kt = 0; kt < IPKC / 32; ++kt) {
        const bool more = (kt + 1) < IPKC / 32;
        const int nk = kbase + (kt + 1) * 32;
        if (more) {
            float4 v0 = *(const float4*)(aptr + nk);
            float4 v1 = *(const float4*)(aptr + nk + 4);
            av[0]=v0.x; av[1]=v0.y; av[2]=v0.z; av[3]=v0.w;
            av[4]=v1.x; av[5]=v1.y; av[6]=v1.z; av[7]=v1.w;
#pragma unroll
            for (int j = 0; j < 4; ++j) {
                int slice = wid * 4 + j;
                int row = slice * 16 + brow_l;
                int lc = bch ^ ((row >> 1) & 3);
                gl_lds16(B + (size_t)row * 2048 + nk + lc * 8, &sB[cur ^ 1][slice * 512]);
            }
        }
        f16x8 b[4];
#pragma unroll
        for (int ni = 0; ni < 4; ++ni) {
            int r = wn + ni * 16 + fr;
            b[ni] = *(const f16x8*)&sB[cur][r * 32 + ((fq ^ ((r >> 1) & 3)) << 3)];
        }
#pragma unroll
        for (int mi = 0; mi < 4; ++mi) {
            int r = mi * 16 + fr;
            int e = r * 32 + ((fq ^ ((r >> 1) & 3)) << 3);
            f16x8 ah = *(const f16x8*)&sAh[cur][e];
            f16x8 al = *(const f16x8*)&sAl[cur][e];
#pragma unroll
            for (int ni = 0; ni < 4; ++ni) {
                acc[mi][ni] = __builtin_amdgcn_mfma_f32_16x16x32_f16(ah, b[ni], acc[mi][ni], 0, 0, 0);
                acc[mi][ni] = __builtin_amdgcn_mfma_f32_16x16x32_f16(al, b[ni], acc[mi][ni], 0, 0, 0);
            }
        }
        if (more) {
            f16x8 hv, lv;
#pragma unroll
            for (int j = 0; j < 8; ++j) {
                _Float16 h = (_Float16)av[j];
                hv[j] = h; lv[j] = (_Float16)(av[j] - (float)h);
            }
            *(f16x8*)&sAh[cur ^ 1][scA] = hv;
            *(f16x8*)&sAl[cur ^ 1][scA] = lv;
        }
        __syncthreads();
        cur ^= 1;
    }

    float* Pz = P + (size_t)blockIdx.z * NPH;
#pragma unroll
    for (int mi = 0; mi < 4; ++mi) {
        int row0 = bm + mi * 16 + fq * 4;
#pragma unroll
        for (int ni = 0; ni < 4; ++ni) {
            int col = wn + ni * 16 + fr;
#pragma unroll
            for (int r = 0; r < 4; ++r)
                Pz[(size_t)(row0 + r) * 256 + col] = acc[mi][ni][r];
        }
    }
}

// reduce 4 partials + bias + relu -> fp16 hi/lo planes (zero pad rows)
__global__ void inproj_epi(const float* __restrict__ P, const float* __restrict__ b,
                           _Float16* __restrict__ hh, _Float16* __restrict__ hl) {
    int t = blockIdx.x * 256 + threadIdx.x;
    size_t idx = (size_t)t * 4;
    int row = (int)(idx >> 8), col = (int)(idx & 255);
    float v[4] = {0, 0, 0, 0};
    if (row < NN) {
        const float* p = P + idx;
        float4 a0 = *(const float4*)(p);
        float4 a1 = *(const float4*)(p + NPH);
        float4 a2 = *(const float4*)(p + 2 * NPH);
        float4 a3 = *(const float4*)(p + 3 * NPH);
        v[0] = fmaxf(a0.x + a1.x + a2.x + a3.x + b[col + 0], 0.0f);
        v[1] = fmaxf(a0.y + a1.y + a2.y + a3.y + b[col + 1], 0.0f);
        v[2] = fmaxf(a0.z + a1.z + a2.z + a3.z + b[col + 2], 0.0f);
        v[3] = fmaxf(a0.w + a1.w + a2.w + a3.w + b[col + 3], 0.0f);
    }
    f16x4 hv, lv;
#pragma unroll
    for (int j = 0; j < 4; ++j) {
        _Float16 h = (_Float16)v[j];
        hv[j] = h; lv[j] = (_Float16)(v[j] - (float)h);
    }
    *(f16x4*)&hh[idx] = hv;
    *(f16x4*)&hl[idx] = lv;
}

// ------------------------------------------------------------------
// Layer GEMM (K=256): no LDS, per-lane direct fragment loads.
// A = h fp16 hi/lo (2-term exact), B = single fp16 weight plane; 2 passes.
// Epilogue pre-scales each output row by dinv[row] -> hws = (h @ W^T) * dinv
__global__ __launch_bounds__(256) void gemm_layer(
    const _Float16* __restrict__ Ah, const _Float16* __restrict__ Al,
    const _Float16* __restrict__ Bw,
    const float* __restrict__ dinv, float* __restrict__ Cf)
{
    const int tid = threadIdx.x, wid = tid >> 6, lane = tid & 63;
    const int fr = lane & 15, fq = lane >> 4;
    const int wr = wid >> 1, wc = wid & 1;
    const int bm = blockIdx.x * 64, bn = blockIdx.y * 64;

    f32x4 acc[2][2] = {};
    size_t ra[2], rb[2];
#pragma unroll
    for (int mi = 0; mi < 2; ++mi) ra[mi] = (size_t)(bm + wr * 32 + mi * 16 + fr) * 256 + fq * 8;
#pragma unroll
    for (int ni = 0; ni < 2; ++ni) rb[ni] = (size_t)(bn + wc * 32 + ni * 16 + fr) * 256 + fq * 8;

#pragma unroll
    for (int kt = 0; kt < 8; ++kt) {
        f16x8 ah[2], al[2], bw[2];
#pragma unroll
        for (int mi = 0; mi < 2; ++mi) {
            ah[mi] = *(const f16x8*)(Ah + ra[mi] + kt * 32);
            al[mi] = *(const f16x8*)(Al + ra[mi] + kt * 32);
        }
#pragma unroll
        for (int ni = 0; ni < 2; ++ni)
            bw[ni] = *(const f16x8*)(Bw + rb[ni] + kt * 32);
#pragma unroll
        for (int mi = 0; mi < 2; ++mi)
#pragma unroll
            for (int ni = 0; ni < 2; ++ni) {
                acc[mi][ni] = __builtin_amdgcn_mfma_f32_16x16x32_f16(ah[mi], bw[ni], acc[mi][ni], 0, 0, 0);
                acc[mi][ni] = __builtin_amdgcn_mfma_f32_16x16x32_f16(al[mi], bw[ni], acc[mi][ni], 0, 0, 0);
            }
    }

    float dv[2][4];
#pragma unroll
    for (int mi = 0; mi < 2; ++mi)
#pragma unroll
        for (int r = 0; r < 4; ++r) {
            int row = bm + wr * 32 + mi * 16 + fq * 4 + r;
            dv[mi][r] = (row < NN) ? dinv[row] : 0.0f;
        }

#pragma unroll
    for (int mi = 0; mi < 2; ++mi)
#pragma unroll
        for (int ni = 0; ni < 2; ++ni) {
            int col = bn + wc * 32 + ni * 16 + fr;
#pragma unroll
            for (int r = 0; r < 4; ++r) {
                int row = bm + wr * 32 + mi * 16 + fq * 4 + r;
                if (row < NN) Cf[(size_t)row * 256 + col] = acc[mi][ni][r] * dv[mi][r];
            }
        }
}

// ------------------------------------------------------------------
// XCD-pinned, feature-chunked GCN aggregate (v4: 8-way ILP).
__global__ __launch_bounds__(256) void gcn_aggregate(
    const float* __restrict__ hws, const float* __restrict__ res,
    const float* __restrict__ dinv, const unsigned* __restrict__ off,
    const int* __restrict__ csr,
    const float* __restrict__ bias, const float* __restrict__ gamma,
    const float* __restrict__ beta, const float* __restrict__ mean,
    const float* __restrict__ var,
    float* __restrict__ hf, _Float16* __restrict__ hh, _Float16* __restrict__ hl)
{
    const int xcd = blockIdx.x & 7;
    const int chunk = xcd >> 1;                       // 0..3
    const int nb = (blockIdx.x >> 3) * 2 + (xcd & 1); // node-block 0..625
    if (nb >= 625) return;                            // 625*16 = 10000 exactly

    const int tid = threadIdx.x;
    const int g = tid >> 4;                           // node-in-block 0..15
    const int q = tid & 15;                           // feature lane 0..15
    const int node = nb * 16 + g;
    const int f = chunk * 64 + q * 4;
    const size_t rowb = (size_t)node * HID + f;

    const float dn = dinv[node];
    const unsigned j0 = off[node], j1 = off[node + 1];

    f32x4 a0 = *(const f32x4*)(hws + rowb);           // self term (pre-scaled)
    f32x4 a1 = {0.f,0.f,0.f,0.f}, a2 = {0.f,0.f,0.f,0.f}, a3 = {0.f,0.f,0.f,0.f};
    f32x4 a4 = {0.f,0.f,0.f,0.f}, a5 = {0.f,0.f,0.f,0.f};
    f32x4 a6 = {0.f,0.f,0.f,0.f}, a7 = {0.f,0.f,0.f,0.f};

    unsigned j = j0;
    for (; j + 8 <= j1; j += 8) {
        int s0 = csr[j + 0];
        int s1 = csr[j + 1];
        int s2 = csr[j + 2];
        int s3 = csr[j + 3];
        int s4 = csr[j + 4];
        int s5 = csr[j + 5];
        int s6 = csr[j + 6];
        int s7 = csr[j + 7];
        a0 += *(const f32x4*)(hws + (size_t)s0 * HID + f);
        a1 += *(const f32x4*)(hws + (size_t)s1 * HID + f);
        a2 += *(const f32x4*)(hws + (size_t)s2 * HID + f);
        a3 += *(const f32x4*)(hws + (size_t)s3 * HID + f);
        a4 += *(const f32x4*)(hws + (size_t)s4 * HID + f);
        a5 += *(const f32x4*)(hws + (size_t)s5 * HID + f);
        a6 += *(const f32x4*)(hws + (size_t)s6 * HID + f);
        a7 += *(const f32x4*)(hws + (size_t)s7 * HID + f);
    }
    for (; j + 4 <= j1; j += 4) {
        int s0 = csr[j + 0];
        int s1 = csr[j + 1];
        int s2 = csr[j + 2];
        int s3 = csr[j + 3];
        a1 += *(const f32x4*)(hws + (size_t)s0 * HID + f);
        a2 += *(const f32x4*)(hws + (size_t)s1 * HID + f);
        a3 += *(const f32x4*)(hws + (size_t)s2 * HID + f);
        a4 += *(const f32x4*)(hws + (size_t)s3 * HID + f);
    }
    for (; j < j1; ++j) {
        int s = csr[j];
        a5 += *(const f32x4*)(hws + (size_t)s * HID + f);
    }
    f32x4 acc = ((a0 + a1) + (a2 + a3)) + ((a4 + a5) + (a6 + a7));

    f32x4 b4  = *(const f32x4*)(bias + f);
    f32x4 m4  = *(const f32x4*)(mean + f);
    f32x4 v4  = *(const f32x4*)(var + f);
    f32x4 g4  = *(const f32x4*)(gamma + f);
    f32x4 be4 = *(const f32x4*)(beta + f);
    f32x4 r4 = {0.0f, 0.0f, 0.0f, 0.0f};
    if (res) r4 = *(const f32x4*)(res + rowb);

    f32x4 o;
    f16x4 hv, lv;
#pragma unroll
    for (int jj = 0; jj < 4; ++jj) {
        float t = dn * acc[jj] + b4[jj];
        t = (t - m4[jj]) * rsqrtf(v4[jj] + BN_EPS) * g4[jj] + be4[jj];
        t = fmaxf(t, 0.0f);
        t += r4[jj];
        o[jj] = t;
        _Float16 h = (_Float16)t;
        hv[jj] = h; lv[jj] = (_Float16)(t - (float)h);
    }
    if (hf) *(f32x4*)(hf + rowb) = o;
    *(f16x4*)&hh[rowb] = hv;
    *(f16x4*)&hl[rowb] = lv;
}

// ------------------------------------------------------------------
// Fused classifier: 32-row tile, h -> O1(LDS) -> O2(LDS) -> logits.
// A-side fp16 hi/lo split, weights single fp16; 2 MFMA passes per frag.
__global__ __launch_bounds__(256) void classifier(
    const _Float16* __restrict__ Ah, const _Float16* __restrict__ Al,
    const _Float16* __restrict__ c1w, const float* __restrict__ b1,
    const _Float16* __restrict__ c2w, const float* __restrict__ b2,
    const _Float16* __restrict__ c3w, const float* __restrict__ b3,
    float* __restrict__ out)
{
    __shared__ __align__(16) float sO1[32][132];
    __shared__ __align__(16) float sO2[32][68];

    const int tid = threadIdx.x, wid = tid >> 6, lane = tid & 63;
    const int fr = lane & 15, fq = lane >> 4;
    const int bm = blockIdx.x * 32;

    // ---- stage 1: O1 = relu(h @ c1^T + b1)   M=32 N=128 K=256
    {
        f32x4 acc[2][2] = {};
        size_t ra[2], rb[2];
#pragma unroll
        for (int mi = 0; mi < 2; ++mi) ra[mi] = (size_t)(bm + mi * 16 + fr) * 256 + fq * 8;
#pragma unroll
        for (int ni = 0; ni < 2; ++ni) rb[ni] = (size_t)(wid * 32 + ni * 16 + fr) * 256 + fq * 8;
#pragma unroll
        for (int kt = 0; kt < 8; ++kt) {
            f16x8 ah[2], al[2], bw[2];
#pragma unroll
            for (int mi = 0; mi < 2; ++mi) {
                ah[mi] = *(const f16x8*)(Ah + ra[mi] + kt * 32);
                al[mi] = *(const f16x8*)(Al + ra[mi] + kt * 32);
            }
#pragma unroll
            for (int ni = 0; ni < 2; ++ni)
                bw[ni] = *(const f16x8*)(c1w + rb[ni] + kt * 32);
#pragma unroll
            for (int mi = 0; mi < 2; ++mi)
#pragma unroll
                for (int ni = 0; ni < 2; ++ni) {
                    acc[mi][ni] = __builtin_amdgcn_mfma_f32_16x16x32_f16(ah[mi], bw[ni], acc[mi][ni], 0, 0, 0);
                    acc[mi][ni] = __builtin_amdgcn_mfma_f32_16x16x32_f16(al[mi], bw[ni], acc[mi][ni], 0, 0, 0);
                }
        }
#pragma unroll
        for (int mi = 0; mi < 2; ++mi)
#pragma unroll
            for (int ni = 0; ni < 2; ++ni) {
                int col = wid * 32 + ni * 16 + fr;
                float bb = b1[col];
#pragma unroll
                for (int r = 0; r < 4; ++r)
                    sO1[mi * 16 + fq * 4 + r][col] = fmaxf(acc[mi][ni][r] + bb, 0.0f);
            }
    }
    __syncthreads();

    // ---- stage 2: O2 = relu(O1 @ c2^T + b2)   M=32 N=64 K=128
    {
        f32x4 acc[2] = {};
#pragma unroll
        for (int kt = 0; kt < 4; ++kt) {
            f16x8 ah[2], al[2];
#pragma unroll
            for (int mi = 0; mi < 2; ++mi) {
                const float* p = &sO1[mi * 16 + fr][kt * 32 + fq * 8];
                f32x4 v0 = *(const f32x4*)p;
                f32x4 v1 = *(const f32x4*)(p + 4);
                float vv[8] = {v0[0], v0[1], v0[2], v0[3], v1[0], v1[1], v1[2], v1[3]};
#pragma unroll
                for (int j = 0; j < 8; ++j) {
                    _Float16 h = (_Float16)vv[j];
                    ah[mi][j] = h; al[mi][j] = (_Float16)(vv[j] - (float)h);
                }
            }
            size_t rb = (size_t)(wid * 16 + fr) * 128 + kt * 32 + fq * 8;
            f16x8 bw = *(const f16x8*)(c2w + rb);
#pragma unroll
            for (int mi = 0; mi < 2; ++mi) {
                acc[mi] = __builtin_amdgcn_mfma_f32_16x16x32_f16(ah[mi], bw, acc[mi], 0, 0, 0);
                acc[mi] = __builtin_amdgcn_mfma_f32_16x16x32_f16(al[mi], bw, acc[mi], 0, 0, 0);
            }
        }
        int col = wid * 16 + fr;
        float bb = b2[col];
#pragma unroll
        for (int mi = 0; mi < 2; ++mi)
#pragma unroll
            for (int r = 0; r < 4; ++r)
                sO2[mi * 16 + fq * 4 + r][col] = fmaxf(acc[mi][r] + bb, 0.0f);
    }
    __syncthreads();

    // ---- stage 3: logits = O2 @ c3^T + b3
    if (wid < 2) {
        f32x4 acc = {};
#pragma unroll
        for (int kt = 0; kt < 2; ++kt) {
            const float* p = &sO2[wid * 16 + fr][kt * 32 + fq * 8];
            f32x4 v0 = *(const f32x4*)p;
            f32x4 v1 = *(const f32x4*)(p + 4);
            float vv[8] = {v0[0], v0[1], v0[2], v0[3], v1[0], v1[1], v1[2], v1[3]};
            f16x8 ah, al;
#pragma unroll
            for (int j = 0; j < 8; ++j) {
                _Float16 h = (_Float16)vv[j];
                ah[j] = h; al[j] = (_Float16)(vv[j] - (float)h);
            }
            size_t rb = (size_t)fr * 64 + kt * 32 + fq * 8;
            f16x8 bw = *(const f16x8*)(c3w + rb);
            acc = __builtin_amdgcn_mfma_f32_16x16x32_f16(ah, bw, acc, 0, 0, 0);
            acc = __builtin_amdgcn_mfma_f32_16x16x32_f16(al, bw, acc, 0, 0, 0);
        }
        if (fr < 10) {
            float bb = b3[fr];
#pragma unroll
            for (int r = 0; r < 4; ++r) {
                int row = bm + wid * 16 + fq * 4 + r;
                if (row < NN) out[(size_t)row * 10 + fr] = acc[r] + bb;
            }
        }
    }
}

// ------------------------------------------------------------------
extern "C" void kernel_launch(void* const* d_in, const int* in_sizes, int n_in,
                              void* d_out, int out_size, void* d_ws, size_t ws_size,
                              hipStream_t stream)
{
    const float* x     = (const float*)d_in[0];
    const int*   eidx  = (const int*)d_in[1];
    const float* in_W  = (const float*)d_in[2];
    const float* in_b  = (const float*)d_in[3];
    const float* gcn_W = (const float*)d_in[4];
    const float* gcn_b = (const float*)d_in[5];
    const float* bn_g  = (const float*)d_in[6];
    const float* bn_be = (const float*)d_in[7];
    const float* bn_m  = (const float*)d_in[8];
    const float* bn_v  = (const float*)d_in[9];
    const float* c1_W  = (const float*)d_in[10];
    const float* c1_b  = (const float*)d_in[11];
    const float* c2_W  = (const float*)d_in[12];
    const float* c2_b  = (const float*)d_in[13];
    const float* c3_W  = (const float*)d_in[14];
    const float* c3_b  = (const float*)d_in[15];
    float* out = (float*)d_out;

    const int E = in_sizes[1] / 2;
    float* ws = (float*)d_ws;

    // ---- workspace layout ----
    float*  P   = ws;                 // 4 slices of NPH f32 (reused as h1,h2,hws)
    float*  h1  = P;
    float*  h2  = P + NPH;
    float*  hws = P + 2 * NPH;
    _Float16* hh  = (_Float16*)(P + 4 * NPH);
    _Float16* hl  = hh + NPH;
    _Float16* wi  = hl + NPH;         // 256x2048
    _Float16* gw  = wi + 524288;      // 768x256
    _Float16* c1w = gw + 196608;      // 128x256
    _Float16* c2w = c1w + 32768;      // 64x128
    _Float16* c3w = c2w + 8192;       // 16x64 (10 real rows)
    float*    dinv = (float*)(c3w + 1024);
    unsigned* cnt  = (unsigned*)(dinv + NN);
    unsigned* off  = cnt + NN;
    unsigned* cur  = off + NN + 1;
    unsigned* flag = cur + NN;
    int*      csr  = (int*)(flag + 4);

    // ---- graph prep + weight fp16 conversion (merged first launch) ----
    prep_split<<<3020, 256, 0, stream>>>(eidx, cnt, flag, in_W, gcn_W, c1_W, c2_W, c3_W,
                                         wi, gw, c1w, c2w, c3w);
    count_edges<<<(E + 255) / 256, 256, 0, stream>>>(eidx, flag, cnt, E);
    scan_dinv<<<1, 256, 0, stream>>>(cnt, off, cur, dinv, NN);
    fill_csr<<<(E + 255) / 256, 256, 0, stream>>>(eidx, flag, cur, csr, E);

    // ---- input projection ----
    inproj_gemm<<<dim3(NP / 64, 1, IPZ), 256, 0, stream>>>(x, wi, P);
    inproj_epi<<<(int)(NPH / 1024), 256, 0, stream>>>(P, in_b, hh, hl);

    // ---- 3 GCN layers ----
    for (int i = 0; i < 3; ++i) {
        gemm_layer<<<dim3(NP / 64, 4), 256, 0, stream>>>(
            hh, hl, gw + (size_t)i * 65536, dinv, hws);
        const float* res = (i == 0) ? nullptr : (i == 1 ? h1 : h2);
        float* hf = (i == 0) ? h1 : (i == 1 ? h2 : nullptr);
        gcn_aggregate<<<2504, 256, 0, stream>>>(
            hws, res, dinv, off, csr,
            gcn_b + i * HID, bn_g + i * HID, bn_be + i * HID,
            bn_m + i * HID, bn_v + i * HID, hf, hh, hl);
    }

    // ---- fused classifier ----
    classifier<<<NP / 32, 256, 0, stream>>>(hh, hl, c1w, c1_b,
                                            c2w, c2_b, c3w, c3_b, out);
}

// Round 13
// 253.700 us; speedup vs baseline: 1.7406x; 1.0940x over previous
//
#include <hip/hip_runtime.h>
#include <hip/hip_bf16.h>

#define NN   10000
#define NP   10048          // 157*64 padded rows
#define HID  256
#define BN_EPS 1e-5f
#define NPH  ((size_t)NP * 256)

typedef _Float16 f16x4 __attribute__((ext_vector_type(4)));
typedef _Float16 f16x8 __attribute__((ext_vector_type(8)));
typedef float    f32x4 __attribute__((ext_vector_type(4)));

__device__ __forceinline__ void gl_lds16(const void* gptr, void* lptr) {
    __builtin_amdgcn_global_load_lds(
        (const __attribute__((address_space(1))) void*)gptr,
        (__attribute__((address_space(3))) void*)lptr,
        16, 0, 0);
}

__device__ __forceinline__ f32x4 cvt4(const _Float16* p) {
    f16x4 t = *(const f16x4*)p;
    f32x4 r; r[0] = t[0]; r[1] = t[1]; r[2] = t[2]; r[3] = t[3];
    return r;
}

// ------------------------------------------------------------------
// Merged: cnt-zero + i64-layout detect (blocks 0..39) and weight fp16
// conversion (single plane per weight; blocks 40..3019).
__global__ void prep_split(const int* __restrict__ e, unsigned* __restrict__ cnt,
                           unsigned* __restrict__ flag,
                           const float* __restrict__ in_W, const float* __restrict__ gcn_W,
                           const float* __restrict__ c1_W, const float* __restrict__ c2_W,
                           const float* __restrict__ c3_W,
                           _Float16* __restrict__ wi, _Float16* __restrict__ gw,
                           _Float16* __restrict__ c1, _Float16* __restrict__ c2,
                           _Float16* __restrict__ c3) {
    if (blockIdx.x < 40) {
        int i = blockIdx.x * 256 + threadIdx.x;
        if (i < NN) cnt[i] = 0u;
        if (blockIdx.x == 0) {
            __shared__ int nz;
            if (threadIdx.x == 0) nz = 0;
            __syncthreads();
            if (e[2 * threadIdx.x + 1] != 0) nz = 1;
            __syncthreads();
            if (threadIdx.x == 0) *flag = (nz == 0) ? 1u : 0u;  // 1 => int64 layout
        }
        return;
    }
    int idx = (blockIdx.x - 40) * 256 + threadIdx.x;
    float v; _Float16* d; int o;
    if (idx < 524288)      { v = in_W[idx];          d = wi; o = idx; }
    else if (idx < 720896) { o = idx - 524288; v = gcn_W[o]; d = gw; }
    else if (idx < 753664) { o = idx - 720896; v = c1_W[o];  d = c1; }
    else if (idx < 761856) { o = idx - 753664; v = c2_W[o];  d = c2; }
    else                   { o = idx - 761856; int r = o >> 6, c = o & 63;
                             v = (r < 10) ? c3_W[r * 64 + c] : 0.0f; d = c3; }
    d[o] = (_Float16)v;
}

__device__ __forceinline__ int edge_val(const int* e, unsigned f, long idx) {
    return f ? e[2 * idx] : e[idx];
}

__global__ void count_edges(const int* __restrict__ e, const unsigned* __restrict__ flag,
                            unsigned* __restrict__ cnt, int E) {
    int i = blockIdx.x * blockDim.x + threadIdx.x;
    if (i >= E) return;
    unsigned f = *flag;
    atomicAdd(&cnt[edge_val(e, f, (long)E + i)], 1u);
}

// single block, 1024 threads
__global__ void scan_dinv(const unsigned* __restrict__ cnt, unsigned* __restrict__ off,
                          unsigned* __restrict__ cur, float* __restrict__ dinv, int n) {
    __shared__ unsigned partial[1024];
    int t = threadIdx.x;
    int chunk = (n + 1023) / 1024;
    int lo = t * chunk;
    int hi = lo + chunk; if (hi > n) hi = n; if (lo > n) lo = n;
    unsigned s = 0;
    for (int i = lo; i < hi; ++i) s += cnt[i];
    partial[t] = s;
    __syncthreads();
    for (int d = 1; d < 1024; d <<= 1) {
        unsigned v = (t >= d) ? partial[t - d] : 0u;
        __syncthreads();
        partial[t] += v;
        __syncthreads();
    }
    unsigned base = (t == 0) ? 0u : partial[t - 1];
    for (int i = lo; i < hi; ++i) {
        off[i] = base; cur[i] = base;
        dinv[i] = rsqrtf((float)cnt[i] + 1.0f);
        base += cnt[i];
    }
    if (t == 1023) off[n] = base;
}

__global__ void fill_csr(const int* __restrict__ e, const unsigned* __restrict__ flag,
                         unsigned* __restrict__ cur, int* __restrict__ csr_src, int E) {
    int i = blockIdx.x * blockDim.x + threadIdx.x;
    if (i >= E) return;
    unsigned f = *flag;
    int src = edge_val(e, f, (long)i);
    int dst = edge_val(e, f, (long)E + i);
    unsigned pos = atomicAdd(&cur[dst], 1u);
    csr_src[pos] = src;
}

// ------------------------------------------------------------------
// Input projection: BM=64 x BN=256, split-K=4, 2-phase pipelined, dbuf LDS.
// A(x) split fp16 hi/lo in-kernel (exact to 2^-22); B = single fp16 plane via
// global_load_lds. 2 MFMA passes/frag. LDS 48 KB -> 3 blk/CU.
#define IPZ 4
#define IPKC 512
__global__ __launch_bounds__(256) void inproj_gemm(
    const float* __restrict__ A,
    const _Float16* __restrict__ B,
    float* __restrict__ P)
{
    __shared__ __align__(16) _Float16 sAh[2][2048], sAl[2][2048];
    __shared__ __align__(16) _Float16 sB[2][8192];

    const int tid = threadIdx.x, wid = tid >> 6, lane = tid & 63;
    const int fr = lane & 15, fq = lane >> 4;
    const int bm = blockIdx.x * 64;
    const int kbase = blockIdx.z * IPKC;
    const int wn = wid * 64;

    f32x4 acc[4][4] = {};

    const int rs = tid >> 2, cq = tid & 3;
    const int gr = min(bm + rs, NN - 1);
    const float* aptr = A + (size_t)gr * 2048 + cq * 8;
    const int scA = rs * 32 + ((cq ^ ((rs >> 1) & 3)) << 3);
    const int brow_l = lane >> 2, bch = lane & 3;

    float av[8];
    int cur = 0;

    {   // prologue: stage tile 0
        float4 v0 = *(const float4*)(aptr + kbase);
        float4 v1 = *(const float4*)(aptr + kbase + 4);
        av[0]=v0.x; av[1]=v0.y; av[2]=v0.z; av[3]=v0.w;
        av[4]=v1.x; av[5]=v1.y; av[6]=v1.z; av[7]=v1.w;
#pragma unroll
        for (int j = 0; j < 4; ++j) {
            int slice = wid * 4 + j;
            int row = slice * 16 + brow_l;
            int lc = bch ^ ((row >> 1) & 3);
            gl_lds16(B + (size_t)row * 2048 + kbase + lc * 8, &sB[0][slice * 512]);
        }
        f16x8 hv, lv;
#pragma unroll
        for (int j = 0; j < 8; ++j) {
            _Float16 h = (_Float16)av[j];
            hv[j] = h; lv[j] = (_Float16)(av[j] - (float)h);
        }
        *(f16x8*)&sAh[0][scA] = hv;
        *(f16x8*)&sAl[0][scA] = lv;
    }
    __syncthreads();

    for (int kt = 0; kt < IPKC / 32; ++kt) {
        const bool more = (kt + 1) < IPKC / 32;
        const int nk = kbase + (kt + 1) * 32;
        if (more) {
            float4 v0 = *(const float4*)(aptr + nk);
            float4 v1 = *(const float4*)(aptr + nk + 4);
            av[0]=v0.x; av[1]=v0.y; av[2]=v0.z; av[3]=v0.w;
            av[4]=v1.x; av[5]=v1.y; av[6]=v1.z; av[7]=v1.w;
#pragma unroll
            for (int j = 0; j < 4; ++j) {
                int slice = wid * 4 + j;
                int row = slice * 16 + brow_l;
                int lc = bch ^ ((row >> 1) & 3);
                gl_lds16(B + (size_t)row * 2048 + nk + lc * 8, &sB[cur ^ 1][slice * 512]);
            }
        }
        f16x8 b[4];
#pragma unroll
        for (int ni = 0; ni < 4; ++ni) {
            int r = wn + ni * 16 + fr;
            b[ni] = *(const f16x8*)&sB[cur][r * 32 + ((fq ^ ((r >> 1) & 3)) << 3)];
        }
#pragma unroll
        for (int mi = 0; mi < 4; ++mi) {
            int r = mi * 16 + fr;
            int e = r * 32 + ((fq ^ ((r >> 1) & 3)) << 3);
            f16x8 ah = *(const f16x8*)&sAh[cur][e];
            f16x8 al = *(const f16x8*)&sAl[cur][e];
#pragma unroll
            for (int ni = 0; ni < 4; ++ni) {
                acc[mi][ni] = __builtin_amdgcn_mfma_f32_16x16x32_f16(ah, b[ni], acc[mi][ni], 0, 0, 0);
                acc[mi][ni] = __builtin_amdgcn_mfma_f32_16x16x32_f16(al, b[ni], acc[mi][ni], 0, 0, 0);
            }
        }
        if (more) {
            f16x8 hv, lv;
#pragma unroll
            for (int j = 0; j < 8; ++j) {
                _Float16 h = (_Float16)av[j];
                hv[j] = h; lv[j] = (_Float16)(av[j] - (float)h);
            }
            *(f16x8*)&sAh[cur ^ 1][scA] = hv;
            *(f16x8*)&sAl[cur ^ 1][scA] = lv;
        }
        __syncthreads();
        cur ^= 1;
    }

    float* Pz = P + (size_t)blockIdx.z * NPH;
#pragma unroll
    for (int mi = 0; mi < 4; ++mi) {
        int row0 = bm + mi * 16 + fq * 4;
#pragma unroll
        for (int ni = 0; ni < 4; ++ni) {
            int col = wn + ni * 16 + fr;
#pragma unroll
            for (int r = 0; r < 4; ++r)
                Pz[(size_t)(row0 + r) * 256 + col] = acc[mi][ni][r];
        }
    }
}

// reduce 4 partials + bias + relu -> fp16 hi/lo planes (zero pad rows)
__global__ void inproj_epi(const float* __restrict__ P, const float* __restrict__ b,
                           _Float16* __restrict__ hh, _Float16* __restrict__ hl) {
    int t = blockIdx.x * 256 + threadIdx.x;
    size_t idx = (size_t)t * 4;
    int row = (int)(idx >> 8), col = (int)(idx & 255);
    float v[4] = {0, 0, 0, 0};
    if (row < NN) {
        const float* p = P + idx;
        float4 a0 = *(const float4*)(p);
        float4 a1 = *(const float4*)(p + NPH);
        float4 a2 = *(const float4*)(p + 2 * NPH);
        float4 a3 = *(const float4*)(p + 3 * NPH);
        v[0] = fmaxf(a0.x + a1.x + a2.x + a3.x + b[col + 0], 0.0f);
        v[1] = fmaxf(a0.y + a1.y + a2.y + a3.y + b[col + 1], 0.0f);
        v[2] = fmaxf(a0.z + a1.z + a2.z + a3.z + b[col + 2], 0.0f);
        v[3] = fmaxf(a0.w + a1.w + a2.w + a3.w + b[col + 3], 0.0f);
    }
    f16x4 hv, lv;
#pragma unroll
    for (int j = 0; j < 4; ++j) {
        _Float16 h = (_Float16)v[j];
        hv[j] = h; lv[j] = (_Float16)(v[j] - (float)h);
    }
    *(f16x4*)&hh[idx] = hv;
    *(f16x4*)&hl[idx] = lv;
}

// ------------------------------------------------------------------
// Layer GEMM (K=256): no LDS, per-lane direct fragment loads.
// A = h fp16 hi/lo, B = single fp16 weight plane; 2 passes.
// Epilogue pre-scales by dinv[row] and emits hws as FP16 (halves gather BW).
__global__ __launch_bounds__(256) void gemm_layer(
    const _Float16* __restrict__ Ah, const _Float16* __restrict__ Al,
    const _Float16* __restrict__ Bw,
    const float* __restrict__ dinv, _Float16* __restrict__ Cw)
{
    const int tid = threadIdx.x, wid = tid >> 6, lane = tid & 63;
    const int fr = lane & 15, fq = lane >> 4;
    const int wr = wid >> 1, wc = wid & 1;
    const int bm = blockIdx.x * 64, bn = blockIdx.y * 64;

    f32x4 acc[2][2] = {};
    size_t ra[2], rb[2];
#pragma unroll
    for (int mi = 0; mi < 2; ++mi) ra[mi] = (size_t)(bm + wr * 32 + mi * 16 + fr) * 256 + fq * 8;
#pragma unroll
    for (int ni = 0; ni < 2; ++ni) rb[ni] = (size_t)(bn + wc * 32 + ni * 16 + fr) * 256 + fq * 8;

#pragma unroll
    for (int kt = 0; kt < 8; ++kt) {
        f16x8 ah[2], al[2], bw[2];
#pragma unroll
        for (int mi = 0; mi < 2; ++mi) {
            ah[mi] = *(const f16x8*)(Ah + ra[mi] + kt * 32);
            al[mi] = *(const f16x8*)(Al + ra[mi] + kt * 32);
        }
#pragma unroll
        for (int ni = 0; ni < 2; ++ni)
            bw[ni] = *(const f16x8*)(Bw + rb[ni] + kt * 32);
#pragma unroll
        for (int mi = 0; mi < 2; ++mi)
#pragma unroll
            for (int ni = 0; ni < 2; ++ni) {
                acc[mi][ni] = __builtin_amdgcn_mfma_f32_16x16x32_f16(ah[mi], bw[ni], acc[mi][ni], 0, 0, 0);
                acc[mi][ni] = __builtin_amdgcn_mfma_f32_16x16x32_f16(al[mi], bw[ni], acc[mi][ni], 0, 0, 0);
            }
    }

    float dv[2][4];
#pragma unroll
    for (int mi = 0; mi < 2; ++mi)
#pragma unroll
        for (int r = 0; r < 4; ++r) {
            int row = bm + wr * 32 + mi * 16 + fq * 4 + r;
            dv[mi][r] = (row < NN) ? dinv[row] : 0.0f;
        }

#pragma unroll
    for (int mi = 0; mi < 2; ++mi)
#pragma unroll
        for (int ni = 0; ni < 2; ++ni) {
            int col = bn + wc * 32 + ni * 16 + fr;
#pragma unroll
            for (int r = 0; r < 4; ++r) {
                int row = bm + wr * 32 + mi * 16 + fq * 4 + r;
                if (row < NN)
                    Cw[(size_t)row * 256 + col] = (_Float16)(acc[mi][ni][r] * dv[mi][r]);
            }
        }
}

// ------------------------------------------------------------------
// XCD-pinned, feature-chunked GCN aggregate (v5: fp16 gather, 8-way ILP).
// hws is fp16 (pre-scaled by dinv[src]); per-chunk working set = 10000*128B
// = 1.28 MB << 4 MB per-XCD L2. Accumulation in fp32.
__global__ __launch_bounds__(256) void gcn_aggregate(
    const _Float16* __restrict__ hws, const float* __restrict__ res,
    const float* __restrict__ dinv, const unsigned* __restrict__ off,
    const int* __restrict__ csr,
    const float* __restrict__ bias, const float* __restrict__ gamma,
    const float* __restrict__ beta, const float* __restrict__ mean,
    const float* __restrict__ var,
    float* __restrict__ hf, _Float16* __restrict__ hh, _Float16* __restrict__ hl)
{
    const int xcd = blockIdx.x & 7;
    const int chunk = xcd >> 1;                       // 0..3
    const int nb = (blockIdx.x >> 3) * 2 + (xcd & 1); // node-block 0..625
    if (nb >= 625) return;                            // 625*16 = 10000 exactly

    const int tid = threadIdx.x;
    const int g = tid >> 4;                           // node-in-block 0..15
    const int q = tid & 15;                           // feature lane 0..15
    const int node = nb * 16 + g;
    const int f = chunk * 64 + q * 4;
    const size_t rowb = (size_t)node * HID + f;

    const float dn = dinv[node];
    const unsigned j0 = off[node], j1 = off[node + 1];

    f32x4 a0 = cvt4(hws + rowb);                      // self term (pre-scaled)
    f32x4 a1 = {0.f,0.f,0.f,0.f}, a2 = {0.f,0.f,0.f,0.f}, a3 = {0.f,0.f,0.f,0.f};
    f32x4 a4 = {0.f,0.f,0.f,0.f}, a5 = {0.f,0.f,0.f,0.f};
    f32x4 a6 = {0.f,0.f,0.f,0.f}, a7 = {0.f,0.f,0.f,0.f};

    unsigned j = j0;
    for (; j + 8 <= j1; j += 8) {
        int s0 = csr[j + 0];
        int s1 = csr[j + 1];
        int s2 = csr[j + 2];
        int s3 = csr[j + 3];
        int s4 = csr[j + 4];
        int s5 = csr[j + 5];
        int s6 = csr[j + 6];
        int s7 = csr[j + 7];
        a0 += cvt4(hws + (size_t)s0 * HID + f);
        a1 += cvt4(hws + (size_t)s1 * HID + f);
        a2 += cvt4(hws + (size_t)s2 * HID + f);
        a3 += cvt4(hws + (size_t)s3 * HID + f);
        a4 += cvt4(hws + (size_t)s4 * HID + f);
        a5 += cvt4(hws + (size_t)s5 * HID + f);
        a6 += cvt4(hws + (size_t)s6 * HID + f);
        a7 += cvt4(hws + (size_t)s7 * HID + f);
    }
    for (; j + 4 <= j1; j += 4) {
        int s0 = csr[j + 0];
        int s1 = csr[j + 1];
        int s2 = csr[j + 2];
        int s3 = csr[j + 3];
        a1 += cvt4(hws + (size_t)s0 * HID + f);
        a2 += cvt4(hws + (size_t)s1 * HID + f);
        a3 += cvt4(hws + (size_t)s2 * HID + f);
        a4 += cvt4(hws + (size_t)s3 * HID + f);
    }
    for (; j < j1; ++j) {
        int s = csr[j];
        a5 += cvt4(hws + (size_t)s * HID + f);
    }
    f32x4 acc = ((a0 + a1) + (a2 + a3)) + ((a4 + a5) + (a6 + a7));

    f32x4 b4  = *(const f32x4*)(bias + f);
    f32x4 m4  = *(const f32x4*)(mean + f);
    f32x4 v4  = *(const f32x4*)(var + f);
    f32x4 g4  = *(const f32x4*)(gamma + f);
    f32x4 be4 = *(const f32x4*)(beta + f);
    f32x4 r4 = {0.0f, 0.0f, 0.0f, 0.0f};
    if (res) r4 = *(const f32x4*)(res + rowb);

    f32x4 o;
    f16x4 hv, lv;
#pragma unroll
    for (int jj = 0; jj < 4; ++jj) {
        float t = dn * acc[jj] + b4[jj];
        t = (t - m4[jj]) * rsqrtf(v4[jj] + BN_EPS) * g4[jj] + be4[jj];
        t = fmaxf(t, 0.0f);
        t += r4[jj];
        o[jj] = t;
        _Float16 h = (_Float16)t;
        hv[jj] = h; lv[jj] = (_Float16)(t - (float)h);
    }
    if (hf) *(f32x4*)(hf + rowb) = o;
    *(f16x4*)&hh[rowb] = hv;
    *(f16x4*)&hl[rowb] = lv;
}

// ------------------------------------------------------------------
// Fused classifier: 32-row tile, h -> O1(LDS) -> O2(LDS) -> logits.
__global__ __launch_bounds__(256) void classifier(
    const _Float16* __restrict__ Ah, const _Float16* __restrict__ Al,
    const _Float16* __restrict__ c1w, const float* __restrict__ b1,
    const _Float16* __restrict__ c2w, const float* __restrict__ b2,
    const _Float16* __restrict__ c3w, const float* __restrict__ b3,
    float* __restrict__ out)
{
    __shared__ __align__(16) float sO1[32][132];
    __shared__ __align__(16) float sO2[32][68];

    const int tid = threadIdx.x, wid = tid >> 6, lane = tid & 63;
    const int fr = lane & 15, fq = lane >> 4;
    const int bm = blockIdx.x * 32;

    // ---- stage 1: O1 = relu(h @ c1^T + b1)   M=32 N=128 K=256
    {
        f32x4 acc[2][2] = {};
        size_t ra[2], rb[2];
#pragma unroll
        for (int mi = 0; mi < 2; ++mi) ra[mi] = (size_t)(bm + mi * 16 + fr) * 256 + fq * 8;
#pragma unroll
        for (int ni = 0; ni < 2; ++ni) rb[ni] = (size_t)(wid * 32 + ni * 16 + fr) * 256 + fq * 8;
#pragma unroll
        for (int kt = 0; kt < 8; ++kt) {
            f16x8 ah[2], al[2], bw[2];
#pragma unroll
            for (int mi = 0; mi < 2; ++mi) {
                ah[mi] = *(const f16x8*)(Ah + ra[mi] + kt * 32);
                al[mi] = *(const f16x8*)(Al + ra[mi] + kt * 32);
            }
#pragma unroll
            for (int ni = 0; ni < 2; ++ni)
                bw[ni] = *(const f16x8*)(c1w + rb[ni] + kt * 32);
#pragma unroll
            for (int mi = 0; mi < 2; ++mi)
#pragma unroll
                for (int ni = 0; ni < 2; ++ni) {
                    acc[mi][ni] = __builtin_amdgcn_mfma_f32_16x16x32_f16(ah[mi], bw[ni], acc[mi][ni], 0, 0, 0);
                    acc[mi][ni] = __builtin_amdgcn_mfma_f32_16x16x32_f16(al[mi], bw[ni], acc[mi][ni], 0, 0, 0);
                }
        }
#pragma unroll
        for (int mi = 0; mi < 2; ++mi)
#pragma unroll
            for (int ni = 0; ni < 2; ++ni) {
                int col = wid * 32 + ni * 16 + fr;
                float bb = b1[col];
#pragma unroll
                for (int r = 0; r < 4; ++r)
                    sO1[mi * 16 + fq * 4 + r][col] = fmaxf(acc[mi][ni][r] + bb, 0.0f);
            }
    }
    __syncthreads();

    // ---- stage 2: O2 = relu(O1 @ c2^T + b2)   M=32 N=64 K=128
    {
        f32x4 acc[2] = {};
#pragma unroll
        for (int kt = 0; kt < 4; ++kt) {
            f16x8 ah[2], al[2];
#pragma unroll
            for (int mi = 0; mi < 2; ++mi) {
                const float* p = &sO1[mi * 16 + fr][kt * 32 + fq * 8];
                f32x4 v0 = *(const f32x4*)p;
                f32x4 v1 = *(const f32x4*)(p + 4);
                float vv[8] = {v0[0], v0[1], v0[2], v0[3], v1[0], v1[1], v1[2], v1[3]};
#pragma unroll
                for (int j = 0; j < 8; ++j) {
                    _Float16 h = (_Float16)vv[j];
                    ah[mi][j] = h; al[mi][j] = (_Float16)(vv[j] - (float)h);
                }
            }
            size_t rb = (size_t)(wid * 16 + fr) * 128 + kt * 32 + fq * 8;
            f16x8 bw = *(const f16x8*)(c2w + rb);
#pragma unroll
            for (int mi = 0; mi < 2; ++mi) {
                acc[mi] = __builtin_amdgcn_mfma_f32_16x16x32_f16(ah[mi], bw, acc[mi], 0, 0, 0);
                acc[mi] = __builtin_amdgcn_mfma_f32_16x16x32_f16(al[mi], bw, acc[mi], 0, 0, 0);
            }
        }
        int col = wid * 16 + fr;
        float bb = b2[col];
#pragma unroll
        for (int mi = 0; mi < 2; ++mi)
#pragma unroll
            for (int r = 0; r < 4; ++r)
                sO2[mi * 16 + fq * 4 + r][col] = fmaxf(acc[mi][r] + bb, 0.0f);
    }
    __syncthreads();

    // ---- stage 3: logits = O2 @ c3^T + b3
    if (wid < 2) {
        f32x4 acc = {};
#pragma unroll
        for (int kt = 0; kt < 2; ++kt) {
            const float* p = &sO2[wid * 16 + fr][kt * 32 + fq * 8];
            f32x4 v0 = *(const f32x4*)p;
            f32x4 v1 = *(const f32x4*)(p + 4);
            float vv[8] = {v0[0], v0[1], v0[2], v0[3], v1[0], v1[1], v1[2], v1[3]};
            f16x8 ah, al;
#pragma unroll
            for (int j = 0; j < 8; ++j) {
                _Float16 h = (_Float16)vv[j];
                ah[j] = h; al[j] = (_Float16)(vv[j] - (float)h);
            }
            size_t rb = (size_t)fr * 64 + kt * 32 + fq * 8;
            f16x8 bw = *(const f16x8*)(c3w + rb);
            acc = __builtin_amdgcn_mfma_f32_16x16x32_f16(ah, bw, acc, 0, 0, 0);
            acc = __builtin_amdgcn_mfma_f32_16x16x32_f16(al, bw, acc, 0, 0, 0);
        }
        if (fr < 10) {
            float bb = b3[fr];
#pragma unroll
            for (int r = 0; r < 4; ++r) {
                int row = bm + wid * 16 + fq * 4 + r;
                if (row < NN) out[(size_t)row * 10 + fr] = acc[r] + bb;
            }
        }
    }
}

// ------------------------------------------------------------------
extern "C" void kernel_launch(void* const* d_in, const int* in_sizes, int n_in,
                              void* d_out, int out_size, void* d_ws, size_t ws_size,
                              hipStream_t stream)
{
    const float* x     = (const float*)d_in[0];
    const int*   eidx  = (const int*)d_in[1];
    const float* in_W  = (const float*)d_in[2];
    const float* in_b  = (const float*)d_in[3];
    const float* gcn_W = (const float*)d_in[4];
    const float* gcn_b = (const float*)d_in[5];
    const float* bn_g  = (const float*)d_in[6];
    const float* bn_be = (const float*)d_in[7];
    const float* bn_m  = (const float*)d_in[8];
    const float* bn_v  = (const float*)d_in[9];
    const float* c1_W  = (const float*)d_in[10];
    const float* c1_b  = (const float*)d_in[11];
    const float* c2_W  = (const float*)d_in[12];
    const float* c2_b  = (const float*)d_in[13];
    const float* c3_W  = (const float*)d_in[14];
    const float* c3_b  = (const float*)d_in[15];
    float* out = (float*)d_out;

    const int E = in_sizes[1] / 2;
    float* ws = (float*)d_ws;

    // ---- workspace layout ----
    float*  P   = ws;                 // 4 slices of NPH f32 (reused as h1,h2)
    float*  h1  = P;
    float*  h2  = P + NPH;
    _Float16* hws = (_Float16*)(P + 2 * NPH);   // NPH fp16 (gather table)
    _Float16* hh  = (_Float16*)(P + 4 * NPH);
    _Float16* hl  = hh + NPH;
    _Float16* wi  = hl + NPH;         // 256x2048
    _Float16* gw  = wi + 524288;      // 768x256
    _Float16* c1w = gw + 196608;      // 128x256
    _Float16* c2w = c1w + 32768;      // 64x128
    _Float16* c3w = c2w + 8192;       // 16x64 (10 real rows)
    float*    dinv = (float*)(c3w + 1024);
    unsigned* cnt  = (unsigned*)(dinv + NN);
    unsigned* off  = cnt + NN;
    unsigned* cur  = off + NN + 1;
    unsigned* flag = cur + NN;
    int*      csr  = (int*)(flag + 4);

    // ---- graph prep + weight fp16 conversion (merged first launch) ----
    prep_split<<<3020, 256, 0, stream>>>(eidx, cnt, flag, in_W, gcn_W, c1_W, c2_W, c3_W,
                                         wi, gw, c1w, c2w, c3w);
    count_edges<<<(E + 255) / 256, 256, 0, stream>>>(eidx, flag, cnt, E);
    scan_dinv<<<1, 1024, 0, stream>>>(cnt, off, cur, dinv, NN);
    fill_csr<<<(E + 255) / 256, 256, 0, stream>>>(eidx, flag, cur, csr, E);

    // ---- input projection ----
    inproj_gemm<<<dim3(NP / 64, 1, IPZ), 256, 0, stream>>>(x, wi, P);
    inproj_epi<<<(int)(NPH / 1024), 256, 0, stream>>>(P, in_b, hh, hl);

    // ---- 3 GCN layers ----
    for (int i = 0; i < 3; ++i) {
        gemm_layer<<<dim3(NP / 64, 4), 256, 0, stream>>>(
            hh, hl, gw + (size_t)i * 65536, dinv, hws);
        const float* res = (i == 0) ? nullptr : (i == 1 ? h1 : h2);
        float* hf = (i == 0) ? h1 : (i == 1 ? h2 : nullptr);
        gcn_aggregate<<<2504, 256, 0, stream>>>(
            hws, res, dinv, off, csr,
            gcn_b + i * HID, bn_g + i * HID, bn_be + i * HID,
            bn_m + i * HID, bn_v + i * HID, hf, hh, hl);
    }

    // ---- fused classifier ----
    classifier<<<NP / 32, 256, 0, stream>>>(hh, hl, c1w, c1_b,
                                            c2w, c2_b, c3w, c3_b, out);
}

// Round 14
// 248.419 us; speedup vs baseline: 1.7776x; 1.0213x over previous
//
#include <hip/hip_runtime.h>
#include <hip/hip_bf16.h>

#define NN   10000
#define NP   10048          // 157*64 padded rows
#define HID  256
#define BN_EPS 1e-5f
#define NPH  ((size_t)NP * 256)

typedef _Float16 f16x4 __attribute__((ext_vector_type(4)));
typedef _Float16 f16x8 __attribute__((ext_vector_type(8)));
typedef float    f32x4 __attribute__((ext_vector_type(4)));

__device__ __forceinline__ void gl_lds16(const void* gptr, void* lptr) {
    __builtin_amdgcn_global_load_lds(
        (const __attribute__((address_space(1))) void*)gptr,
        (__attribute__((address_space(3))) void*)lptr,
        16, 0, 0);
}

__device__ __forceinline__ f32x4 cvt4(const _Float16* p) {
    f16x4 t = *(const f16x4*)p;
    f32x4 r; r[0] = t[0]; r[1] = t[1]; r[2] = t[2]; r[3] = t[3];
    return r;
}

// ------------------------------------------------------------------
// Merged: cnt-zero + i64-layout detect (blocks 0..39) and weight fp16
// conversion (single plane per weight; blocks 40..3019).
__global__ void prep_split(const int* __restrict__ e, unsigned* __restrict__ cnt,
                           unsigned* __restrict__ flag,
                           const float* __restrict__ in_W, const float* __restrict__ gcn_W,
                           const float* __restrict__ c1_W, const float* __restrict__ c2_W,
                           const float* __restrict__ c3_W,
                           _Float16* __restrict__ wi, _Float16* __restrict__ gw,
                           _Float16* __restrict__ c1, _Float16* __restrict__ c2,
                           _Float16* __restrict__ c3) {
    if (blockIdx.x < 40) {
        int i = blockIdx.x * 256 + threadIdx.x;
        if (i < NN) cnt[i] = 0u;
        if (blockIdx.x == 0) {
            __shared__ int nz;
            if (threadIdx.x == 0) nz = 0;
            __syncthreads();
            if (e[2 * threadIdx.x + 1] != 0) nz = 1;
            __syncthreads();
            if (threadIdx.x == 0) *flag = (nz == 0) ? 1u : 0u;  // 1 => int64 layout
        }
        return;
    }
    int idx = (blockIdx.x - 40) * 256 + threadIdx.x;
    float v; _Float16* d; int o;
    if (idx < 524288)      { v = in_W[idx];          d = wi; o = idx; }
    else if (idx < 720896) { o = idx - 524288; v = gcn_W[o]; d = gw; }
    else if (idx < 753664) { o = idx - 720896; v = c1_W[o];  d = c1; }
    else if (idx < 761856) { o = idx - 753664; v = c2_W[o];  d = c2; }
    else                   { o = idx - 761856; int r = o >> 6, c = o & 63;
                             v = (r < 10) ? c3_W[r * 64 + c] : 0.0f; d = c3; }
    d[o] = (_Float16)v;
}

__device__ __forceinline__ int edge_val(const int* e, unsigned f, long idx) {
    return f ? e[2 * idx] : e[idx];
}

__global__ void count_edges(const int* __restrict__ e, const unsigned* __restrict__ flag,
                            unsigned* __restrict__ cnt, int E) {
    int i = blockIdx.x * blockDim.x + threadIdx.x;
    if (i >= E) return;
    unsigned f = *flag;
    atomicAdd(&cnt[edge_val(e, f, (long)E + i)], 1u);
}

// single block, 1024 threads
__global__ void scan_dinv(const unsigned* __restrict__ cnt, unsigned* __restrict__ off,
                          unsigned* __restrict__ cur, float* __restrict__ dinv, int n) {
    __shared__ unsigned partial[1024];
    int t = threadIdx.x;
    int chunk = (n + 1023) / 1024;
    int lo = t * chunk;
    int hi = lo + chunk; if (hi > n) hi = n; if (lo > n) lo = n;
    unsigned s = 0;
    for (int i = lo; i < hi; ++i) s += cnt[i];
    partial[t] = s;
    __syncthreads();
    for (int d = 1; d < 1024; d <<= 1) {
        unsigned v = (t >= d) ? partial[t - d] : 0u;
        __syncthreads();
        partial[t] += v;
        __syncthreads();
    }
    unsigned base = (t == 0) ? 0u : partial[t - 1];
    for (int i = lo; i < hi; ++i) {
        off[i] = base; cur[i] = base;
        dinv[i] = rsqrtf((float)cnt[i] + 1.0f);
        base += cnt[i];
    }
    if (t == 1023) off[n] = base;
}

__global__ void fill_csr(const int* __restrict__ e, const unsigned* __restrict__ flag,
                         unsigned* __restrict__ cur, int* __restrict__ csr_src, int E) {
    int i = blockIdx.x * blockDim.x + threadIdx.x;
    if (i >= E) return;
    unsigned f = *flag;
    int src = edge_val(e, f, (long)i);
    int dst = edge_val(e, f, (long)E + i);
    unsigned pos = atomicAdd(&cur[dst], 1u);
    csr_src[pos] = src;
}

// ------------------------------------------------------------------
// Input projection: BM=64 x BN=256, split-K=4, 2-phase pipelined, dbuf LDS.
// A(x) split fp16 hi/lo in-kernel; B = single fp16 plane via global_load_lds.
// 2 MFMA passes/frag. LDS 48 KB -> 3 blk/CU.
#define IPZ 4
#define IPKC 512
__global__ __launch_bounds__(256) void inproj_gemm(
    const float* __restrict__ A,
    const _Float16* __restrict__ B,
    float* __restrict__ P)
{
    __shared__ __align__(16) _Float16 sAh[2][2048], sAl[2][2048];
    __shared__ __align__(16) _Float16 sB[2][8192];

    const int tid = threadIdx.x, wid = tid >> 6, lane = tid & 63;
    const int fr = lane & 15, fq = lane >> 4;
    const int bm = blockIdx.x * 64;
    const int kbase = blockIdx.z * IPKC;
    const int wn = wid * 64;

    f32x4 acc[4][4] = {};

    const int rs = tid >> 2, cq = tid & 3;
    const int gr = min(bm + rs, NN - 1);
    const float* aptr = A + (size_t)gr * 2048 + cq * 8;
    const int scA = rs * 32 + ((cq ^ ((rs >> 1) & 3)) << 3);
    const int brow_l = lane >> 2, bch = lane & 3;

    float av[8];
    int cur = 0;

    {   // prologue: stage tile 0
        float4 v0 = *(const float4*)(aptr + kbase);
        float4 v1 = *(const float4*)(aptr + kbase + 4);
        av[0]=v0.x; av[1]=v0.y; av[2]=v0.z; av[3]=v0.w;
        av[4]=v1.x; av[5]=v1.y; av[6]=v1.z; av[7]=v1.w;
#pragma unroll
        for (int j = 0; j < 4; ++j) {
            int slice = wid * 4 + j;
            int row = slice * 16 + brow_l;
            int lc = bch ^ ((row >> 1) & 3);
            gl_lds16(B + (size_t)row * 2048 + kbase + lc * 8, &sB[0][slice * 512]);
        }
        f16x8 hv, lv;
#pragma unroll
        for (int j = 0; j < 8; ++j) {
            _Float16 h = (_Float16)av[j];
            hv[j] = h; lv[j] = (_Float16)(av[j] - (float)h);
        }
        *(f16x8*)&sAh[0][scA] = hv;
        *(f16x8*)&sAl[0][scA] = lv;
    }
    __syncthreads();

    for (int kt = 0; kt < IPKC / 32; ++kt) {
        const bool more = (kt + 1) < IPKC / 32;
        const int nk = kbase + (kt + 1) * 32;
        if (more) {
            float4 v0 = *(const float4*)(aptr + nk);
            float4 v1 = *(const float4*)(aptr + nk + 4);
            av[0]=v0.x; av[1]=v0.y; av[2]=v0.z; av[3]=v0.w;
            av[4]=v1.x; av[5]=v1.y; av[6]=v1.z; av[7]=v1.w;
#pragma unroll
            for (int j = 0; j < 4; ++j) {
                int slice = wid * 4 + j;
                int row = slice * 16 + brow_l;
                int lc = bch ^ ((row >> 1) & 3);
                gl_lds16(B + (size_t)row * 2048 + nk + lc * 8, &sB[cur ^ 1][slice * 512]);
            }
        }
        f16x8 b[4];
#pragma unroll
        for (int ni = 0; ni < 4; ++ni) {
            int r = wn + ni * 16 + fr;
            b[ni] = *(const f16x8*)&sB[cur][r * 32 + ((fq ^ ((r >> 1) & 3)) << 3)];
        }
#pragma unroll
        for (int mi = 0; mi < 4; ++mi) {
            int r = mi * 16 + fr;
            int e = r * 32 + ((fq ^ ((r >> 1) & 3)) << 3);
            f16x8 ah = *(const f16x8*)&sAh[cur][e];
            f16x8 al = *(const f16x8*)&sAl[cur][e];
#pragma unroll
            for (int ni = 0; ni < 4; ++ni) {
                acc[mi][ni] = __builtin_amdgcn_mfma_f32_16x16x32_f16(ah, b[ni], acc[mi][ni], 0, 0, 0);
                acc[mi][ni] = __builtin_amdgcn_mfma_f32_16x16x32_f16(al, b[ni], acc[mi][ni], 0, 0, 0);
            }
        }
        if (more) {
            f16x8 hv, lv;
#pragma unroll
            for (int j = 0; j < 8; ++j) {
                _Float16 h = (_Float16)av[j];
                hv[j] = h; lv[j] = (_Float16)(av[j] - (float)h);
            }
            *(f16x8*)&sAh[cur ^ 1][scA] = hv;
            *(f16x8*)&sAl[cur ^ 1][scA] = lv;
        }
        __syncthreads();
        cur ^= 1;
    }

    float* Pz = P + (size_t)blockIdx.z * NPH;
#pragma unroll
    for (int mi = 0; mi < 4; ++mi) {
        int row0 = bm + mi * 16 + fq * 4;
#pragma unroll
        for (int ni = 0; ni < 4; ++ni) {
            int col = wn + ni * 16 + fr;
#pragma unroll
            for (int r = 0; r < 4; ++r)
                Pz[(size_t)(row0 + r) * 256 + col] = acc[mi][ni][r];
        }
    }
}

// reduce 4 partials + bias + relu -> fp16 hi/lo planes (zero pad rows)
__global__ void inproj_epi(const float* __restrict__ P, const float* __restrict__ b,
                           _Float16* __restrict__ hh, _Float16* __restrict__ hl) {
    int t = blockIdx.x * 256 + threadIdx.x;
    size_t idx = (size_t)t * 4;
    int row = (int)(idx >> 8), col = (int)(idx & 255);
    float v[4] = {0, 0, 0, 0};
    if (row < NN) {
        const float* p = P + idx;
        float4 a0 = *(const float4*)(p);
        float4 a1 = *(const float4*)(p + NPH);
        float4 a2 = *(const float4*)(p + 2 * NPH);
        float4 a3 = *(const float4*)(p + 3 * NPH);
        v[0] = fmaxf(a0.x + a1.x + a2.x + a3.x + b[col + 0], 0.0f);
        v[1] = fmaxf(a0.y + a1.y + a2.y + a3.y + b[col + 1], 0.0f);
        v[2] = fmaxf(a0.z + a1.z + a2.z + a3.z + b[col + 2], 0.0f);
        v[3] = fmaxf(a0.w + a1.w + a2.w + a3.w + b[col + 3], 0.0f);
    }
    f16x4 hv, lv;
#pragma unroll
    for (int j = 0; j < 4; ++j) {
        _Float16 h = (_Float16)v[j];
        hv[j] = h; lv[j] = (_Float16)(v[j] - (float)h);
    }
    *(f16x4*)&hh[idx] = hv;
    *(f16x4*)&hl[idx] = lv;
}

// ------------------------------------------------------------------
// Layer GEMM (K=256): no LDS, per-lane direct fragment loads.
// A = h fp16 hi/lo, B = single fp16 weight plane; 2 passes.
// Epilogue pre-scales by dinv[row] and emits hws as FP16.
__global__ __launch_bounds__(256) void gemm_layer(
    const _Float16* __restrict__ Ah, const _Float16* __restrict__ Al,
    const _Float16* __restrict__ Bw,
    const float* __restrict__ dinv, _Float16* __restrict__ Cw)
{
    const int tid = threadIdx.x, wid = tid >> 6, lane = tid & 63;
    const int fr = lane & 15, fq = lane >> 4;
    const int wr = wid >> 1, wc = wid & 1;
    const int bm = blockIdx.x * 64, bn = blockIdx.y * 64;

    f32x4 acc[2][2] = {};
    size_t ra[2], rb[2];
#pragma unroll
    for (int mi = 0; mi < 2; ++mi) ra[mi] = (size_t)(bm + wr * 32 + mi * 16 + fr) * 256 + fq * 8;
#pragma unroll
    for (int ni = 0; ni < 2; ++ni) rb[ni] = (size_t)(bn + wc * 32 + ni * 16 + fr) * 256 + fq * 8;

#pragma unroll
    for (int kt = 0; kt < 8; ++kt) {
        f16x8 ah[2], al[2], bw[2];
#pragma unroll
        for (int mi = 0; mi < 2; ++mi) {
            ah[mi] = *(const f16x8*)(Ah + ra[mi] + kt * 32);
            al[mi] = *(const f16x8*)(Al + ra[mi] + kt * 32);
        }
#pragma unroll
        for (int ni = 0; ni < 2; ++ni)
            bw[ni] = *(const f16x8*)(Bw + rb[ni] + kt * 32);
#pragma unroll
        for (int mi = 0; mi < 2; ++mi)
#pragma unroll
            for (int ni = 0; ni < 2; ++ni) {
                acc[mi][ni] = __builtin_amdgcn_mfma_f32_16x16x32_f16(ah[mi], bw[ni], acc[mi][ni], 0, 0, 0);
                acc[mi][ni] = __builtin_amdgcn_mfma_f32_16x16x32_f16(al[mi], bw[ni], acc[mi][ni], 0, 0, 0);
            }
    }

    float dv[2][4];
#pragma unroll
    for (int mi = 0; mi < 2; ++mi)
#pragma unroll
        for (int r = 0; r < 4; ++r) {
            int row = bm + wr * 32 + mi * 16 + fq * 4 + r;
            dv[mi][r] = (row < NN) ? dinv[row] : 0.0f;
        }

#pragma unroll
    for (int mi = 0; mi < 2; ++mi)
#pragma unroll
        for (int ni = 0; ni < 2; ++ni) {
            int col = bn + wc * 32 + ni * 16 + fr;
#pragma unroll
            for (int r = 0; r < 4; ++r) {
                int row = bm + wr * 32 + mi * 16 + fq * 4 + r;
                if (row < NN)
                    Cw[(size_t)row * 256 + col] = (_Float16)(acc[mi][ni][r] * dv[mi][r]);
            }
        }
}

// ------------------------------------------------------------------
// GCN aggregate v6: full-row, wave-per-node. 64 lanes x f16x4 = whole 512 B
// fp16 row in one coalesced request. No chunking, no XCD heuristic, csr read
// once per edge. 8 independent accumulators for MLP; fp32 accumulation.
__global__ __launch_bounds__(256) void gcn_aggregate(
    const _Float16* __restrict__ hws, const float* __restrict__ res,
    const float* __restrict__ dinv, const unsigned* __restrict__ off,
    const int* __restrict__ csr,
    const float* __restrict__ bias, const float* __restrict__ gamma,
    const float* __restrict__ beta, const float* __restrict__ mean,
    const float* __restrict__ var,
    float* __restrict__ hf, _Float16* __restrict__ hh, _Float16* __restrict__ hl)
{
    const int wid = threadIdx.x >> 6, l = threadIdx.x & 63;
    const int node = blockIdx.x * 4 + wid;            // grid = 2500 blocks
    const int f = l << 2;                             // 0..252
    const size_t rowb = (size_t)node * HID + f;

    const float dn = dinv[node];
    const unsigned j0 = off[node], j1 = off[node + 1];

    f32x4 a0 = cvt4(hws + rowb);                      // self term (pre-scaled)
    f32x4 a1 = {0.f,0.f,0.f,0.f}, a2 = {0.f,0.f,0.f,0.f}, a3 = {0.f,0.f,0.f,0.f};
    f32x4 a4 = {0.f,0.f,0.f,0.f}, a5 = {0.f,0.f,0.f,0.f};
    f32x4 a6 = {0.f,0.f,0.f,0.f}, a7 = {0.f,0.f,0.f,0.f};

    unsigned j = j0;
    for (; j + 8 <= j1; j += 8) {
        int s0 = csr[j + 0];
        int s1 = csr[j + 1];
        int s2 = csr[j + 2];
        int s3 = csr[j + 3];
        int s4 = csr[j + 4];
        int s5 = csr[j + 5];
        int s6 = csr[j + 6];
        int s7 = csr[j + 7];
        a0 += cvt4(hws + (size_t)s0 * HID + f);
        a1 += cvt4(hws + (size_t)s1 * HID + f);
        a2 += cvt4(hws + (size_t)s2 * HID + f);
        a3 += cvt4(hws + (size_t)s3 * HID + f);
        a4 += cvt4(hws + (size_t)s4 * HID + f);
        a5 += cvt4(hws + (size_t)s5 * HID + f);
        a6 += cvt4(hws + (size_t)s6 * HID + f);
        a7 += cvt4(hws + (size_t)s7 * HID + f);
    }
    for (; j + 4 <= j1; j += 4) {
        int s0 = csr[j + 0];
        int s1 = csr[j + 1];
        int s2 = csr[j + 2];
        int s3 = csr[j + 3];
        a1 += cvt4(hws + (size_t)s0 * HID + f);
        a2 += cvt4(hws + (size_t)s1 * HID + f);
        a3 += cvt4(hws + (size_t)s2 * HID + f);
        a4 += cvt4(hws + (size_t)s3 * HID + f);
    }
    for (; j < j1; ++j) {
        int s = csr[j];
        a5 += cvt4(hws + (size_t)s * HID + f);
    }
    f32x4 acc = ((a0 + a1) + (a2 + a3)) + ((a4 + a5) + (a6 + a7));

    f32x4 b4  = *(const f32x4*)(bias + f);
    f32x4 m4  = *(const f32x4*)(mean + f);
    f32x4 v4  = *(const f32x4*)(var + f);
    f32x4 g4  = *(const f32x4*)(gamma + f);
    f32x4 be4 = *(const f32x4*)(beta + f);
    f32x4 r4 = {0.0f, 0.0f, 0.0f, 0.0f};
    if (res) r4 = *(const f32x4*)(res + rowb);

    f32x4 o;
    f16x4 hv, lv;
#pragma unroll
    for (int jj = 0; jj < 4; ++jj) {
        float t = dn * acc[jj] + b4[jj];
        t = (t - m4[jj]) * rsqrtf(v4[jj] + BN_EPS) * g4[jj] + be4[jj];
        t = fmaxf(t, 0.0f);
        t += r4[jj];
        o[jj] = t;
        _Float16 h = (_Float16)t;
        hv[jj] = h; lv[jj] = (_Float16)(t - (float)h);
    }
    if (hf) *(f32x4*)(hf + rowb) = o;
    *(f16x4*)&hh[rowb] = hv;
    *(f16x4*)&hl[rowb] = lv;
}

// ------------------------------------------------------------------
// Fused classifier: 32-row tile, h -> O1(LDS) -> O2(LDS) -> logits.
__global__ __launch_bounds__(256) void classifier(
    const _Float16* __restrict__ Ah, const _Float16* __restrict__ Al,
    const _Float16* __restrict__ c1w, const float* __restrict__ b1,
    const _Float16* __restrict__ c2w, const float* __restrict__ b2,
    const _Float16* __restrict__ c3w, const float* __restrict__ b3,
    float* __restrict__ out)
{
    __shared__ __align__(16) float sO1[32][132];
    __shared__ __align__(16) float sO2[32][68];

    const int tid = threadIdx.x, wid = tid >> 6, lane = tid & 63;
    const int fr = lane & 15, fq = lane >> 4;
    const int bm = blockIdx.x * 32;

    // ---- stage 1: O1 = relu(h @ c1^T + b1)   M=32 N=128 K=256
    {
        f32x4 acc[2][2] = {};
        size_t ra[2], rb[2];
#pragma unroll
        for (int mi = 0; mi < 2; ++mi) ra[mi] = (size_t)(bm + mi * 16 + fr) * 256 + fq * 8;
#pragma unroll
        for (int ni = 0; ni < 2; ++ni) rb[ni] = (size_t)(wid * 32 + ni * 16 + fr) * 256 + fq * 8;
#pragma unroll
        for (int kt = 0; kt < 8; ++kt) {
            f16x8 ah[2], al[2], bw[2];
#pragma unroll
            for (int mi = 0; mi < 2; ++mi) {
                ah[mi] = *(const f16x8*)(Ah + ra[mi] + kt * 32);
                al[mi] = *(const f16x8*)(Al + ra[mi] + kt * 32);
            }
#pragma unroll
            for (int ni = 0; ni < 2; ++ni)
                bw[ni] = *(const f16x8*)(c1w + rb[ni] + kt * 32);
#pragma unroll
            for (int mi = 0; mi < 2; ++mi)
#pragma unroll
                for (int ni = 0; ni < 2; ++ni) {
                    acc[mi][ni] = __builtin_amdgcn_mfma_f32_16x16x32_f16(ah[mi], bw[ni], acc[mi][ni], 0, 0, 0);
                    acc[mi][ni] = __builtin_amdgcn_mfma_f32_16x16x32_f16(al[mi], bw[ni], acc[mi][ni], 0, 0, 0);
                }
        }
#pragma unroll
        for (int mi = 0; mi < 2; ++mi)
#pragma unroll
            for (int ni = 0; ni < 2; ++ni) {
                int col = wid * 32 + ni * 16 + fr;
                float bb = b1[col];
#pragma unroll
                for (int r = 0; r < 4; ++r)
                    sO1[mi * 16 + fq * 4 + r][col] = fmaxf(acc[mi][ni][r] + bb, 0.0f);
            }
    }
    __syncthreads();

    // ---- stage 2: O2 = relu(O1 @ c2^T + b2)   M=32 N=64 K=128
    {
        f32x4 acc[2] = {};
#pragma unroll
        for (int kt = 0; kt < 4; ++kt) {
            f16x8 ah[2], al[2];
#pragma unroll
            for (int mi = 0; mi < 2; ++mi) {
                const float* p = &sO1[mi * 16 + fr][kt * 32 + fq * 8];
                f32x4 v0 = *(const f32x4*)p;
                f32x4 v1 = *(const f32x4*)(p + 4);
                float vv[8] = {v0[0], v0[1], v0[2], v0[3], v1[0], v1[1], v1[2], v1[3]};
#pragma unroll
                for (int j = 0; j < 8; ++j) {
                    _Float16 h = (_Float16)vv[j];
                    ah[mi][j] = h; al[mi][j] = (_Float16)(vv[j] - (float)h);
                }
            }
            size_t rb = (size_t)(wid * 16 + fr) * 128 + kt * 32 + fq * 8;
            f16x8 bw = *(const f16x8*)(c2w + rb);
#pragma unroll
            for (int mi = 0; mi < 2; ++mi) {
                acc[mi] = __builtin_amdgcn_mfma_f32_16x16x32_f16(ah[mi], bw, acc[mi], 0, 0, 0);
                acc[mi] = __builtin_amdgcn_mfma_f32_16x16x32_f16(al[mi], bw, acc[mi], 0, 0, 0);
            }
        }
        int col = wid * 16 + fr;
        float bb = b2[col];
#pragma unroll
        for (int mi = 0; mi < 2; ++mi)
#pragma unroll
            for (int r = 0; r < 4; ++r)
                sO2[mi * 16 + fq * 4 + r][col] = fmaxf(acc[mi][r] + bb, 0.0f);
    }
    __syncthreads();

    // ---- stage 3: logits = O2 @ c3^T + b3
    if (wid < 2) {
        f32x4 acc = {};
#pragma unroll
        for (int kt = 0; kt < 2; ++kt) {
            const float* p = &sO2[wid * 16 + fr][kt * 32 + fq * 8];
            f32x4 v0 = *(const f32x4*)p;
            f32x4 v1 = *(const f32x4*)(p + 4);
            float vv[8] = {v0[0], v0[1], v0[2], v0[3], v1[0], v1[1], v1[2], v1[3]};
            f16x8 ah, al;
#pragma unroll
            for (int j = 0; j < 8; ++j) {
                _Float16 h = (_Float16)vv[j];
                ah[j] = h; al[j] = (_Float16)(vv[j] - (float)h);
            }
            size_t rb = (size_t)fr * 64 + kt * 32 + fq * 8;
            f16x8 bw = *(const f16x8*)(c3w + rb);
            acc = __builtin_amdgcn_mfma_f32_16x16x32_f16(ah, bw, acc, 0, 0, 0);
            acc = __builtin_amdgcn_mfma_f32_16x16x32_f16(al, bw, acc, 0, 0, 0);
        }
        if (fr < 10) {
            float bb = b3[fr];
#pragma unroll
            for (int r = 0; r < 4; ++r) {
                int row = bm + wid * 16 + fq * 4 + r;
                if (row < NN) out[(size_t)row * 10 + fr] = acc[r] + bb;
            }
        }
    }
}

// ------------------------------------------------------------------
extern "C" void kernel_launch(void* const* d_in, const int* in_sizes, int n_in,
                              void* d_out, int out_size, void* d_ws, size_t ws_size,
                              hipStream_t stream)
{
    const float* x     = (const float*)d_in[0];
    const int*   eidx  = (const int*)d_in[1];
    const float* in_W  = (const float*)d_in[2];
    const float* in_b  = (const float*)d_in[3];
    const float* gcn_W = (const float*)d_in[4];
    const float* gcn_b = (const float*)d_in[5];
    const float* bn_g  = (const float*)d_in[6];
    const float* bn_be = (const float*)d_in[7];
    const float* bn_m  = (const float*)d_in[8];
    const float* bn_v  = (const float*)d_in[9];
    const float* c1_W  = (const float*)d_in[10];
    const float* c1_b  = (const float*)d_in[11];
    const float* c2_W  = (const float*)d_in[12];
    const float* c2_b  = (const float*)d_in[13];
    const float* c3_W  = (const float*)d_in[14];
    const float* c3_b  = (const float*)d_in[15];
    float* out = (float*)d_out;

    const int E = in_sizes[1] / 2;
    float* ws = (float*)d_ws;

    // ---- workspace layout ----
    float*  P   = ws;                 // 4 slices of NPH f32 (reused as h1,h2)
    float*  h1  = P;
    float*  h2  = P + NPH;
    _Float16* hws = (_Float16*)(P + 2 * NPH);   // NPH fp16 (gather table)
    _Float16* hh  = (_Float16*)(P + 4 * NPH);
    _Float16* hl  = hh + NPH;
    _Float16* wi  = hl + NPH;         // 256x2048
    _Float16* gw  = wi + 524288;      // 768x256
    _Float16* c1w = gw + 196608;      // 128x256
    _Float16* c2w = c1w + 32768;      // 64x128
    _Float16* c3w = c2w + 8192;       // 16x64 (10 real rows)
    float*    dinv = (float*)(c3w + 1024);
    unsigned* cnt  = (unsigned*)(dinv + NN);
    unsigned* off  = cnt + NN;
    unsigned* cur  = off + NN + 1;
    unsigned* flag = cur + NN;
    int*      csr  = (int*)(flag + 4);

    // ---- graph prep + weight fp16 conversion (merged first launch) ----
    prep_split<<<3020, 256, 0, stream>>>(eidx, cnt, flag, in_W, gcn_W, c1_W, c2_W, c3_W,
                                         wi, gw, c1w, c2w, c3w);
    count_edges<<<(E + 255) / 256, 256, 0, stream>>>(eidx, flag, cnt, E);
    scan_dinv<<<1, 1024, 0, stream>>>(cnt, off, cur, dinv, NN);
    fill_csr<<<(E + 255) / 256, 256, 0, stream>>>(eidx, flag, cur, csr, E);

    // ---- input projection ----
    inproj_gemm<<<dim3(NP / 64, 1, IPZ), 256, 0, stream>>>(x, wi, P);
    inproj_epi<<<(int)(NPH / 1024), 256, 0, stream>>>(P, in_b, hh, hl);

    // ---- 3 GCN layers ----
    for (int i = 0; i < 3; ++i) {
        gemm_layer<<<dim3(NP / 64, 4), 256, 0, stream>>>(
            hh, hl, gw + (size_t)i * 65536, dinv, hws);
        const float* res = (i == 0) ? nullptr : (i == 1 ? h1 : h2);
        float* hf = (i == 0) ? h1 : (i == 1 ? h2 : nullptr);
        gcn_aggregate<<<NN / 4, 256, 0, stream>>>(
            hws, res, dinv, off, csr,
            gcn_b + i * HID, bn_g + i * HID, bn_be + i * HID,
            bn_m + i * HID, bn_v + i * HID, hf, hh, hl);
    }

    // ---- fused classifier ----
    classifier<<<NP / 32, 256, 0, stream>>>(hh, hl, c1w, c1_b,
                                            c2w, c2_b, c3w, c3_b, out);
}

// Round 15
// 242.542 us; speedup vs baseline: 1.8207x; 1.0242x over previous
//
#include <hip/hip_runtime.h>
#include <hip/hip_bf16.h>

#define NN   10000
#define NP   10048          // 157*64 padded rows
#define HID  256
#define BN_EPS 1e-5f
#define NPH  ((size_t)NP * 256)

typedef _Float16 f16x4 __attribute__((ext_vector_type(4)));
typedef _Float16 f16x8 __attribute__((ext_vector_type(8)));
typedef float    f32x4 __attribute__((ext_vector_type(4)));

__device__ __forceinline__ void gl_lds16(const void* gptr, void* lptr) {
    __builtin_amdgcn_global_load_lds(
        (const __attribute__((address_space(1))) void*)gptr,
        (__attribute__((address_space(3))) void*)lptr,
        16, 0, 0);
}

__device__ __forceinline__ f32x4 cvt4(const _Float16* p) {
    f16x4 t = *(const f16x4*)p;
    f32x4 r; r[0] = t[0]; r[1] = t[1]; r[2] = t[2]; r[3] = t[3];
    return r;
}

// ------------------------------------------------------------------
// Merged: cnt-zero + i64-layout detect (blocks 0..39), weight fp16
// conversion (blocks 40..3019), BN-fold precompute (block 3020):
//   bnA = gamma*rsqrt(var+eps);  bnP2 = bnA*(gcn_b - mean) + beta
__global__ void prep_split(const int* __restrict__ e, unsigned* __restrict__ cnt,
                           unsigned* __restrict__ flag,
                           const float* __restrict__ in_W, const float* __restrict__ gcn_W,
                           const float* __restrict__ c1_W, const float* __restrict__ c2_W,
                           const float* __restrict__ c3_W,
                           const float* __restrict__ gcn_b, const float* __restrict__ bn_g,
                           const float* __restrict__ bn_be, const float* __restrict__ bn_m,
                           const float* __restrict__ bn_v,
                           _Float16* __restrict__ wi, _Float16* __restrict__ gw,
                           _Float16* __restrict__ c1, _Float16* __restrict__ c2,
                           _Float16* __restrict__ c3,
                           float* __restrict__ bnA, float* __restrict__ bnP2) {
    if (blockIdx.x < 40) {
        int i = blockIdx.x * 256 + threadIdx.x;
        if (i < NN) cnt[i] = 0u;
        if (blockIdx.x == 0) {
            __shared__ int nz;
            if (threadIdx.x == 0) nz = 0;
            __syncthreads();
            if (e[2 * threadIdx.x + 1] != 0) nz = 1;
            __syncthreads();
            if (threadIdx.x == 0) *flag = (nz == 0) ? 1u : 0u;  // 1 => int64 layout
        }
        return;
    }
    if (blockIdx.x == 3020) {
#pragma unroll
        for (int it = 0; it < 3; ++it) {
            int idx = it * 256 + threadIdx.x;
            if (idx < 768) {
                float a = bn_g[idx] * rsqrtf(bn_v[idx] + BN_EPS);
                bnA[idx]  = a;
                bnP2[idx] = a * (gcn_b[idx] - bn_m[idx]) + bn_be[idx];
            }
        }
        return;
    }
    int idx = (blockIdx.x - 40) * 256 + threadIdx.x;
    float v; _Float16* d; int o;
    if (idx < 524288)      { v = in_W[idx];          d = wi; o = idx; }
    else if (idx < 720896) { o = idx - 524288; v = gcn_W[o]; d = gw; }
    else if (idx < 753664) { o = idx - 720896; v = c1_W[o];  d = c1; }
    else if (idx < 761856) { o = idx - 753664; v = c2_W[o];  d = c2; }
    else                   { o = idx - 761856; int r = o >> 6, c = o & 63;
                             v = (r < 10) ? c3_W[r * 64 + c] : 0.0f; d = c3; }
    d[o] = (_Float16)v;
}

__device__ __forceinline__ int edge_val(const int* e, unsigned f, long idx) {
    return f ? e[2 * idx] : e[idx];
}

__global__ void count_edges(const int* __restrict__ e, const unsigned* __restrict__ flag,
                            unsigned* __restrict__ cnt, int E) {
    int i = blockIdx.x * blockDim.x + threadIdx.x;
    if (i >= E) return;
    unsigned f = *flag;
    atomicAdd(&cnt[edge_val(e, f, (long)E + i)], 1u);
}

// single block, 1024 threads
__global__ void scan_dinv(const unsigned* __restrict__ cnt, unsigned* __restrict__ off,
                          unsigned* __restrict__ cur, float* __restrict__ dinv, int n) {
    __shared__ unsigned partial[1024];
    int t = threadIdx.x;
    int chunk = (n + 1023) / 1024;
    int lo = t * chunk;
    int hi = lo + chunk; if (hi > n) hi = n; if (lo > n) lo = n;
    unsigned s = 0;
    for (int i = lo; i < hi; ++i) s += cnt[i];
    partial[t] = s;
    __syncthreads();
    for (int d = 1; d < 1024; d <<= 1) {
        unsigned v = (t >= d) ? partial[t - d] : 0u;
        __syncthreads();
        partial[t] += v;
        __syncthreads();
    }
    unsigned base = (t == 0) ? 0u : partial[t - 1];
    for (int i = lo; i < hi; ++i) {
        off[i] = base; cur[i] = base;
        dinv[i] = rsqrtf((float)cnt[i] + 1.0f);
        base += cnt[i];
    }
    if (t == 1023) off[n] = base;
}

__global__ void fill_csr(const int* __restrict__ e, const unsigned* __restrict__ flag,
                         unsigned* __restrict__ cur, int* __restrict__ csr_src, int E) {
    int i = blockIdx.x * blockDim.x + threadIdx.x;
    if (i >= E) return;
    unsigned f = *flag;
    int src = edge_val(e, f, (long)i);
    int dst = edge_val(e, f, (long)E + i);
    unsigned pos = atomicAdd(&cur[dst], 1u);
    csr_src[pos] = src;
}

// ------------------------------------------------------------------
// Input projection: BM=64 x BN=256, split-K=4, 2-phase pipelined, dbuf LDS.
// A(x) split fp16 hi/lo in-kernel; B = single fp16 plane via global_load_lds.
// 2 MFMA passes/frag. LDS 48 KB -> 3 blk/CU. Partials stored FP16.
#define IPZ 4
#define IPKC 512
__global__ __launch_bounds__(256) void inproj_gemm(
    const float* __restrict__ A,
    const _Float16* __restrict__ B,
    _Float16* __restrict__ P)
{
    __shared__ __align__(16) _Float16 sAh[2][2048], sAl[2][2048];
    __shared__ __align__(16) _Float16 sB[2][8192];

    const int tid = threadIdx.x, wid = tid >> 6, lane = tid & 63;
    const int fr = lane & 15, fq = lane >> 4;
    const int bm = blockIdx.x * 64;
    const int kbase = blockIdx.z * IPKC;
    const int wn = wid * 64;

    f32x4 acc[4][4] = {};

    const int rs = tid >> 2, cq = tid & 3;
    const int gr = min(bm + rs, NN - 1);
    const float* aptr = A + (size_t)gr * 2048 + cq * 8;
    const int scA = rs * 32 + ((cq ^ ((rs >> 1) & 3)) << 3);
    const int brow_l = lane >> 2, bch = lane & 3;

    float av[8];
    int cur = 0;

    {   // prologue: stage tile 0
        float4 v0 = *(const float4*)(aptr + kbase);
        float4 v1 = *(const float4*)(aptr + kbase + 4);
        av[0]=v0.x; av[1]=v0.y; av[2]=v0.z; av[3]=v0.w;
        av[4]=v1.x; av[5]=v1.y; av[6]=v1.z; av[7]=v1.w;
#pragma unroll
        for (int j = 0; j < 4; ++j) {
            int slice = wid * 4 + j;
            int row = slice * 16 + brow_l;
            int lc = bch ^ ((row >> 1) & 3);
            gl_lds16(B + (size_t)row * 2048 + kbase + lc * 8, &sB[0][slice * 512]);
        }
        f16x8 hv, lv;
#pragma unroll
        for (int j = 0; j < 8; ++j) {
            _Float16 h = (_Float16)av[j];
            hv[j] = h; lv[j] = (_Float16)(av[j] - (float)h);
        }
        *(f16x8*)&sAh[0][scA] = hv;
        *(f16x8*)&sAl[0][scA] = lv;
    }
    __syncthreads();

    for (int kt = 0; kt < IPKC / 32; ++kt) {
        const bool more = (kt + 1) < IPKC / 32;
        const int nk = kbase + (kt + 1) * 32;
        if (more) {
            float4 v0 = *(const float4*)(aptr + nk);
            float4 v1 = *(const float4*)(aptr + nk + 4);
            av[0]=v0.x; av[1]=v0.y; av[2]=v0.z; av[3]=v0.w;
            av[4]=v1.x; av[5]=v1.y; av[6]=v1.z; av[7]=v1.w;
#pragma unroll
            for (int j = 0; j < 4; ++j) {
                int slice = wid * 4 + j;
                int row = slice * 16 + brow_l;
                int lc = bch ^ ((row >> 1) & 3);
                gl_lds16(B + (size_t)row * 2048 + nk + lc * 8, &sB[cur ^ 1][slice * 512]);
            }
        }
        f16x8 b[4];
#pragma unroll
        for (int ni = 0; ni < 4; ++ni) {
            int r = wn + ni * 16 + fr;
            b[ni] = *(const f16x8*)&sB[cur][r * 32 + ((fq ^ ((r >> 1) & 3)) << 3)];
        }
#pragma unroll
        for (int mi = 0; mi < 4; ++mi) {
            int r = mi * 16 + fr;
            int e = r * 32 + ((fq ^ ((r >> 1) & 3)) << 3);
            f16x8 ah = *(const f16x8*)&sAh[cur][e];
            f16x8 al = *(const f16x8*)&sAl[cur][e];
#pragma unroll
            for (int ni = 0; ni < 4; ++ni) {
                acc[mi][ni] = __builtin_amdgcn_mfma_f32_16x16x32_f16(ah, b[ni], acc[mi][ni], 0, 0, 0);
                acc[mi][ni] = __builtin_amdgcn_mfma_f32_16x16x32_f16(al, b[ni], acc[mi][ni], 0, 0, 0);
            }
        }
        if (more) {
            f16x8 hv, lv;
#pragma unroll
            for (int j = 0; j < 8; ++j) {
                _Float16 h = (_Float16)av[j];
                hv[j] = h; lv[j] = (_Float16)(av[j] - (float)h);
            }
            *(f16x8*)&sAh[cur ^ 1][scA] = hv;
            *(f16x8*)&sAl[cur ^ 1][scA] = lv;
        }
        __syncthreads();
        cur ^= 1;
    }

    _Float16* Pz = P + (size_t)blockIdx.z * NPH;
#pragma unroll
    for (int mi = 0; mi < 4; ++mi) {
        int row0 = bm + mi * 16 + fq * 4;
#pragma unroll
        for (int ni = 0; ni < 4; ++ni) {
            int col = wn + ni * 16 + fr;
#pragma unroll
            for (int r = 0; r < 4; ++r)
                Pz[(size_t)(row0 + r) * 256 + col] = (_Float16)acc[mi][ni][r];
        }
    }
}

// reduce 4 fp16 partials + bias + relu -> fp16 hi/lo planes (zero pad rows)
__global__ void inproj_epi(const _Float16* __restrict__ P, const float* __restrict__ b,
                           _Float16* __restrict__ hh, _Float16* __restrict__ hl) {
    int t = blockIdx.x * 256 + threadIdx.x;
    size_t idx = (size_t)t * 4;
    int row = (int)(idx >> 8), col = (int)(idx & 255);
    float v[4] = {0, 0, 0, 0};
    if (row < NN) {
        f32x4 a0 = cvt4(P + idx);
        f32x4 a1 = cvt4(P + idx + NPH);
        f32x4 a2 = cvt4(P + idx + 2 * NPH);
        f32x4 a3 = cvt4(P + idx + 3 * NPH);
        f32x4 bb = *(const f32x4*)(b + col);
#pragma unroll
        for (int j = 0; j < 4; ++j)
            v[j] = fmaxf((a0[j] + a1[j]) + (a2[j] + a3[j]) + bb[j], 0.0f);
    }
    f16x4 hv, lv;
#pragma unroll
    for (int j = 0; j < 4; ++j) {
        _Float16 h = (_Float16)v[j];
        hv[j] = h; lv[j] = (_Float16)(v[j] - (float)h);
    }
    *(f16x4*)&hh[idx] = hv;
    *(f16x4*)&hl[idx] = lv;
}

// ------------------------------------------------------------------
// Layer GEMM (K=256): no LDS, per-lane direct fragment loads.
// A = h fp16 hi/lo, B = single fp16 weight plane; 2 passes.
// Epilogue pre-scales by dinv[row] and emits hws as FP16.
__global__ __launch_bounds__(256) void gemm_layer(
    const _Float16* __restrict__ Ah, const _Float16* __restrict__ Al,
    const _Float16* __restrict__ Bw,
    const float* __restrict__ dinv, _Float16* __restrict__ Cw)
{
    const int tid = threadIdx.x, wid = tid >> 6, lane = tid & 63;
    const int fr = lane & 15, fq = lane >> 4;
    const int wr = wid >> 1, wc = wid & 1;
    const int bm = blockIdx.x * 64, bn = blockIdx.y * 64;

    f32x4 acc[2][2] = {};
    size_t ra[2], rb[2];
#pragma unroll
    for (int mi = 0; mi < 2; ++mi) ra[mi] = (size_t)(bm + wr * 32 + mi * 16 + fr) * 256 + fq * 8;
#pragma unroll
    for (int ni = 0; ni < 2; ++ni) rb[ni] = (size_t)(bn + wc * 32 + ni * 16 + fr) * 256 + fq * 8;

#pragma unroll
    for (int kt = 0; kt < 8; ++kt) {
        f16x8 ah[2], al[2], bw[2];
#pragma unroll
        for (int mi = 0; mi < 2; ++mi) {
            ah[mi] = *(const f16x8*)(Ah + ra[mi] + kt * 32);
            al[mi] = *(const f16x8*)(Al + ra[mi] + kt * 32);
        }
#pragma unroll
        for (int ni = 0; ni < 2; ++ni)
            bw[ni] = *(const f16x8*)(Bw + rb[ni] + kt * 32);
#pragma unroll
        for (int mi = 0; mi < 2; ++mi)
#pragma unroll
            for (int ni = 0; ni < 2; ++ni) {
                acc[mi][ni] = __builtin_amdgcn_mfma_f32_16x16x32_f16(ah[mi], bw[ni], acc[mi][ni], 0, 0, 0);
                acc[mi][ni] = __builtin_amdgcn_mfma_f32_16x16x32_f16(al[mi], bw[ni], acc[mi][ni], 0, 0, 0);
            }
    }

    float dv[2][4];
#pragma unroll
    for (int mi = 0; mi < 2; ++mi)
#pragma unroll
        for (int r = 0; r < 4; ++r) {
            int row = bm + wr * 32 + mi * 16 + fq * 4 + r;
            dv[mi][r] = (row < NN) ? dinv[row] : 0.0f;
        }

#pragma unroll
    for (int mi = 0; mi < 2; ++mi)
#pragma unroll
        for (int ni = 0; ni < 2; ++ni) {
            int col = bn + wc * 32 + ni * 16 + fr;
#pragma unroll
            for (int r = 0; r < 4; ++r) {
                int row = bm + wr * 32 + mi * 16 + fq * 4 + r;
                if (row < NN)
                    Cw[(size_t)row * 256 + col] = (_Float16)(acc[mi][ni][r] * dv[mi][r]);
            }
        }
}

// ------------------------------------------------------------------
// GCN aggregate v6 + folded BN: full-row, wave-per-node.
//   out = relu(bnA*(dn*acc) + bnP2) (+ res)
__global__ __launch_bounds__(256) void gcn_aggregate(
    const _Float16* __restrict__ hws, const float* __restrict__ res,
    const float* __restrict__ dinv, const unsigned* __restrict__ off,
    const int* __restrict__ csr,
    const float* __restrict__ bnA, const float* __restrict__ bnP2,
    float* __restrict__ hf, _Float16* __restrict__ hh, _Float16* __restrict__ hl)
{
    const int wid = threadIdx.x >> 6, l = threadIdx.x & 63;
    const int node = blockIdx.x * 4 + wid;            // grid = 2500 blocks
    const int f = l << 2;                             // 0..252
    const size_t rowb = (size_t)node * HID + f;

    const float dn = dinv[node];
    const unsigned j0 = off[node], j1 = off[node + 1];

    f32x4 a0 = cvt4(hws + rowb);                      // self term (pre-scaled)
    f32x4 a1 = {0.f,0.f,0.f,0.f}, a2 = {0.f,0.f,0.f,0.f}, a3 = {0.f,0.f,0.f,0.f};
    f32x4 a4 = {0.f,0.f,0.f,0.f}, a5 = {0.f,0.f,0.f,0.f};
    f32x4 a6 = {0.f,0.f,0.f,0.f}, a7 = {0.f,0.f,0.f,0.f};

    unsigned j = j0;
    for (; j + 8 <= j1; j += 8) {
        int s0 = csr[j + 0];
        int s1 = csr[j + 1];
        int s2 = csr[j + 2];
        int s3 = csr[j + 3];
        int s4 = csr[j + 4];
        int s5 = csr[j + 5];
        int s6 = csr[j + 6];
        int s7 = csr[j + 7];
        a0 += cvt4(hws + (size_t)s0 * HID + f);
        a1 += cvt4(hws + (size_t)s1 * HID + f);
        a2 += cvt4(hws + (size_t)s2 * HID + f);
        a3 += cvt4(hws + (size_t)s3 * HID + f);
        a4 += cvt4(hws + (size_t)s4 * HID + f);
        a5 += cvt4(hws + (size_t)s5 * HID + f);
        a6 += cvt4(hws + (size_t)s6 * HID + f);
        a7 += cvt4(hws + (size_t)s7 * HID + f);
    }
    for (; j + 4 <= j1; j += 4) {
        int s0 = csr[j + 0];
        int s1 = csr[j + 1];
        int s2 = csr[j + 2];
        int s3 = csr[j + 3];
        a1 += cvt4(hws + (size_t)s0 * HID + f);
        a2 += cvt4(hws + (size_t)s1 * HID + f);
        a3 += cvt4(hws + (size_t)s2 * HID + f);
        a4 += cvt4(hws + (size_t)s3 * HID + f);
    }
    for (; j < j1; ++j) {
        int s = csr[j];
        a5 += cvt4(hws + (size_t)s * HID + f);
    }
    f32x4 acc = ((a0 + a1) + (a2 + a3)) + ((a4 + a5) + (a6 + a7));

    f32x4 al4 = *(const f32x4*)(bnA + f);
    f32x4 p4  = *(const f32x4*)(bnP2 + f);
    f32x4 r4 = {0.0f, 0.0f, 0.0f, 0.0f};
    if (res) r4 = *(const f32x4*)(res + rowb);

    f32x4 o;
    f16x4 hv, lv;
#pragma unroll
    for (int jj = 0; jj < 4; ++jj) {
        float t = al4[jj] * (dn * acc[jj]) + p4[jj];
        t = fmaxf(t, 0.0f);
        t += r4[jj];
        o[jj] = t;
        _Float16 h = (_Float16)t;
        hv[jj] = h; lv[jj] = (_Float16)(t - (float)h);
    }
    if (hf) *(f32x4*)(hf + rowb) = o;
    *(f16x4*)&hh[rowb] = hv;
    *(f16x4*)&hl[rowb] = lv;
}

// ------------------------------------------------------------------
// Fused classifier: 32-row tile, h -> O1(LDS) -> O2(LDS) -> logits.
__global__ __launch_bounds__(256) void classifier(
    const _Float16* __restrict__ Ah, const _Float16* __restrict__ Al,
    const _Float16* __restrict__ c1w, const float* __restrict__ b1,
    const _Float16* __restrict__ c2w, const float* __restrict__ b2,
    const _Float16* __restrict__ c3w, const float* __restrict__ b3,
    float* __restrict__ out)
{
    __shared__ __align__(16) float sO1[32][132];
    __shared__ __align__(16) float sO2[32][68];

    const int tid = threadIdx.x, wid = tid >> 6, lane = tid & 63;
    const int fr = lane & 15, fq = lane >> 4;
    const int bm = blockIdx.x * 32;

    // ---- stage 1: O1 = relu(h @ c1^T + b1)   M=32 N=128 K=256
    {
        f32x4 acc[2][2] = {};
        size_t ra[2], rb[2];
#pragma unroll
        for (int mi = 0; mi < 2; ++mi) ra[mi] = (size_t)(bm + mi * 16 + fr) * 256 + fq * 8;
#pragma unroll
        for (int ni = 0; ni < 2; ++ni) rb[ni] = (size_t)(wid * 32 + ni * 16 + fr) * 256 + fq * 8;
#pragma unroll
        for (int kt = 0; kt < 8; ++kt) {
            f16x8 ah[2], al[2], bw[2];
#pragma unroll
            for (int mi = 0; mi < 2; ++mi) {
                ah[mi] = *(const f16x8*)(Ah + ra[mi] + kt * 32);
                al[mi] = *(const f16x8*)(Al + ra[mi] + kt * 32);
            }
#pragma unroll
            for (int ni = 0; ni < 2; ++ni)
                bw[ni] = *(const f16x8*)(c1w + rb[ni] + kt * 32);
#pragma unroll
            for (int mi = 0; mi < 2; ++mi)
#pragma unroll
                for (int ni = 0; ni < 2; ++ni) {
                    acc[mi][ni] = __builtin_amdgcn_mfma_f32_16x16x32_f16(ah[mi], bw[ni], acc[mi][ni], 0, 0, 0);
                    acc[mi][ni] = __builtin_amdgcn_mfma_f32_16x16x32_f16(al[mi], bw[ni], acc[mi][ni], 0, 0, 0);
                }
        }
#pragma unroll
        for (int mi = 0; mi < 2; ++mi)
#pragma unroll
            for (int ni = 0; ni < 2; ++ni) {
                int col = wid * 32 + ni * 16 + fr;
                float bb = b1[col];
#pragma unroll
                for (int r = 0; r < 4; ++r)
                    sO1[mi * 16 + fq * 4 + r][col] = fmaxf(acc[mi][ni][r] + bb, 0.0f);
            }
    }
    __syncthreads();

    // ---- stage 2: O2 = relu(O1 @ c2^T + b2)   M=32 N=64 K=128
    {
        f32x4 acc[2] = {};
#pragma unroll
        for (int kt = 0; kt < 4; ++kt) {
            f16x8 ah[2], al[2];
#pragma unroll
            for (int mi = 0; mi < 2; ++mi) {
                const float* p = &sO1[mi * 16 + fr][kt * 32 + fq * 8];
                f32x4 v0 = *(const f32x4*)p;
                f32x4 v1 = *(const f32x4*)(p + 4);
                float vv[8] = {v0[0], v0[1], v0[2], v0[3], v1[0], v1[1], v1[2], v1[3]};
#pragma unroll
                for (int j = 0; j < 8; ++j) {
                    _Float16 h = (_Float16)vv[j];
                    ah[mi][j] = h; al[mi][j] = (_Float16)(vv[j] - (float)h);
                }
            }
            size_t rb = (size_t)(wid * 16 + fr) * 128 + kt * 32 + fq * 8;
            f16x8 bw = *(const f16x8*)(c2w + rb);
#pragma unroll
            for (int mi = 0; mi < 2; ++mi) {
                acc[mi] = __builtin_amdgcn_mfma_f32_16x16x32_f16(ah[mi], bw, acc[mi], 0, 0, 0);
                acc[mi] = __builtin_amdgcn_mfma_f32_16x16x32_f16(al[mi], bw, acc[mi], 0, 0, 0);
            }
        }
        int col = wid * 16 + fr;
        float bb = b2[col];
#pragma unroll
        for (int mi = 0; mi < 2; ++mi)
#pragma unroll
            for (int r = 0; r < 4; ++r)
                sO2[mi * 16 + fq * 4 + r][col] = fmaxf(acc[mi][r] + bb, 0.0f);
    }
    __syncthreads();

    // ---- stage 3: logits = O2 @ c3^T + b3
    if (wid < 2) {
        f32x4 acc = {};
#pragma unroll
        for (int kt = 0; kt < 2; ++kt) {
            const float* p = &sO2[wid * 16 + fr][kt * 32 + fq * 8];
            f32x4 v0 = *(const f32x4*)p;
            f32x4 v1 = *(const f32x4*)(p + 4);
            float vv[8] = {v0[0], v0[1], v0[2], v0[3], v1[0], v1[1], v1[2], v1[3]};
            f16x8 ah, al;
#pragma unroll
            for (int j = 0; j < 8; ++j) {
                _Float16 h = (_Float16)vv[j];
                ah[j] = h; al[j] = (_Float16)(vv[j] - (float)h);
            }
            size_t rb = (size_t)fr * 64 + kt * 32 + fq * 8;
            f16x8 bw = *(const f16x8*)(c3w + rb);
            acc = __builtin_amdgcn_mfma_f32_16x16x32_f16(ah, bw, acc, 0, 0, 0);
            acc = __builtin_amdgcn_mfma_f32_16x16x32_f16(al, bw, acc, 0, 0, 0);
        }
        if (fr < 10) {
            float bb = b3[fr];
#pragma unroll
            for (int r = 0; r < 4; ++r) {
                int row = bm + wid * 16 + fq * 4 + r;
                if (row < NN) out[(size_t)row * 10 + fr] = acc[r] + bb;
            }
        }
    }
}

// ------------------------------------------------------------------
extern "C" void kernel_launch(void* const* d_in, const int* in_sizes, int n_in,
                              void* d_out, int out_size, void* d_ws, size_t ws_size,
                              hipStream_t stream)
{
    const float* x     = (const float*)d_in[0];
    const int*   eidx  = (const int*)d_in[1];
    const float* in_W  = (const float*)d_in[2];
    const float* in_b  = (const float*)d_in[3];
    const float* gcn_W = (const float*)d_in[4];
    const float* gcn_b = (const float*)d_in[5];
    const float* bn_g  = (const float*)d_in[6];
    const float* bn_be = (const float*)d_in[7];
    const float* bn_m  = (const float*)d_in[8];
    const float* bn_v  = (const float*)d_in[9];
    const float* c1_W  = (const float*)d_in[10];
    const float* c1_b  = (const float*)d_in[11];
    const float* c2_W  = (const float*)d_in[12];
    const float* c2_b  = (const float*)d_in[13];
    const float* c3_W  = (const float*)d_in[14];
    const float* c3_b  = (const float*)d_in[15];
    float* out = (float*)d_out;

    const int E = in_sizes[1] / 2;
    float* ws = (float*)d_ws;

    // ---- workspace layout ----
    float*    h1  = ws;                         // NPH f32 (residual 1)
    float*    h2  = h1 + NPH;                   // NPH f32 (residual 2)
    _Float16* P   = (_Float16*)ws;              // aliases h1/h2: 4*NPH fp16, dead after epi
    _Float16* hws = (_Float16*)(ws + 2 * NPH);  // NPH fp16 (gather table)
    _Float16* hh  = hws + NPH;
    _Float16* hl  = hh + NPH;
    _Float16* wi  = hl + NPH;         // 256x2048
    _Float16* gw  = wi + 524288;      // 768x256
    _Float16* c1w = gw + 196608;      // 128x256
    _Float16* c2w = c1w + 32768;      // 64x128
    _Float16* c3w = c2w + 8192;       // 16x64 (10 real rows)
    float*    bnA  = (float*)(c3w + 1024);      // 768
    float*    bnP2 = bnA + 768;                 // 768
    float*    dinv = bnP2 + 768;
    unsigned* cnt  = (unsigned*)(dinv + NN);
    unsigned* off  = cnt + NN;
    unsigned* cur  = off + NN + 1;
    unsigned* flag = cur + NN;
    int*      csr  = (int*)(flag + 4);

    // ---- graph prep + weight fp16 conversion + BN fold ----
    prep_split<<<3021, 256, 0, stream>>>(eidx, cnt, flag, in_W, gcn_W, c1_W, c2_W, c3_W,
                                         gcn_b, bn_g, bn_be, bn_m, bn_v,
                                         wi, gw, c1w, c2w, c3w, bnA, bnP2);
    count_edges<<<(E + 255) / 256, 256, 0, stream>>>(eidx, flag, cnt, E);
    scan_dinv<<<1, 1024, 0, stream>>>(cnt, off, cur, dinv, NN);
    fill_csr<<<(E + 255) / 256, 256, 0, stream>>>(eidx, flag, cur, csr, E);

    // ---- input projection ----
    inproj_gemm<<<dim3(NP / 64, 1, IPZ), 256, 0, stream>>>(x, wi, P);
    inproj_epi<<<(int)(NPH / 1024), 256, 0, stream>>>(P, in_b, hh, hl);

    // ---- 3 GCN layers ----
    for (int i = 0; i < 3; ++i) {
        gemm_layer<<<dim3(NP / 64, 4), 256, 0, stream>>>(
            hh, hl, gw + (size_t)i * 65536, dinv, hws);
        const float* res = (i == 0) ? nullptr : (i == 1 ? h1 : h2);
        float* hf = (i == 0) ? h1 : (i == 1 ? h2 : nullptr);
        gcn_aggregate<<<NN / 4, 256, 0, stream>>>(
            hws, res, dinv, off, csr,
            bnA + i * HID, bnP2 + i * HID, hf, hh, hl);
    }

    // ---- fused classifier ----
    classifier<<<NP / 32, 256, 0, stream>>>(hh, hl, c1w, c1_b,
                                            c2w, c2_b, c3w, c3_b, out);
}

// Round 16
// 240.831 us; speedup vs baseline: 1.8336x; 1.0071x over previous
//
#include <hip/hip_runtime.h>
#include <hip/hip_bf16.h>

#define NN   10000
#define NP   10048          // 157*64 padded rows
#define HID  256
#define BN_EPS 1e-5f
#define NPH  ((size_t)NP * 256)

typedef _Float16 f16x4 __attribute__((ext_vector_type(4)));
typedef _Float16 f16x8 __attribute__((ext_vector_type(8)));
typedef float    f32x4 __attribute__((ext_vector_type(4)));

__device__ __forceinline__ void gl_lds16(const void* gptr, void* lptr) {
    __builtin_amdgcn_global_load_lds(
        (const __attribute__((address_space(1))) void*)gptr,
        (__attribute__((address_space(3))) void*)lptr,
        16, 0, 0);
}

__device__ __forceinline__ f32x4 cvt4(const _Float16* p) {
    f16x4 t = *(const f16x4*)p;
    f32x4 r; r[0] = t[0]; r[1] = t[1]; r[2] = t[2]; r[3] = t[3];
    return r;
}

// ------------------------------------------------------------------
// Merged: cnt-zero + i64-layout detect (blocks 0..39), weight fp16
// conversion (blocks 40..3019), BN-fold precompute (block 3020):
//   bnA = gamma*rsqrt(var+eps);  bnP2 = bnA*(gcn_b - mean) + beta
__global__ void prep_split(const int* __restrict__ e, unsigned* __restrict__ cnt,
                           unsigned* __restrict__ flag,
                           const float* __restrict__ in_W, const float* __restrict__ gcn_W,
                           const float* __restrict__ c1_W, const float* __restrict__ c2_W,
                           const float* __restrict__ c3_W,
                           const float* __restrict__ gcn_b, const float* __restrict__ bn_g,
                           const float* __restrict__ bn_be, const float* __restrict__ bn_m,
                           const float* __restrict__ bn_v,
                           _Float16* __restrict__ wi, _Float16* __restrict__ gw,
                           _Float16* __restrict__ c1, _Float16* __restrict__ c2,
                           _Float16* __restrict__ c3,
                           float* __restrict__ bnA, float* __restrict__ bnP2) {
    if (blockIdx.x < 40) {
        int i = blockIdx.x * 256 + threadIdx.x;
        if (i < NN) cnt[i] = 0u;
        if (blockIdx.x == 0) {
            __shared__ int nz;
            if (threadIdx.x == 0) nz = 0;
            __syncthreads();
            if (e[2 * threadIdx.x + 1] != 0) nz = 1;
            __syncthreads();
            if (threadIdx.x == 0) *flag = (nz == 0) ? 1u : 0u;  // 1 => int64 layout
        }
        return;
    }
    if (blockIdx.x == 3020) {
#pragma unroll
        for (int it = 0; it < 3; ++it) {
            int idx = it * 256 + threadIdx.x;
            if (idx < 768) {
                float a = bn_g[idx] * rsqrtf(bn_v[idx] + BN_EPS);
                bnA[idx]  = a;
                bnP2[idx] = a * (gcn_b[idx] - bn_m[idx]) + bn_be[idx];
            }
        }
        return;
    }
    int idx = (blockIdx.x - 40) * 256 + threadIdx.x;
    float v; _Float16* d; int o;
    if (idx < 524288)      { v = in_W[idx];          d = wi; o = idx; }
    else if (idx < 720896) { o = idx - 524288; v = gcn_W[o]; d = gw; }
    else if (idx < 753664) { o = idx - 720896; v = c1_W[o];  d = c1; }
    else if (idx < 761856) { o = idx - 753664; v = c2_W[o];  d = c2; }
    else                   { o = idx - 761856; int r = o >> 6, c = o & 63;
                             v = (r < 10) ? c3_W[r * 64 + c] : 0.0f; d = c3; }
    d[o] = (_Float16)v;
}

__device__ __forceinline__ int edge_val(const int* e, unsigned f, long idx) {
    return f ? e[2 * idx] : e[idx];
}

__global__ void count_edges(const int* __restrict__ e, const unsigned* __restrict__ flag,
                            unsigned* __restrict__ cnt, int E) {
    int i = blockIdx.x * blockDim.x + threadIdx.x;
    if (i >= E) return;
    unsigned f = *flag;
    atomicAdd(&cnt[edge_val(e, f, (long)E + i)], 1u);
}

// single block, 1024 threads
__global__ void scan_dinv(const unsigned* __restrict__ cnt, unsigned* __restrict__ off,
                          unsigned* __restrict__ cur, float* __restrict__ dinv, int n) {
    __shared__ unsigned partial[1024];
    int t = threadIdx.x;
    int chunk = (n + 1023) / 1024;
    int lo = t * chunk;
    int hi = lo + chunk; if (hi > n) hi = n; if (lo > n) lo = n;
    unsigned s = 0;
    for (int i = lo; i < hi; ++i) s += cnt[i];
    partial[t] = s;
    __syncthreads();
    for (int d = 1; d < 1024; d <<= 1) {
        unsigned v = (t >= d) ? partial[t - d] : 0u;
        __syncthreads();
        partial[t] += v;
        __syncthreads();
    }
    unsigned base = (t == 0) ? 0u : partial[t - 1];
    for (int i = lo; i < hi; ++i) {
        off[i] = base; cur[i] = base;
        dinv[i] = rsqrtf((float)cnt[i] + 1.0f);
        base += cnt[i];
    }
    if (t == 1023) off[n] = base;
}

__global__ void fill_csr(const int* __restrict__ e, const unsigned* __restrict__ flag,
                         unsigned* __restrict__ cur, int* __restrict__ csr_src, int E) {
    int i = blockIdx.x * blockDim.x + threadIdx.x;
    if (i >= E) return;
    unsigned f = *flag;
    int src = edge_val(e, f, (long)i);
    int dst = edge_val(e, f, (long)E + i);
    unsigned pos = atomicAdd(&cur[dst], 1u);
    csr_src[pos] = src;
}

// ------------------------------------------------------------------
// Input projection: BM=64 x BN=256, split-K=8 (IPKC=256), 2-phase pipelined,
// dbuf LDS. A(x) split fp16 hi/lo in-kernel; B = single fp16 plane via
// global_load_lds. 2 MFMA passes/frag. LDS 48 KB; grid 1256 blocks (~5/CU
// pending) so barrier-drain stalls overlap across blocks. Partials FP16.
#define IPZ 8
#define IPKC 256
__global__ __launch_bounds__(256) void inproj_gemm(
    const float* __restrict__ A,
    const _Float16* __restrict__ B,
    _Float16* __restrict__ P)
{
    __shared__ __align__(16) _Float16 sAh[2][2048], sAl[2][2048];
    __shared__ __align__(16) _Float16 sB[2][8192];

    const int tid = threadIdx.x, wid = tid >> 6, lane = tid & 63;
    const int fr = lane & 15, fq = lane >> 4;
    const int bm = blockIdx.x * 64;
    const int kbase = blockIdx.z * IPKC;
    const int wn = wid * 64;

    f32x4 acc[4][4] = {};

    const int rs = tid >> 2, cq = tid & 3;
    const int gr = min(bm + rs, NN - 1);
    const float* aptr = A + (size_t)gr * 2048 + cq * 8;
    const int scA = rs * 32 + ((cq ^ ((rs >> 1) & 3)) << 3);
    const int brow_l = lane >> 2, bch = lane & 3;

    float av[8];
    int cur = 0;

    {   // prologue: stage tile 0
        float4 v0 = *(const float4*)(aptr + kbase);
        float4 v1 = *(const float4*)(aptr + kbase + 4);
        av[0]=v0.x; av[1]=v0.y; av[2]=v0.z; av[3]=v0.w;
        av[4]=v1.x; av[5]=v1.y; av[6]=v1.z; av[7]=v1.w;
#pragma unroll
        for (int j = 0; j < 4; ++j) {
            int slice = wid * 4 + j;
            int row = slice * 16 + brow_l;
            int lc = bch ^ ((row >> 1) & 3);
            gl_lds16(B + (size_t)row * 2048 + kbase + lc * 8, &sB[0][slice * 512]);
        }
        f16x8 hv, lv;
#pragma unroll
        for (int j = 0; j < 8; ++j) {
            _Float16 h = (_Float16)av[j];
            hv[j] = h; lv[j] = (_Float16)(av[j] - (float)h);
        }
        *(f16x8*)&sAh[0][scA] = hv;
        *(f16x8*)&sAl[0][scA] = lv;
    }
    __syncthreads();

    for (int kt = 0; kt < IPKC / 32; ++kt) {
        const bool more = (kt + 1) < IPKC / 32;
        const int nk = kbase + (kt + 1) * 32;
        if (more) {
            float4 v0 = *(const float4*)(aptr + nk);
            float4 v1 = *(const float4*)(aptr + nk + 4);
            av[0]=v0.x; av[1]=v0.y; av[2]=v0.z; av[3]=v0.w;
            av[4]=v1.x; av[5]=v1.y; av[6]=v1.z; av[7]=v1.w;
#pragma unroll
            for (int j = 0; j < 4; ++j) {
                int slice = wid * 4 + j;
                int row = slice * 16 + brow_l;
                int lc = bch ^ ((row >> 1) & 3);
                gl_lds16(B + (size_t)row * 2048 + nk + lc * 8, &sB[cur ^ 1][slice * 512]);
            }
        }
        f16x8 b[4];
#pragma unroll
        for (int ni = 0; ni < 4; ++ni) {
            int r = wn + ni * 16 + fr;
            b[ni] = *(const f16x8*)&sB[cur][r * 32 + ((fq ^ ((r >> 1) & 3)) << 3)];
        }
#pragma unroll
        for (int mi = 0; mi < 4; ++mi) {
            int r = mi * 16 + fr;
            int e = r * 32 + ((fq ^ ((r >> 1) & 3)) << 3);
            f16x8 ah = *(const f16x8*)&sAh[cur][e];
            f16x8 al = *(const f16x8*)&sAl[cur][e];
#pragma unroll
            for (int ni = 0; ni < 4; ++ni) {
                acc[mi][ni] = __builtin_amdgcn_mfma_f32_16x16x32_f16(ah, b[ni], acc[mi][ni], 0, 0, 0);
                acc[mi][ni] = __builtin_amdgcn_mfma_f32_16x16x32_f16(al, b[ni], acc[mi][ni], 0, 0, 0);
            }
        }
        if (more) {
            f16x8 hv, lv;
#pragma unroll
            for (int j = 0; j < 8; ++j) {
                _Float16 h = (_Float16)av[j];
                hv[j] = h; lv[j] = (_Float16)(av[j] - (float)h);
            }
            *(f16x8*)&sAh[cur ^ 1][scA] = hv;
            *(f16x8*)&sAl[cur ^ 1][scA] = lv;
        }
        __syncthreads();
        cur ^= 1;
    }

    _Float16* Pz = P + (size_t)blockIdx.z * NPH;
#pragma unroll
    for (int mi = 0; mi < 4; ++mi) {
        int row0 = bm + mi * 16 + fq * 4;
#pragma unroll
        for (int ni = 0; ni < 4; ++ni) {
            int col = wn + ni * 16 + fr;
#pragma unroll
            for (int r = 0; r < 4; ++r)
                Pz[(size_t)(row0 + r) * 256 + col] = (_Float16)acc[mi][ni][r];
        }
    }
}

// reduce 8 fp16 partials + bias + relu -> fp16 hi/lo planes (zero pad rows)
__global__ void inproj_epi(const _Float16* __restrict__ P, const float* __restrict__ b,
                           _Float16* __restrict__ hh, _Float16* __restrict__ hl) {
    int t = blockIdx.x * 256 + threadIdx.x;
    size_t idx = (size_t)t * 4;
    int row = (int)(idx >> 8), col = (int)(idx & 255);
    float v[4] = {0, 0, 0, 0};
    if (row < NN) {
        f32x4 a0 = cvt4(P + idx)           + cvt4(P + idx + NPH);
        f32x4 a1 = cvt4(P + idx + 2 * NPH) + cvt4(P + idx + 3 * NPH);
        f32x4 a2 = cvt4(P + idx + 4 * NPH) + cvt4(P + idx + 5 * NPH);
        f32x4 a3 = cvt4(P + idx + 6 * NPH) + cvt4(P + idx + 7 * NPH);
        f32x4 bb = *(const f32x4*)(b + col);
#pragma unroll
        for (int j = 0; j < 4; ++j)
            v[j] = fmaxf((a0[j] + a1[j]) + (a2[j] + a3[j]) + bb[j], 0.0f);
    }
    f16x4 hv, lv;
#pragma unroll
    for (int j = 0; j < 4; ++j) {
        _Float16 h = (_Float16)v[j];
        hv[j] = h; lv[j] = (_Float16)(v[j] - (float)h);
    }
    *(f16x4*)&hh[idx] = hv;
    *(f16x4*)&hl[idx] = lv;
}

// ------------------------------------------------------------------
// Layer GEMM (K=256): no LDS, per-lane direct fragment loads.
// A = h fp16 hi/lo, B = single fp16 weight plane; 2 passes.
// Epilogue pre-scales by dinv[row] and emits hws as FP16.
__global__ __launch_bounds__(256) void gemm_layer(
    const _Float16* __restrict__ Ah, const _Float16* __restrict__ Al,
    const _Float16* __restrict__ Bw,
    const float* __restrict__ dinv, _Float16* __restrict__ Cw)
{
    const int tid = threadIdx.x, wid = tid >> 6, lane = tid & 63;
    const int fr = lane & 15, fq = lane >> 4;
    const int wr = wid >> 1, wc = wid & 1;
    const int bm = blockIdx.x * 64, bn = blockIdx.y * 64;

    f32x4 acc[2][2] = {};
    size_t ra[2], rb[2];
#pragma unroll
    for (int mi = 0; mi < 2; ++mi) ra[mi] = (size_t)(bm + wr * 32 + mi * 16 + fr) * 256 + fq * 8;
#pragma unroll
    for (int ni = 0; ni < 2; ++ni) rb[ni] = (size_t)(bn + wc * 32 + ni * 16 + fr) * 256 + fq * 8;

#pragma unroll
    for (int kt = 0; kt < 8; ++kt) {
        f16x8 ah[2], al[2], bw[2];
#pragma unroll
        for (int mi = 0; mi < 2; ++mi) {
            ah[mi] = *(const f16x8*)(Ah + ra[mi] + kt * 32);
            al[mi] = *(const f16x8*)(Al + ra[mi] + kt * 32);
        }
#pragma unroll
        for (int ni = 0; ni < 2; ++ni)
            bw[ni] = *(const f16x8*)(Bw + rb[ni] + kt * 32);
#pragma unroll
        for (int mi = 0; mi < 2; ++mi)
#pragma unroll
            for (int ni = 0; ni < 2; ++ni) {
                acc[mi][ni] = __builtin_amdgcn_mfma_f32_16x16x32_f16(ah[mi], bw[ni], acc[mi][ni], 0, 0, 0);
                acc[mi][ni] = __builtin_amdgcn_mfma_f32_16x16x32_f16(al[mi], bw[ni], acc[mi][ni], 0, 0, 0);
            }
    }

    float dv[2][4];
#pragma unroll
    for (int mi = 0; mi < 2; ++mi)
#pragma unroll
        for (int r = 0; r < 4; ++r) {
            int row = bm + wr * 32 + mi * 16 + fq * 4 + r;
            dv[mi][r] = (row < NN) ? dinv[row] : 0.0f;
        }

#pragma unroll
    for (int mi = 0; mi < 2; ++mi)
#pragma unroll
        for (int ni = 0; ni < 2; ++ni) {
            int col = bn + wc * 32 + ni * 16 + fr;
#pragma unroll
            for (int r = 0; r < 4; ++r) {
                int row = bm + wr * 32 + mi * 16 + fq * 4 + r;
                if (row < NN)
                    Cw[(size_t)row * 256 + col] = (_Float16)(acc[mi][ni][r] * dv[mi][r]);
            }
        }
}

// ------------------------------------------------------------------
// GCN aggregate v6 + folded BN: full-row, wave-per-node.
//   out = relu(bnA*(dn*acc) + bnP2) (+ res)
__global__ __launch_bounds__(256) void gcn_aggregate(
    const _Float16* __restrict__ hws, const float* __restrict__ res,
    const float* __restrict__ dinv, const unsigned* __restrict__ off,
    const int* __restrict__ csr,
    const float* __restrict__ bnA, const float* __restrict__ bnP2,
    float* __restrict__ hf, _Float16* __restrict__ hh, _Float16* __restrict__ hl)
{
    const int wid = threadIdx.x >> 6, l = threadIdx.x & 63;
    const int node = blockIdx.x * 4 + wid;            // grid = 2500 blocks
    const int f = l << 2;                             // 0..252
    const size_t rowb = (size_t)node * HID + f;

    const float dn = dinv[node];
    const unsigned j0 = off[node], j1 = off[node + 1];

    f32x4 a0 = cvt4(hws + rowb);                      // self term (pre-scaled)
    f32x4 a1 = {0.f,0.f,0.f,0.f}, a2 = {0.f,0.f,0.f,0.f}, a3 = {0.f,0.f,0.f,0.f};
    f32x4 a4 = {0.f,0.f,0.f,0.f}, a5 = {0.f,0.f,0.f,0.f};
    f32x4 a6 = {0.f,0.f,0.f,0.f}, a7 = {0.f,0.f,0.f,0.f};

    unsigned j = j0;
    for (; j + 8 <= j1; j += 8) {
        int s0 = csr[j + 0];
        int s1 = csr[j + 1];
        int s2 = csr[j + 2];
        int s3 = csr[j + 3];
        int s4 = csr[j + 4];
        int s5 = csr[j + 5];
        int s6 = csr[j + 6];
        int s7 = csr[j + 7];
        a0 += cvt4(hws + (size_t)s0 * HID + f);
        a1 += cvt4(hws + (size_t)s1 * HID + f);
        a2 += cvt4(hws + (size_t)s2 * HID + f);
        a3 += cvt4(hws + (size_t)s3 * HID + f);
        a4 += cvt4(hws + (size_t)s4 * HID + f);
        a5 += cvt4(hws + (size_t)s5 * HID + f);
        a6 += cvt4(hws + (size_t)s6 * HID + f);
        a7 += cvt4(hws + (size_t)s7 * HID + f);
    }
    for (; j + 4 <= j1; j += 4) {
        int s0 = csr[j + 0];
        int s1 = csr[j + 1];
        int s2 = csr[j + 2];
        int s3 = csr[j + 3];
        a1 += cvt4(hws + (size_t)s0 * HID + f);
        a2 += cvt4(hws + (size_t)s1 * HID + f);
        a3 += cvt4(hws + (size_t)s2 * HID + f);
        a4 += cvt4(hws + (size_t)s3 * HID + f);
    }
    for (; j < j1; ++j) {
        int s = csr[j];
        a5 += cvt4(hws + (size_t)s * HID + f);
    }
    f32x4 acc = ((a0 + a1) + (a2 + a3)) + ((a4 + a5) + (a6 + a7));

    f32x4 al4 = *(const f32x4*)(bnA + f);
    f32x4 p4  = *(const f32x4*)(bnP2 + f);
    f32x4 r4 = {0.0f, 0.0f, 0.0f, 0.0f};
    if (res) r4 = *(const f32x4*)(res + rowb);

    f32x4 o;
    f16x4 hv, lv;
#pragma unroll
    for (int jj = 0; jj < 4; ++jj) {
        float t = al4[jj] * (dn * acc[jj]) + p4[jj];
        t = fmaxf(t, 0.0f);
        t += r4[jj];
        o[jj] = t;
        _Float16 h = (_Float16)t;
        hv[jj] = h; lv[jj] = (_Float16)(t - (float)h);
    }
    if (hf) *(f32x4*)(hf + rowb) = o;
    *(f16x4*)&hh[rowb] = hv;
    *(f16x4*)&hl[rowb] = lv;
}

// ------------------------------------------------------------------
// Fused classifier: 32-row tile, h -> O1(LDS) -> O2(LDS) -> logits.
__global__ __launch_bounds__(256) void classifier(
    const _Float16* __restrict__ Ah, const _Float16* __restrict__ Al,
    const _Float16* __restrict__ c1w, const float* __restrict__ b1,
    const _Float16* __restrict__ c2w, const float* __restrict__ b2,
    const _Float16* __restrict__ c3w, const float* __restrict__ b3,
    float* __restrict__ out)
{
    __shared__ __align__(16) float sO1[32][132];
    __shared__ __align__(16) float sO2[32][68];

    const int tid = threadIdx.x, wid = tid >> 6, lane = tid & 63;
    const int fr = lane & 15, fq = lane >> 4;
    const int bm = blockIdx.x * 32;

    // ---- stage 1: O1 = relu(h @ c1^T + b1)   M=32 N=128 K=256
    {
        f32x4 acc[2][2] = {};
        size_t ra[2], rb[2];
#pragma unroll
        for (int mi = 0; mi < 2; ++mi) ra[mi] = (size_t)(bm + mi * 16 + fr) * 256 + fq * 8;
#pragma unroll
        for (int ni = 0; ni < 2; ++ni) rb[ni] = (size_t)(wid * 32 + ni * 16 + fr) * 256 + fq * 8;
#pragma unroll
        for (int kt = 0; kt < 8; ++kt) {
            f16x8 ah[2], al[2], bw[2];
#pragma unroll
            for (int mi = 0; mi < 2; ++mi) {
                ah[mi] = *(const f16x8*)(Ah + ra[mi] + kt * 32);
                al[mi] = *(const f16x8*)(Al + ra[mi] + kt * 32);
            }
#pragma unroll
            for (int ni = 0; ni < 2; ++ni)
                bw[ni] = *(const f16x8*)(c1w + rb[ni] + kt * 32);
#pragma unroll
            for (int mi = 0; mi < 2; ++mi)
#pragma unroll
                for (int ni = 0; ni < 2; ++ni) {
                    acc[mi][ni] = __builtin_amdgcn_mfma_f32_16x16x32_f16(ah[mi], bw[ni], acc[mi][ni], 0, 0, 0);
                    acc[mi][ni] = __builtin_amdgcn_mfma_f32_16x16x32_f16(al[mi], bw[ni], acc[mi][ni], 0, 0, 0);
                }
        }
#pragma unroll
        for (int mi = 0; mi < 2; ++mi)
#pragma unroll
            for (int ni = 0; ni < 2; ++ni) {
                int col = wid * 32 + ni * 16 + fr;
                float bb = b1[col];
#pragma unroll
                for (int r = 0; r < 4; ++r)
                    sO1[mi * 16 + fq * 4 + r][col] = fmaxf(acc[mi][ni][r] + bb, 0.0f);
            }
    }
    __syncthreads();

    // ---- stage 2: O2 = relu(O1 @ c2^T + b2)   M=32 N=64 K=128
    {
        f32x4 acc[2] = {};
#pragma unroll
        for (int kt = 0; kt < 4; ++kt) {
            f16x8 ah[2], al[2];
#pragma unroll
            for (int mi = 0; mi < 2; ++mi) {
                const float* p = &sO1[mi * 16 + fr][kt * 32 + fq * 8];
                f32x4 v0 = *(const f32x4*)p;
                f32x4 v1 = *(const f32x4*)(p + 4);
                float vv[8] = {v0[0], v0[1], v0[2], v0[3], v1[0], v1[1], v1[2], v1[3]};
#pragma unroll
                for (int j = 0; j < 8; ++j) {
                    _Float16 h = (_Float16)vv[j];
                    ah[mi][j] = h; al[mi][j] = (_Float16)(vv[j] - (float)h);
                }
            }
            size_t rb = (size_t)(wid * 16 + fr) * 128 + kt * 32 + fq * 8;
            f16x8 bw = *(const f16x8*)(c2w + rb);
#pragma unroll
            for (int mi = 0; mi < 2; ++mi) {
                acc[mi] = __builtin_amdgcn_mfma_f32_16x16x32_f16(ah[mi], bw, acc[mi], 0, 0, 0);
                acc[mi] = __builtin_amdgcn_mfma_f32_16x16x32_f16(al[mi], bw, acc[mi], 0, 0, 0);
            }
        }
        int col = wid * 16 + fr;
        float bb = b2[col];
#pragma unroll
        for (int mi = 0; mi < 2; ++mi)
#pragma unroll
            for (int r = 0; r < 4; ++r)
                sO2[mi * 16 + fq * 4 + r][col] = fmaxf(acc[mi][r] + bb, 0.0f);
    }
    __syncthreads();

    // ---- stage 3: logits = O2 @ c3^T + b3
    if (wid < 2) {
        f32x4 acc = {};
#pragma unroll
        for (int kt = 0; kt < 2; ++kt) {
            const float* p = &sO2[wid * 16 + fr][kt * 32 + fq * 8];
            f32x4 v0 = *(const f32x4*)p;
            f32x4 v1 = *(const f32x4*)(p + 4);
            float vv[8] = {v0[0], v0[1], v0[2], v0[3], v1[0], v1[1], v1[2], v1[3]};
            f16x8 ah, al;
#pragma unroll
            for (int j = 0; j < 8; ++j) {
                _Float16 h = (_Float16)vv[j];
                ah[j] = h; al[j] = (_Float16)(vv[j] - (float)h);
            }
            size_t rb = (size_t)fr * 64 + kt * 32 + fq * 8;
            f16x8 bw = *(const f16x8*)(c3w + rb);
            acc = __builtin_amdgcn_mfma_f32_16x16x32_f16(ah, bw, acc, 0, 0, 0);
            acc = __builtin_amdgcn_mfma_f32_16x16x32_f16(al, bw, acc, 0, 0, 0);
        }
        if (fr < 10) {
            float bb = b3[fr];
#pragma unroll
            for (int r = 0; r < 4; ++r) {
                int row = bm + wid * 16 + fq * 4 + r;
                if (row < NN) out[(size_t)row * 10 + fr] = acc[r] + bb;
            }
        }
    }
}

// ------------------------------------------------------------------
extern "C" void kernel_launch(void* const* d_in, const int* in_sizes, int n_in,
                              void* d_out, int out_size, void* d_ws, size_t ws_size,
                              hipStream_t stream)
{
    const float* x     = (const float*)d_in[0];
    const int*   eidx  = (const int*)d_in[1];
    const float* in_W  = (const float*)d_in[2];
    const float* in_b  = (const float*)d_in[3];
    const float* gcn_W = (const float*)d_in[4];
    const float* gcn_b = (const float*)d_in[5];
    const float* bn_g  = (const float*)d_in[6];
    const float* bn_be = (const float*)d_in[7];
    const float* bn_m  = (const float*)d_in[8];
    const float* bn_v  = (const float*)d_in[9];
    const float* c1_W  = (const float*)d_in[10];
    const float* c1_b  = (const float*)d_in[11];
    const float* c2_W  = (const float*)d_in[12];
    const float* c2_b  = (const float*)d_in[13];
    const float* c3_W  = (const float*)d_in[14];
    const float* c3_b  = (const float*)d_in[15];
    float* out = (float*)d_out;

    const int E = in_sizes[1] / 2;
    float* ws = (float*)d_ws;

    // ---- workspace layout ----
    // P: 8 fp16 slices of NPH = 4*NPH floats; dead after epi.
    // h1/h2 (residuals, written from layer 1 onwards) alias the P region.
    _Float16* P   = (_Float16*)ws;
    float*    h1  = ws;
    float*    h2  = ws + NPH;
    _Float16* hws = (_Float16*)(ws + 4 * NPH);  // NPH fp16 (gather table)
    _Float16* hh  = hws + NPH;
    _Float16* hl  = hh + NPH;
    _Float16* wi  = hl + NPH;         // 256x2048
    _Float16* gw  = wi + 524288;      // 768x256
    _Float16* c1w = gw + 196608;      // 128x256
    _Float16* c2w = c1w + 32768;      // 64x128
    _Float16* c3w = c2w + 8192;       // 16x64 (10 real rows)
    float*    bnA  = (float*)(c3w + 1024);      // 768
    float*    bnP2 = bnA + 768;                 // 768
    float*    dinv = bnP2 + 768;
    unsigned* cnt  = (unsigned*)(dinv + NN);
    unsigned* off  = cnt + NN;
    unsigned* cur  = off + NN + 1;
    unsigned* flag = cur + NN;
    int*      csr  = (int*)(flag + 4);

    // ---- graph prep + weight fp16 conversion + BN fold ----
    prep_split<<<3021, 256, 0, stream>>>(eidx, cnt, flag, in_W, gcn_W, c1_W, c2_W, c3_W,
                                         gcn_b, bn_g, bn_be, bn_m, bn_v,
                                         wi, gw, c1w, c2w, c3w, bnA, bnP2);
    count_edges<<<(E + 255) / 256, 256, 0, stream>>>(eidx, flag, cnt, E);
    scan_dinv<<<1, 1024, 0, stream>>>(cnt, off, cur, dinv, NN);
    fill_csr<<<(E + 255) / 256, 256, 0, stream>>>(eidx, flag, cur, csr, E);

    // ---- input projection ----
    inproj_gemm<<<dim3(NP / 64, 1, IPZ), 256, 0, stream>>>(x, wi, P);
    inproj_epi<<<(int)(NPH / 1024), 256, 0, stream>>>(P, in_b, hh, hl);

    // ---- 3 GCN layers ----
    for (int i = 0; i < 3; ++i) {
        gemm_layer<<<dim3(NP / 64, 4), 256, 0, stream>>>(
            hh, hl, gw + (size_t)i * 65536, dinv, hws);
        const float* res = (i == 0) ? nullptr : (i == 1 ? h1 : h2);
        float* hf = (i == 0) ? h1 : (i == 1 ? h2 : nullptr);
        gcn_aggregate<<<NN / 4, 256, 0, stream>>>(
            hws, res, dinv, off, csr,
            bnA + i * HID, bnP2 + i * HID, hf, hh, hl);
    }

    // ---- fused classifier ----
    classifier<<<NP / 32, 256, 0, stream>>>(hh, hl, c1w, c1_b,
                                            c2w, c2_b, c3w, c3_b, out);
}

// Round 17
// 222.207 us; speedup vs baseline: 1.9873x; 1.0838x over previous
//
#include <hip/hip_runtime.h>
#include <hip/hip_bf16.h>

#define NN   10000
#define NP   10048          // 157*64 padded rows
#define HID  256
#define BN_EPS 1e-5f
#define NPH  ((size_t)NP * 256)

typedef _Float16 f16x4 __attribute__((ext_vector_type(4)));
typedef _Float16 f16x8 __attribute__((ext_vector_type(8)));
typedef float    f32x4 __attribute__((ext_vector_type(4)));

__device__ __forceinline__ void gl_lds16(const void* gptr, void* lptr) {
    __builtin_amdgcn_global_load_lds(
        (const __attribute__((address_space(1))) void*)gptr,
        (__attribute__((address_space(3))) void*)lptr,
        16, 0, 0);
}

__device__ __forceinline__ f32x4 cvt4(const _Float16* p) {
    f16x4 t = *(const f16x4*)p;
    f32x4 r; r[0] = t[0]; r[1] = t[1]; r[2] = t[2]; r[3] = t[3];
    return r;
}

// ------------------------------------------------------------------
// Merged: cnt-zero + i64-layout detect (blocks 0..39), weight fp16
// conversion (blocks 40..3019), BN-fold precompute (block 3020).
__global__ void prep_split(const int* __restrict__ e, unsigned* __restrict__ cnt,
                           unsigned* __restrict__ flag,
                           const float* __restrict__ in_W, const float* __restrict__ gcn_W,
                           const float* __restrict__ c1_W, const float* __restrict__ c2_W,
                           const float* __restrict__ c3_W,
                           const float* __restrict__ gcn_b, const float* __restrict__ bn_g,
                           const float* __restrict__ bn_be, const float* __restrict__ bn_m,
                           const float* __restrict__ bn_v,
                           _Float16* __restrict__ wi, _Float16* __restrict__ gw,
                           _Float16* __restrict__ c1, _Float16* __restrict__ c2,
                           _Float16* __restrict__ c3,
                           float* __restrict__ bnA, float* __restrict__ bnP2) {
    if (blockIdx.x < 40) {
        int i = blockIdx.x * 256 + threadIdx.x;
        if (i < NN) cnt[i] = 0u;
        if (blockIdx.x == 0) {
            __shared__ int nz;
            if (threadIdx.x == 0) nz = 0;
            __syncthreads();
            if (e[2 * threadIdx.x + 1] != 0) nz = 1;
            __syncthreads();
            if (threadIdx.x == 0) *flag = (nz == 0) ? 1u : 0u;  // 1 => int64 layout
        }
        return;
    }
    if (blockIdx.x == 3020) {
#pragma unroll
        for (int it = 0; it < 3; ++it) {
            int idx = it * 256 + threadIdx.x;
            if (idx < 768) {
                float a = bn_g[idx] * rsqrtf(bn_v[idx] + BN_EPS);
                bnA[idx]  = a;
                bnP2[idx] = a * (gcn_b[idx] - bn_m[idx]) + bn_be[idx];
            }
        }
        return;
    }
    int idx = (blockIdx.x - 40) * 256 + threadIdx.x;
    float v; _Float16* d; int o;
    if (idx < 524288)      { v = in_W[idx];          d = wi; o = idx; }
    else if (idx < 720896) { o = idx - 524288; v = gcn_W[o]; d = gw; }
    else if (idx < 753664) { o = idx - 720896; v = c1_W[o];  d = c1; }
    else if (idx < 761856) { o = idx - 753664; v = c2_W[o];  d = c2; }
    else                   { o = idx - 761856; int r = o >> 6, c = o & 63;
                             v = (r < 10) ? c3_W[r * 64 + c] : 0.0f; d = c3; }
    d[o] = (_Float16)v;
}

__device__ __forceinline__ int edge_val(const int* e, unsigned f, long idx) {
    return f ? e[2 * idx] : e[idx];
}

__global__ void count_edges(const int* __restrict__ e, const unsigned* __restrict__ flag,
                            unsigned* __restrict__ cnt, int E) {
    int i = blockIdx.x * blockDim.x + threadIdx.x;
    if (i >= E) return;
    unsigned f = *flag;
    atomicAdd(&cnt[edge_val(e, f, (long)E + i)], 1u);
}

// single block, 1024 threads
__global__ void scan_dinv(const unsigned* __restrict__ cnt, unsigned* __restrict__ off,
                          unsigned* __restrict__ cur, float* __restrict__ dinv, int n) {
    __shared__ unsigned partial[1024];
    int t = threadIdx.x;
    int chunk = (n + 1023) / 1024;
    int lo = t * chunk;
    int hi = lo + chunk; if (hi > n) hi = n; if (lo > n) lo = n;
    unsigned s = 0;
    for (int i = lo; i < hi; ++i) s += cnt[i];
    partial[t] = s;
    __syncthreads();
    for (int d = 1; d < 1024; d <<= 1) {
        unsigned v = (t >= d) ? partial[t - d] : 0u;
        __syncthreads();
        partial[t] += v;
        __syncthreads();
    }
    unsigned base = (t == 0) ? 0u : partial[t - 1];
    for (int i = lo; i < hi; ++i) {
        off[i] = base; cur[i] = base;
        dinv[i] = rsqrtf((float)cnt[i] + 1.0f);
        base += cnt[i];
    }
    if (t == 1023) off[n] = base;
}

__global__ void fill_csr(const int* __restrict__ e, const unsigned* __restrict__ flag,
                         unsigned* __restrict__ cur, int* __restrict__ csr_src, int E) {
    int i = blockIdx.x * blockDim.x + threadIdx.x;
    if (i >= E) return;
    unsigned f = *flag;
    int src = edge_val(e, f, (long)i);
    int dst = edge_val(e, f, (long)E + i);
    unsigned pos = atomicAdd(&cur[dst], 1u);
    csr_src[pos] = src;
}

// ------------------------------------------------------------------
// Input projection: BM=64 x BN=256, split-K=8, 2-phase pipelined, dbuf LDS.
// A(x) single fp16 (activation-lo dropped; err ~5e-4 max, see analysis);
// B single fp16 plane via global_load_lds. 1 MFMA pass/frag.
// LDS 40 KB -> 4 blk/CU. Partials FP16.
#define IPZ 8
#define IPKC 256
__global__ __launch_bounds__(256) void inproj_gemm(
    const float* __restrict__ A,
    const _Float16* __restrict__ B,
    _Float16* __restrict__ P)
{
    __shared__ __align__(16) _Float16 sA[2][2048];
    __shared__ __align__(16) _Float16 sB[2][8192];

    const int tid = threadIdx.x, wid = tid >> 6, lane = tid & 63;
    const int fr = lane & 15, fq = lane >> 4;
    const int bm = blockIdx.x * 64;
    const int kbase = blockIdx.z * IPKC;
    const int wn = wid * 64;

    f32x4 acc[4][4] = {};

    const int rs = tid >> 2, cq = tid & 3;
    const int gr = min(bm + rs, NN - 1);
    const float* aptr = A + (size_t)gr * 2048 + cq * 8;
    const int scA = rs * 32 + ((cq ^ ((rs >> 1) & 3)) << 3);
    const int brow_l = lane >> 2, bch = lane & 3;

    float av[8];
    int cur = 0;

    {   // prologue: stage tile 0
        float4 v0 = *(const float4*)(aptr + kbase);
        float4 v1 = *(const float4*)(aptr + kbase + 4);
        av[0]=v0.x; av[1]=v0.y; av[2]=v0.z; av[3]=v0.w;
        av[4]=v1.x; av[5]=v1.y; av[6]=v1.z; av[7]=v1.w;
#pragma unroll
        for (int j = 0; j < 4; ++j) {
            int slice = wid * 4 + j;
            int row = slice * 16 + brow_l;
            int lc = bch ^ ((row >> 1) & 3);
            gl_lds16(B + (size_t)row * 2048 + kbase + lc * 8, &sB[0][slice * 512]);
        }
        f16x8 hv;
#pragma unroll
        for (int j = 0; j < 8; ++j) hv[j] = (_Float16)av[j];
        *(f16x8*)&sA[0][scA] = hv;
    }
    __syncthreads();

    for (int kt = 0; kt < IPKC / 32; ++kt) {
        const bool more = (kt + 1) < IPKC / 32;
        const int nk = kbase + (kt + 1) * 32;
        if (more) {
            float4 v0 = *(const float4*)(aptr + nk);
            float4 v1 = *(const float4*)(aptr + nk + 4);
            av[0]=v0.x; av[1]=v0.y; av[2]=v0.z; av[3]=v0.w;
            av[4]=v1.x; av[5]=v1.y; av[6]=v1.z; av[7]=v1.w;
#pragma unroll
            for (int j = 0; j < 4; ++j) {
                int slice = wid * 4 + j;
                int row = slice * 16 + brow_l;
                int lc = bch ^ ((row >> 1) & 3);
                gl_lds16(B + (size_t)row * 2048 + nk + lc * 8, &sB[cur ^ 1][slice * 512]);
            }
        }
        f16x8 b[4];
#pragma unroll
        for (int ni = 0; ni < 4; ++ni) {
            int r = wn + ni * 16 + fr;
            b[ni] = *(const f16x8*)&sB[cur][r * 32 + ((fq ^ ((r >> 1) & 3)) << 3)];
        }
#pragma unroll
        for (int mi = 0; mi < 4; ++mi) {
            int r = mi * 16 + fr;
            f16x8 a = *(const f16x8*)&sA[cur][r * 32 + ((fq ^ ((r >> 1) & 3)) << 3)];
#pragma unroll
            for (int ni = 0; ni < 4; ++ni)
                acc[mi][ni] = __builtin_amdgcn_mfma_f32_16x16x32_f16(a, b[ni], acc[mi][ni], 0, 0, 0);
        }
        if (more) {
            f16x8 hv;
#pragma unroll
            for (int j = 0; j < 8; ++j) hv[j] = (_Float16)av[j];
            *(f16x8*)&sA[cur ^ 1][scA] = hv;
        }
        __syncthreads();
        cur ^= 1;
    }

    _Float16* Pz = P + (size_t)blockIdx.z * NPH;
#pragma unroll
    for (int mi = 0; mi < 4; ++mi) {
        int row0 = bm + mi * 16 + fq * 4;
#pragma unroll
        for (int ni = 0; ni < 4; ++ni) {
            int col = wn + ni * 16 + fr;
#pragma unroll
            for (int r = 0; r < 4; ++r)
                Pz[(size_t)(row0 + r) * 256 + col] = (_Float16)acc[mi][ni][r];
        }
    }
}

// reduce 8 fp16 partials + bias + relu -> single fp16 plane (zero pad rows)
__global__ void inproj_epi(const _Float16* __restrict__ P, const float* __restrict__ b,
                           _Float16* __restrict__ hh) {
    int t = blockIdx.x * 256 + threadIdx.x;
    size_t idx = (size_t)t * 4;
    int row = (int)(idx >> 8), col = (int)(idx & 255);
    float v[4] = {0, 0, 0, 0};
    if (row < NN) {
        f32x4 a0 = cvt4(P + idx)           + cvt4(P + idx + NPH);
        f32x4 a1 = cvt4(P + idx + 2 * NPH) + cvt4(P + idx + 3 * NPH);
        f32x4 a2 = cvt4(P + idx + 4 * NPH) + cvt4(P + idx + 5 * NPH);
        f32x4 a3 = cvt4(P + idx + 6 * NPH) + cvt4(P + idx + 7 * NPH);
        f32x4 bb = *(const f32x4*)(b + col);
#pragma unroll
        for (int j = 0; j < 4; ++j)
            v[j] = fmaxf((a0[j] + a1[j]) + (a2[j] + a3[j]) + bb[j], 0.0f);
    }
    f16x4 hv;
#pragma unroll
    for (int j = 0; j < 4; ++j) hv[j] = (_Float16)v[j];
    *(f16x4*)&hh[idx] = hv;
}

// ------------------------------------------------------------------
// Layer GEMM (K=256): no LDS, per-lane direct fragment loads.
// A = h single fp16, B = single fp16 weight plane; 1 pass.
// Epilogue pre-scales by dinv[row] and emits hws as FP16.
__global__ __launch_bounds__(256) void gemm_layer(
    const _Float16* __restrict__ Ah,
    const _Float16* __restrict__ Bw,
    const float* __restrict__ dinv, _Float16* __restrict__ Cw)
{
    const int tid = threadIdx.x, wid = tid >> 6, lane = tid & 63;
    const int fr = lane & 15, fq = lane >> 4;
    const int wr = wid >> 1, wc = wid & 1;
    const int bm = blockIdx.x * 64, bn = blockIdx.y * 64;

    f32x4 acc[2][2] = {};
    size_t ra[2], rb[2];
#pragma unroll
    for (int mi = 0; mi < 2; ++mi) ra[mi] = (size_t)(bm + wr * 32 + mi * 16 + fr) * 256 + fq * 8;
#pragma unroll
    for (int ni = 0; ni < 2; ++ni) rb[ni] = (size_t)(bn + wc * 32 + ni * 16 + fr) * 256 + fq * 8;

#pragma unroll
    for (int kt = 0; kt < 8; ++kt) {
        f16x8 ah[2], bw[2];
#pragma unroll
        for (int mi = 0; mi < 2; ++mi)
            ah[mi] = *(const f16x8*)(Ah + ra[mi] + kt * 32);
#pragma unroll
        for (int ni = 0; ni < 2; ++ni)
            bw[ni] = *(const f16x8*)(Bw + rb[ni] + kt * 32);
#pragma unroll
        for (int mi = 0; mi < 2; ++mi)
#pragma unroll
            for (int ni = 0; ni < 2; ++ni)
                acc[mi][ni] = __builtin_amdgcn_mfma_f32_16x16x32_f16(ah[mi], bw[ni], acc[mi][ni], 0, 0, 0);
    }

    float dv[2][4];
#pragma unroll
    for (int mi = 0; mi < 2; ++mi)
#pragma unroll
        for (int r = 0; r < 4; ++r) {
            int row = bm + wr * 32 + mi * 16 + fq * 4 + r;
            dv[mi][r] = (row < NN) ? dinv[row] : 0.0f;
        }

#pragma unroll
    for (int mi = 0; mi < 2; ++mi)
#pragma unroll
        for (int ni = 0; ni < 2; ++ni) {
            int col = bn + wc * 32 + ni * 16 + fr;
#pragma unroll
            for (int r = 0; r < 4; ++r) {
                int row = bm + wr * 32 + mi * 16 + fq * 4 + r;
                if (row < NN)
                    Cw[(size_t)row * 256 + col] = (_Float16)(acc[mi][ni][r] * dv[mi][r]);
            }
        }
}

// ------------------------------------------------------------------
// GCN aggregate v6 + folded BN: full-row, wave-per-node.
//   out = relu(bnA*(dn*acc) + bnP2) (+ res); emits single fp16 plane.
__global__ __launch_bounds__(256) void gcn_aggregate(
    const _Float16* __restrict__ hws, const float* __restrict__ res,
    const float* __restrict__ dinv, const unsigned* __restrict__ off,
    const int* __restrict__ csr,
    const float* __restrict__ bnA, const float* __restrict__ bnP2,
    float* __restrict__ hf, _Float16* __restrict__ hh)
{
    const int wid = threadIdx.x >> 6, l = threadIdx.x & 63;
    const int node = blockIdx.x * 4 + wid;            // grid = 2500 blocks
    const int f = l << 2;                             // 0..252
    const size_t rowb = (size_t)node * HID + f;

    const float dn = dinv[node];
    const unsigned j0 = off[node], j1 = off[node + 1];

    f32x4 a0 = cvt4(hws + rowb);                      // self term (pre-scaled)
    f32x4 a1 = {0.f,0.f,0.f,0.f}, a2 = {0.f,0.f,0.f,0.f}, a3 = {0.f,0.f,0.f,0.f};
    f32x4 a4 = {0.f,0.f,0.f,0.f}, a5 = {0.f,0.f,0.f,0.f};
    f32x4 a6 = {0.f,0.f,0.f,0.f}, a7 = {0.f,0.f,0.f,0.f};

    unsigned j = j0;
    for (; j + 8 <= j1; j += 8) {
        int s0 = csr[j + 0];
        int s1 = csr[j + 1];
        int s2 = csr[j + 2];
        int s3 = csr[j + 3];
        int s4 = csr[j + 4];
        int s5 = csr[j + 5];
        int s6 = csr[j + 6];
        int s7 = csr[j + 7];
        a0 += cvt4(hws + (size_t)s0 * HID + f);
        a1 += cvt4(hws + (size_t)s1 * HID + f);
        a2 += cvt4(hws + (size_t)s2 * HID + f);
        a3 += cvt4(hws + (size_t)s3 * HID + f);
        a4 += cvt4(hws + (size_t)s4 * HID + f);
        a5 += cvt4(hws + (size_t)s5 * HID + f);
        a6 += cvt4(hws + (size_t)s6 * HID + f);
        a7 += cvt4(hws + (size_t)s7 * HID + f);
    }
    for (; j + 4 <= j1; j += 4) {
        int s0 = csr[j + 0];
        int s1 = csr[j + 1];
        int s2 = csr[j + 2];
        int s3 = csr[j + 3];
        a1 += cvt4(hws + (size_t)s0 * HID + f);
        a2 += cvt4(hws + (size_t)s1 * HID + f);
        a3 += cvt4(hws + (size_t)s2 * HID + f);
        a4 += cvt4(hws + (size_t)s3 * HID + f);
    }
    for (; j < j1; ++j) {
        int s = csr[j];
        a5 += cvt4(hws + (size_t)s * HID + f);
    }
    f32x4 acc = ((a0 + a1) + (a2 + a3)) + ((a4 + a5) + (a6 + a7));

    f32x4 al4 = *(const f32x4*)(bnA + f);
    f32x4 p4  = *(const f32x4*)(bnP2 + f);
    f32x4 r4 = {0.0f, 0.0f, 0.0f, 0.0f};
    if (res) r4 = *(const f32x4*)(res + rowb);

    f32x4 o;
    f16x4 hv;
#pragma unroll
    for (int jj = 0; jj < 4; ++jj) {
        float t = al4[jj] * (dn * acc[jj]) + p4[jj];
        t = fmaxf(t, 0.0f);
        t += r4[jj];
        o[jj] = t;
        hv[jj] = (_Float16)t;
    }
    if (hf) *(f32x4*)(hf + rowb) = o;
    *(f16x4*)&hh[rowb] = hv;
}

// ------------------------------------------------------------------
// Fused classifier: 32-row tile, h -> O1(LDS) -> O2(LDS) -> logits.
// Single-fp16 activations throughout; 1 MFMA pass per fragment.
__global__ __launch_bounds__(256) void classifier(
    const _Float16* __restrict__ Ah,
    const _Float16* __restrict__ c1w, const float* __restrict__ b1,
    const _Float16* __restrict__ c2w, const float* __restrict__ b2,
    const _Float16* __restrict__ c3w, const float* __restrict__ b3,
    float* __restrict__ out)
{
    __shared__ __align__(16) float sO1[32][132];
    __shared__ __align__(16) float sO2[32][68];

    const int tid = threadIdx.x, wid = tid >> 6, lane = tid & 63;
    const int fr = lane & 15, fq = lane >> 4;
    const int bm = blockIdx.x * 32;

    // ---- stage 1: O1 = relu(h @ c1^T + b1)   M=32 N=128 K=256
    {
        f32x4 acc[2][2] = {};
        size_t ra[2], rb[2];
#pragma unroll
        for (int mi = 0; mi < 2; ++mi) ra[mi] = (size_t)(bm + mi * 16 + fr) * 256 + fq * 8;
#pragma unroll
        for (int ni = 0; ni < 2; ++ni) rb[ni] = (size_t)(wid * 32 + ni * 16 + fr) * 256 + fq * 8;
#pragma unroll
        for (int kt = 0; kt < 8; ++kt) {
            f16x8 ah[2], bw[2];
#pragma unroll
            for (int mi = 0; mi < 2; ++mi)
                ah[mi] = *(const f16x8*)(Ah + ra[mi] + kt * 32);
#pragma unroll
            for (int ni = 0; ni < 2; ++ni)
                bw[ni] = *(const f16x8*)(c1w + rb[ni] + kt * 32);
#pragma unroll
            for (int mi = 0; mi < 2; ++mi)
#pragma unroll
                for (int ni = 0; ni < 2; ++ni)
                    acc[mi][ni] = __builtin_amdgcn_mfma_f32_16x16x32_f16(ah[mi], bw[ni], acc[mi][ni], 0, 0, 0);
        }
#pragma unroll
        for (int mi = 0; mi < 2; ++mi)
#pragma unroll
            for (int ni = 0; ni < 2; ++ni) {
                int col = wid * 32 + ni * 16 + fr;
                float bb = b1[col];
#pragma unroll
                for (int r = 0; r < 4; ++r)
                    sO1[mi * 16 + fq * 4 + r][col] = fmaxf(acc[mi][ni][r] + bb, 0.0f);
            }
    }
    __syncthreads();

    // ---- stage 2: O2 = relu(O1 @ c2^T + b2)   M=32 N=64 K=128
    {
        f32x4 acc[2] = {};
#pragma unroll
        for (int kt = 0; kt < 4; ++kt) {
            f16x8 ah[2];
#pragma unroll
            for (int mi = 0; mi < 2; ++mi) {
                const float* p = &sO1[mi * 16 + fr][kt * 32 + fq * 8];
                f32x4 v0 = *(const f32x4*)p;
                f32x4 v1 = *(const f32x4*)(p + 4);
#pragma unroll
                for (int j = 0; j < 4; ++j) {
                    ah[mi][j]     = (_Float16)v0[j];
                    ah[mi][j + 4] = (_Float16)v1[j];
                }
            }
            size_t rb = (size_t)(wid * 16 + fr) * 128 + kt * 32 + fq * 8;
            f16x8 bw = *(const f16x8*)(c2w + rb);
#pragma unroll
            for (int mi = 0; mi < 2; ++mi)
                acc[mi] = __builtin_amdgcn_mfma_f32_16x16x32_f16(ah[mi], bw, acc[mi], 0, 0, 0);
        }
        int col = wid * 16 + fr;
        float bb = b2[col];
#pragma unroll
        for (int mi = 0; mi < 2; ++mi)
#pragma unroll
            for (int r = 0; r < 4; ++r)
                sO2[mi * 16 + fq * 4 + r][col] = fmaxf(acc[mi][r] + bb, 0.0f);
    }
    __syncthreads();

    // ---- stage 3: logits = O2 @ c3^T + b3
    if (wid < 2) {
        f32x4 acc = {};
#pragma unroll
        for (int kt = 0; kt < 2; ++kt) {
            const float* p = &sO2[wid * 16 + fr][kt * 32 + fq * 8];
            f32x4 v0 = *(const f32x4*)p;
            f32x4 v1 = *(const f32x4*)(p + 4);
            f16x8 ah;
#pragma unroll
            for (int j = 0; j < 4; ++j) {
                ah[j]     = (_Float16)v0[j];
                ah[j + 4] = (_Float16)v1[j];
            }
            size_t rb = (size_t)fr * 64 + kt * 32 + fq * 8;
            f16x8 bw = *(const f16x8*)(c3w + rb);
            acc = __builtin_amdgcn_mfma_f32_16x16x32_f16(ah, bw, acc, 0, 0, 0);
        }
        if (fr < 10) {
            float bb = b3[fr];
#pragma unroll
            for (int r = 0; r < 4; ++r) {
                int row = bm + wid * 16 + fq * 4 + r;
                if (row < NN) out[(size_t)row * 10 + fr] = acc[r] + bb;
            }
        }
    }
}

// ------------------------------------------------------------------
extern "C" void kernel_launch(void* const* d_in, const int* in_sizes, int n_in,
                              void* d_out, int out_size, void* d_ws, size_t ws_size,
                              hipStream_t stream)
{
    const float* x     = (const float*)d_in[0];
    const int*   eidx  = (const int*)d_in[1];
    const float* in_W  = (const float*)d_in[2];
    const float* in_b  = (const float*)d_in[3];
    const float* gcn_W = (const float*)d_in[4];
    const float* gcn_b = (const float*)d_in[5];
    const float* bn_g  = (const float*)d_in[6];
    const float* bn_be = (const float*)d_in[7];
    const float* bn_m  = (const float*)d_in[8];
    const float* bn_v  = (const float*)d_in[9];
    const float* c1_W  = (const float*)d_in[10];
    const float* c1_b  = (const float*)d_in[11];
    const float* c2_W  = (const float*)d_in[12];
    const float* c2_b  = (const float*)d_in[13];
    const float* c3_W  = (const float*)d_in[14];
    const float* c3_b  = (const float*)d_in[15];
    float* out = (float*)d_out;

    const int E = in_sizes[1] / 2;
    float* ws = (float*)d_ws;

    // ---- workspace layout ----
    // P: 8 fp16 slices of NPH = 4*NPH floats; dead after epi.
    // h1/h2 (residuals, written from layer 1 onwards) alias the P region.
    _Float16* P   = (_Float16*)ws;
    float*    h1  = ws;
    float*    h2  = ws + NPH;
    _Float16* hws = (_Float16*)(ws + 4 * NPH);  // NPH fp16 (gather table)
    _Float16* hh  = hws + NPH;
    _Float16* wi  = hh + NPH;         // 256x2048
    _Float16* gw  = wi + 524288;      // 768x256
    _Float16* c1w = gw + 196608;      // 128x256
    _Float16* c2w = c1w + 32768;      // 64x128
    _Float16* c3w = c2w + 8192;       // 16x64 (10 real rows)
    float*    bnA  = (float*)(c3w + 1024);      // 768
    float*    bnP2 = bnA + 768;                 // 768
    float*    dinv = bnP2 + 768;
    unsigned* cnt  = (unsigned*)(dinv + NN);
    unsigned* off  = cnt + NN;
    unsigned* cur  = off + NN + 1;
    unsigned* flag = cur + NN;
    int*      csr  = (int*)(flag + 4);

    // ---- graph prep + weight fp16 conversion + BN fold ----
    prep_split<<<3021, 256, 0, stream>>>(eidx, cnt, flag, in_W, gcn_W, c1_W, c2_W, c3_W,
                                         gcn_b, bn_g, bn_be, bn_m, bn_v,
                                         wi, gw, c1w, c2w, c3w, bnA, bnP2);
    count_edges<<<(E + 255) / 256, 256, 0, stream>>>(eidx, flag, cnt, E);
    scan_dinv<<<1, 1024, 0, stream>>>(cnt, off, cur, dinv, NN);
    fill_csr<<<(E + 255) / 256, 256, 0, stream>>>(eidx, flag, cur, csr, E);

    // ---- input projection ----
    inproj_gemm<<<dim3(NP / 64, 1, IPZ), 256, 0, stream>>>(x, wi, P);
    inproj_epi<<<(int)(NPH / 1024), 256, 0, stream>>>(P, in_b, hh);

    // ---- 3 GCN layers ----
    for (int i = 0; i < 3; ++i) {
        gemm_layer<<<dim3(NP / 64, 4), 256, 0, stream>>>(
            hh, gw + (size_t)i * 65536, dinv, hws);
        const float* res = (i == 0) ? nullptr : (i == 1 ? h1 : h2);
        float* hf = (i == 0) ? h1 : (i == 1 ? h2 : nullptr);
        gcn_aggregate<<<NN / 4, 256, 0, stream>>>(
            hws, res, dinv, off, csr,
            bnA + i * HID, bnP2 + i * HID, hf, hh);
    }

    // ---- fused classifier ----
    classifier<<<NP / 32, 256, 0, stream>>>(hh, c1w, c1_b,
                                            c2w, c2_b, c3w, c3_b, out);
}

// Round 18
// 217.985 us; speedup vs baseline: 2.0258x; 1.0194x over previous
//
#include <hip/hip_runtime.h>
#include <hip/hip_bf16.h>

#define NN   10000
#define NP   10048          // 157*64 padded rows
#define HID  256
#define BN_EPS 1e-5f
#define NPH  ((size_t)NP * 256)

typedef _Float16 f16x4 __attribute__((ext_vector_type(4)));
typedef _Float16 f16x8 __attribute__((ext_vector_type(8)));
typedef float    f32x4 __attribute__((ext_vector_type(4)));

__device__ __forceinline__ void gl_lds16(const void* gptr, void* lptr) {
    __builtin_amdgcn_global_load_lds(
        (const __attribute__((address_space(1))) void*)gptr,
        (__attribute__((address_space(3))) void*)lptr,
        16, 0, 0);
}

__device__ __forceinline__ f32x4 cvt4(const _Float16* p) {
    f16x4 t = *(const f16x4*)p;
    f32x4 r; r[0] = t[0]; r[1] = t[1]; r[2] = t[2]; r[3] = t[3];
    return r;
}

// 8-wide fp16 load -> two f32x4
__device__ __forceinline__ void cvt8(const _Float16* p, f32x4& lo, f32x4& hi) {
    f16x8 t = *(const f16x8*)p;
    lo[0] = t[0]; lo[1] = t[1]; lo[2] = t[2]; lo[3] = t[3];
    hi[0] = t[4]; hi[1] = t[5]; hi[2] = t[6]; hi[3] = t[7];
}

// ------------------------------------------------------------------
// Merged: cnt-zero + i64-layout detect (blocks 0..39), weight fp16
// conversion (blocks 40..3019), BN-fold precompute (block 3020).
__global__ void prep_split(const int* __restrict__ e, unsigned* __restrict__ cnt,
                           unsigned* __restrict__ flag,
                           const float* __restrict__ in_W, const float* __restrict__ gcn_W,
                           const float* __restrict__ c1_W, const float* __restrict__ c2_W,
                           const float* __restrict__ c3_W,
                           const float* __restrict__ gcn_b, const float* __restrict__ bn_g,
                           const float* __restrict__ bn_be, const float* __restrict__ bn_m,
                           const float* __restrict__ bn_v,
                           _Float16* __restrict__ wi, _Float16* __restrict__ gw,
                           _Float16* __restrict__ c1, _Float16* __restrict__ c2,
                           _Float16* __restrict__ c3,
                           float* __restrict__ bnA, float* __restrict__ bnP2) {
    if (blockIdx.x < 40) {
        int i = blockIdx.x * 256 + threadIdx.x;
        if (i < NN) cnt[i] = 0u;
        if (blockIdx.x == 0) {
            __shared__ int nz;
            if (threadIdx.x == 0) nz = 0;
            __syncthreads();
            if (e[2 * threadIdx.x + 1] != 0) nz = 1;
            __syncthreads();
            if (threadIdx.x == 0) *flag = (nz == 0) ? 1u : 0u;  // 1 => int64 layout
        }
        return;
    }
    if (blockIdx.x == 3020) {
#pragma unroll
        for (int it = 0; it < 3; ++it) {
            int idx = it * 256 + threadIdx.x;
            if (idx < 768) {
                float a = bn_g[idx] * rsqrtf(bn_v[idx] + BN_EPS);
                bnA[idx]  = a;
                bnP2[idx] = a * (gcn_b[idx] - bn_m[idx]) + bn_be[idx];
            }
        }
        return;
    }
    int idx = (blockIdx.x - 40) * 256 + threadIdx.x;
    float v; _Float16* d; int o;
    if (idx < 524288)      { v = in_W[idx];          d = wi; o = idx; }
    else if (idx < 720896) { o = idx - 524288; v = gcn_W[o]; d = gw; }
    else if (idx < 753664) { o = idx - 720896; v = c1_W[o];  d = c1; }
    else if (idx < 761856) { o = idx - 753664; v = c2_W[o];  d = c2; }
    else                   { o = idx - 761856; int r = o >> 6, c = o & 63;
                             v = (r < 10) ? c3_W[r * 64 + c] : 0.0f; d = c3; }
    d[o] = (_Float16)v;
}

__device__ __forceinline__ int edge_val(const int* e, unsigned f, long idx) {
    return f ? e[2 * idx] : e[idx];
}

__global__ void count_edges(const int* __restrict__ e, const unsigned* __restrict__ flag,
                            unsigned* __restrict__ cnt, int E) {
    int i = blockIdx.x * blockDim.x + threadIdx.x;
    if (i >= E) return;
    unsigned f = *flag;
    atomicAdd(&cnt[edge_val(e, f, (long)E + i)], 1u);
}

// single block, 1024 threads
__global__ void scan_dinv(const unsigned* __restrict__ cnt, unsigned* __restrict__ off,
                          unsigned* __restrict__ cur, float* __restrict__ dinv, int n) {
    __shared__ unsigned partial[1024];
    int t = threadIdx.x;
    int chunk = (n + 1023) / 1024;
    int lo = t * chunk;
    int hi = lo + chunk; if (hi > n) hi = n; if (lo > n) lo = n;
    unsigned s = 0;
    for (int i = lo; i < hi; ++i) s += cnt[i];
    partial[t] = s;
    __syncthreads();
    for (int d = 1; d < 1024; d <<= 1) {
        unsigned v = (t >= d) ? partial[t - d] : 0u;
        __syncthreads();
        partial[t] += v;
        __syncthreads();
    }
    unsigned base = (t == 0) ? 0u : partial[t - 1];
    for (int i = lo; i < hi; ++i) {
        off[i] = base; cur[i] = base;
        dinv[i] = rsqrtf((float)cnt[i] + 1.0f);
        base += cnt[i];
    }
    if (t == 1023) off[n] = base;
}

__global__ void fill_csr(const int* __restrict__ e, const unsigned* __restrict__ flag,
                         unsigned* __restrict__ cur, int* __restrict__ csr_src, int E) {
    int i = blockIdx.x * blockDim.x + threadIdx.x;
    if (i >= E) return;
    unsigned f = *flag;
    int src = edge_val(e, f, (long)i);
    int dst = edge_val(e, f, (long)E + i);
    unsigned pos = atomicAdd(&cur[dst], 1u);
    csr_src[pos] = src;
}

// ------------------------------------------------------------------
// Input projection: BM=64 x BN=256, split-K=8, 2-phase pipelined, dbuf LDS.
// A(x) single fp16; B single fp16 plane via global_load_lds. 1 MFMA
// pass/frag. LDS 40 KB. Partials FP16.
#define IPZ 8
#define IPKC 256
__global__ __launch_bounds__(256) void inproj_gemm(
    const float* __restrict__ A,
    const _Float16* __restrict__ B,
    _Float16* __restrict__ P)
{
    __shared__ __align__(16) _Float16 sA[2][2048];
    __shared__ __align__(16) _Float16 sB[2][8192];

    const int tid = threadIdx.x, wid = tid >> 6, lane = tid & 63;
    const int fr = lane & 15, fq = lane >> 4;
    const int bm = blockIdx.x * 64;
    const int kbase = blockIdx.z * IPKC;
    const int wn = wid * 64;

    f32x4 acc[4][4] = {};

    const int rs = tid >> 2, cq = tid & 3;
    const int gr = min(bm + rs, NN - 1);
    const float* aptr = A + (size_t)gr * 2048 + cq * 8;
    const int scA = rs * 32 + ((cq ^ ((rs >> 1) & 3)) << 3);
    const int brow_l = lane >> 2, bch = lane & 3;

    float av[8];
    int cur = 0;

    {   // prologue: stage tile 0
        float4 v0 = *(const float4*)(aptr + kbase);
        float4 v1 = *(const float4*)(aptr + kbase + 4);
        av[0]=v0.x; av[1]=v0.y; av[2]=v0.z; av[3]=v0.w;
        av[4]=v1.x; av[5]=v1.y; av[6]=v1.z; av[7]=v1.w;
#pragma unroll
        for (int j = 0; j < 4; ++j) {
            int slice = wid * 4 + j;
            int row = slice * 16 + brow_l;
            int lc = bch ^ ((row >> 1) & 3);
            gl_lds16(B + (size_t)row * 2048 + kbase + lc * 8, &sB[0][slice * 512]);
        }
        f16x8 hv;
#pragma unroll
        for (int j = 0; j < 8; ++j) hv[j] = (_Float16)av[j];
        *(f16x8*)&sA[0][scA] = hv;
    }
    __syncthreads();

    for (int kt = 0; kt < IPKC / 32; ++kt) {
        const bool more = (kt + 1) < IPKC / 32;
        const int nk = kbase + (kt + 1) * 32;
        if (more) {
            float4 v0 = *(const float4*)(aptr + nk);
            float4 v1 = *(const float4*)(aptr + nk + 4);
            av[0]=v0.x; av[1]=v0.y; av[2]=v0.z; av[3]=v0.w;
            av[4]=v1.x; av[5]=v1.y; av[6]=v1.z; av[7]=v1.w;
#pragma unroll
            for (int j = 0; j < 4; ++j) {
                int slice = wid * 4 + j;
                int row = slice * 16 + brow_l;
                int lc = bch ^ ((row >> 1) & 3);
                gl_lds16(B + (size_t)row * 2048 + nk + lc * 8, &sB[cur ^ 1][slice * 512]);
            }
        }
        f16x8 b[4];
#pragma unroll
        for (int ni = 0; ni < 4; ++ni) {
            int r = wn + ni * 16 + fr;
            b[ni] = *(const f16x8*)&sB[cur][r * 32 + ((fq ^ ((r >> 1) & 3)) << 3)];
        }
#pragma unroll
        for (int mi = 0; mi < 4; ++mi) {
            int r = mi * 16 + fr;
            f16x8 a = *(const f16x8*)&sA[cur][r * 32 + ((fq ^ ((r >> 1) & 3)) << 3)];
#pragma unroll
            for (int ni = 0; ni < 4; ++ni)
                acc[mi][ni] = __builtin_amdgcn_mfma_f32_16x16x32_f16(a, b[ni], acc[mi][ni], 0, 0, 0);
        }
        if (more) {
            f16x8 hv;
#pragma unroll
            for (int j = 0; j < 8; ++j) hv[j] = (_Float16)av[j];
            *(f16x8*)&sA[cur ^ 1][scA] = hv;
        }
        __syncthreads();
        cur ^= 1;
    }

    _Float16* Pz = P + (size_t)blockIdx.z * NPH;
#pragma unroll
    for (int mi = 0; mi < 4; ++mi) {
        int row0 = bm + mi * 16 + fq * 4;
#pragma unroll
        for (int ni = 0; ni < 4; ++ni) {
            int col = wn + ni * 16 + fr;
#pragma unroll
            for (int r = 0; r < 4; ++r)
                Pz[(size_t)(row0 + r) * 256 + col] = (_Float16)acc[mi][ni][r];
        }
    }
}

// reduce 8 fp16 partials + bias + relu -> single fp16 plane (zero pad rows)
__global__ void inproj_epi(const _Float16* __restrict__ P, const float* __restrict__ b,
                           _Float16* __restrict__ hh) {
    int t = blockIdx.x * 256 + threadIdx.x;
    size_t idx = (size_t)t * 4;
    int row = (int)(idx >> 8), col = (int)(idx & 255);
    float v[4] = {0, 0, 0, 0};
    if (row < NN) {
        f32x4 a0 = cvt4(P + idx)           + cvt4(P + idx + NPH);
        f32x4 a1 = cvt4(P + idx + 2 * NPH) + cvt4(P + idx + 3 * NPH);
        f32x4 a2 = cvt4(P + idx + 4 * NPH) + cvt4(P + idx + 5 * NPH);
        f32x4 a3 = cvt4(P + idx + 6 * NPH) + cvt4(P + idx + 7 * NPH);
        f32x4 bb = *(const f32x4*)(b + col);
#pragma unroll
        for (int j = 0; j < 4; ++j)
            v[j] = fmaxf((a0[j] + a1[j]) + (a2[j] + a3[j]) + bb[j], 0.0f);
    }
    f16x4 hv;
#pragma unroll
    for (int j = 0; j < 4; ++j) hv[j] = (_Float16)v[j];
    *(f16x4*)&hh[idx] = hv;
}

// ------------------------------------------------------------------
// Layer GEMM (K=256): no LDS, per-lane direct fragment loads.
// A = h single fp16, B = single fp16 weight plane; 1 pass.
// Epilogue pre-scales by dinv[row] and emits hws as FP16.
__global__ __launch_bounds__(256) void gemm_layer(
    const _Float16* __restrict__ Ah,
    const _Float16* __restrict__ Bw,
    const float* __restrict__ dinv, _Float16* __restrict__ Cw)
{
    const int tid = threadIdx.x, wid = tid >> 6, lane = tid & 63;
    const int fr = lane & 15, fq = lane >> 4;
    const int wr = wid >> 1, wc = wid & 1;
    const int bm = blockIdx.x * 64, bn = blockIdx.y * 64;

    f32x4 acc[2][2] = {};
    size_t ra[2], rb[2];
#pragma unroll
    for (int mi = 0; mi < 2; ++mi) ra[mi] = (size_t)(bm + wr * 32 + mi * 16 + fr) * 256 + fq * 8;
#pragma unroll
    for (int ni = 0; ni < 2; ++ni) rb[ni] = (size_t)(bn + wc * 32 + ni * 16 + fr) * 256 + fq * 8;

#pragma unroll
    for (int kt = 0; kt < 8; ++kt) {
        f16x8 ah[2], bw[2];
#pragma unroll
        for (int mi = 0; mi < 2; ++mi)
            ah[mi] = *(const f16x8*)(Ah + ra[mi] + kt * 32);
#pragma unroll
        for (int ni = 0; ni < 2; ++ni)
            bw[ni] = *(const f16x8*)(Bw + rb[ni] + kt * 32);
#pragma unroll
        for (int mi = 0; mi < 2; ++mi)
#pragma unroll
            for (int ni = 0; ni < 2; ++ni)
                acc[mi][ni] = __builtin_amdgcn_mfma_f32_16x16x32_f16(ah[mi], bw[ni], acc[mi][ni], 0, 0, 0);
    }

    float dv[2][4];
#pragma unroll
    for (int mi = 0; mi < 2; ++mi)
#pragma unroll
        for (int r = 0; r < 4; ++r) {
            int row = bm + wr * 32 + mi * 16 + fq * 4 + r;
            dv[mi][r] = (row < NN) ? dinv[row] : 0.0f;
        }

#pragma unroll
    for (int mi = 0; mi < 2; ++mi)
#pragma unroll
        for (int ni = 0; ni < 2; ++ni) {
            int col = bn + wc * 32 + ni * 16 + fr;
#pragma unroll
            for (int r = 0; r < 4; ++r) {
                int row = bm + wr * 32 + mi * 16 + fq * 4 + r;
                if (row < NN)
                    Cw[(size_t)row * 256 + col] = (_Float16)(acc[mi][ni][r] * dv[mi][r]);
            }
        }
}

// ------------------------------------------------------------------
// GCN aggregate v7: wave-per-node, TWO edges in flight per iteration.
// Wave splits into two 32-lane halves; each half gathers a different edge's
// full 512B row (32 lanes x f16x8 = 16B/lane). Dependent loop length halves;
// halves recombined at the end via shfl_xor(32) (same feature range).
//   out = relu(bnA*(dn*acc) + bnP2) (+ res); emits single fp16 plane.
__global__ __launch_bounds__(256) void gcn_aggregate(
    const _Float16* __restrict__ hws, const float* __restrict__ res,
    const float* __restrict__ dinv, const unsigned* __restrict__ off,
    const int* __restrict__ csr,
    const float* __restrict__ bnA, const float* __restrict__ bnP2,
    float* __restrict__ hf, _Float16* __restrict__ hh)
{
    const int wid = threadIdx.x >> 6, l = threadIdx.x & 63;
    const int node = blockIdx.x * 4 + wid;            // grid = 2500 blocks
    const int half = l >> 5;                          // 0 or 1
    const int q = l & 31;                             // lane-in-half
    const int f = q << 3;                             // feature base 0..248 (8 feats)
    const size_t rowf = (size_t)node * HID + f;

    const float dn = dinv[node];
    const unsigned j0 = off[node], j1 = off[node + 1];
    const unsigned deg = j1 - j0;

    // 8 independent accumulator pairs (lo/hi f32x4) = 4 per half after fold
    f32x4 a0l = {0,0,0,0}, a0h = {0,0,0,0}, a1l = {0,0,0,0}, a1h = {0,0,0,0};
    f32x4 a2l = {0,0,0,0}, a2h = {0,0,0,0}, a3l = {0,0,0,0}, a3h = {0,0,0,0};

    if (half == 0) {   // self term in half 0
        f32x4 lo, hi; cvt8(hws + rowf, lo, hi);
        a0l += lo; a0h += hi;
    }

    // each half walks edges of parity `half`: indices j0+half, +2, +4, ...
    unsigned i = (unsigned)half;
    for (; i + 8 <= deg; i += 8) {     // 4 edges per half per iter (stride 2)
        int s0 = csr[j0 + i];
        int s1 = csr[j0 + i + 2];
        int s2 = csr[j0 + i + 4];
        int s3 = csr[j0 + i + 6];
        f32x4 lo, hi;
        cvt8(hws + (size_t)s0 * HID + f, lo, hi); a0l += lo; a0h += hi;
        cvt8(hws + (size_t)s1 * HID + f, lo, hi); a1l += lo; a1h += hi;
        cvt8(hws + (size_t)s2 * HID + f, lo, hi); a2l += lo; a2h += hi;
        cvt8(hws + (size_t)s3 * HID + f, lo, hi); a3l += lo; a3h += hi;
    }
    for (; i < deg; i += 2) {
        int s = csr[j0 + i];
        f32x4 lo, hi;
        cvt8(hws + (size_t)s * HID + f, lo, hi); a1l += lo; a1h += hi;
    }

    f32x4 accl = (a0l + a1l) + (a2l + a3l);
    f32x4 acch = (a0h + a1h) + (a2h + a3h);

    // combine halves: partner lane l^32 holds same feature range
#pragma unroll
    for (int j = 0; j < 4; ++j) {
        accl[j] += __shfl_xor((float)accl[j], 32);
        acch[j] += __shfl_xor((float)acch[j], 32);
    }
    if (half) return;   // half 1 done (no writes)

    f32x4 alL = *(const f32x4*)(bnA + f);
    f32x4 alH = *(const f32x4*)(bnA + f + 4);
    f32x4 p4L = *(const f32x4*)(bnP2 + f);
    f32x4 p4H = *(const f32x4*)(bnP2 + f + 4);
    f32x4 rL = {0,0,0,0}, rH = {0,0,0,0};
    if (res) {
        rL = *(const f32x4*)(res + rowf);
        rH = *(const f32x4*)(res + rowf + 4);
    }

    f32x4 oL, oH;
    f16x8 hv;
#pragma unroll
    for (int j = 0; j < 4; ++j) {
        float t = alL[j] * (dn * accl[j]) + p4L[j];
        t = fmaxf(t, 0.0f) + rL[j];
        oL[j] = t; hv[j] = (_Float16)t;
        float u = alH[j] * (dn * acch[j]) + p4H[j];
        u = fmaxf(u, 0.0f) + rH[j];
        oH[j] = u; hv[j + 4] = (_Float16)u;
    }
    if (hf) {
        *(f32x4*)(hf + rowf)     = oL;
        *(f32x4*)(hf + rowf + 4) = oH;
    }
    *(f16x8*)&hh[rowf] = hv;
}

// ------------------------------------------------------------------
// Fused classifier: 32-row tile, h -> O1(LDS) -> O2(LDS) -> logits.
__global__ __launch_bounds__(256) void classifier(
    const _Float16* __restrict__ Ah,
    const _Float16* __restrict__ c1w, const float* __restrict__ b1,
    const _Float16* __restrict__ c2w, const float* __restrict__ b2,
    const _Float16* __restrict__ c3w, const float* __restrict__ b3,
    float* __restrict__ out)
{
    __shared__ __align__(16) float sO1[32][132];
    __shared__ __align__(16) float sO2[32][68];

    const int tid = threadIdx.x, wid = tid >> 6, lane = tid & 63;
    const int fr = lane & 15, fq = lane >> 4;
    const int bm = blockIdx.x * 32;

    // ---- stage 1: O1 = relu(h @ c1^T + b1)   M=32 N=128 K=256
    {
        f32x4 acc[2][2] = {};
        size_t ra[2], rb[2];
#pragma unroll
        for (int mi = 0; mi < 2; ++mi) ra[mi] = (size_t)(bm + mi * 16 + fr) * 256 + fq * 8;
#pragma unroll
        for (int ni = 0; ni < 2; ++ni) rb[ni] = (size_t)(wid * 32 + ni * 16 + fr) * 256 + fq * 8;
#pragma unroll
        for (int kt = 0; kt < 8; ++kt) {
            f16x8 ah[2], bw[2];
#pragma unroll
            for (int mi = 0; mi < 2; ++mi)
                ah[mi] = *(const f16x8*)(Ah + ra[mi] + kt * 32);
#pragma unroll
            for (int ni = 0; ni < 2; ++ni)
                bw[ni] = *(const f16x8*)(c1w + rb[ni] + kt * 32);
#pragma unroll
            for (int mi = 0; mi < 2; ++mi)
#pragma unroll
                for (int ni = 0; ni < 2; ++ni)
                    acc[mi][ni] = __builtin_amdgcn_mfma_f32_16x16x32_f16(ah[mi], bw[ni], acc[mi][ni], 0, 0, 0);
        }
#pragma unroll
        for (int mi = 0; mi < 2; ++mi)
#pragma unroll
            for (int ni = 0; ni < 2; ++ni) {
                int col = wid * 32 + ni * 16 + fr;
                float bb = b1[col];
#pragma unroll
                for (int r = 0; r < 4; ++r)
                    sO1[mi * 16 + fq * 4 + r][col] = fmaxf(acc[mi][ni][r] + bb, 0.0f);
            }
    }
    __syncthreads();

    // ---- stage 2: O2 = relu(O1 @ c2^T + b2)   M=32 N=64 K=128
    {
        f32x4 acc[2] = {};
#pragma unroll
        for (int kt = 0; kt < 4; ++kt) {
            f16x8 ah[2];
#pragma unroll
            for (int mi = 0; mi < 2; ++mi) {
                const float* p = &sO1[mi * 16 + fr][kt * 32 + fq * 8];
                f32x4 v0 = *(const f32x4*)p;
                f32x4 v1 = *(const f32x4*)(p + 4);
#pragma unroll
                for (int j = 0; j < 4; ++j) {
                    ah[mi][j]     = (_Float16)v0[j];
                    ah[mi][j + 4] = (_Float16)v1[j];
                }
            }
            size_t rb = (size_t)(wid * 16 + fr) * 128 + kt * 32 + fq * 8;
            f16x8 bw = *(const f16x8*)(c2w + rb);
#pragma unroll
            for (int mi = 0; mi < 2; ++mi)
                acc[mi] = __builtin_amdgcn_mfma_f32_16x16x32_f16(ah[mi], bw, acc[mi], 0, 0, 0);
        }
        int col = wid * 16 + fr;
        float bb = b2[col];
#pragma unroll
        for (int mi = 0; mi < 2; ++mi)
#pragma unroll
            for (int r = 0; r < 4; ++r)
                sO2[mi * 16 + fq * 4 + r][col] = fmaxf(acc[mi][r] + bb, 0.0f);
    }
    __syncthreads();

    // ---- stage 3: logits = O2 @ c3^T + b3
    if (wid < 2) {
        f32x4 acc = {};
#pragma unroll
        for (int kt = 0; kt < 2; ++kt) {
            const float* p = &sO2[wid * 16 + fr][kt * 32 + fq * 8];
            f32x4 v0 = *(const f32x4*)p;
            f32x4 v1 = *(const f32x4*)(p + 4);
            f16x8 ah;
#pragma unroll
            for (int j = 0; j < 4; ++j) {
                ah[j]     = (_Float16)v0[j];
                ah[j + 4] = (_Float16)v1[j];
            }
            size_t rb = (size_t)fr * 64 + kt * 32 + fq * 8;
            f16x8 bw = *(const f16x8*)(c3w + rb);
            acc = __builtin_amdgcn_mfma_f32_16x16x32_f16(ah, bw, acc, 0, 0, 0);
        }
        if (fr < 10) {
            float bb = b3[fr];
#pragma unroll
            for (int r = 0; r < 4; ++r) {
                int row = bm + wid * 16 + fq * 4 + r;
                if (row < NN) out[(size_t)row * 10 + fr] = acc[r] + bb;
            }
        }
    }
}

// ------------------------------------------------------------------
extern "C" void kernel_launch(void* const* d_in, const int* in_sizes, int n_in,
                              void* d_out, int out_size, void* d_ws, size_t ws_size,
                              hipStream_t stream)
{
    const float* x     = (const float*)d_in[0];
    const int*   eidx  = (const int*)d_in[1];
    const float* in_W  = (const float*)d_in[2];
    const float* in_b  = (const float*)d_in[3];
    const float* gcn_W = (const float*)d_in[4];
    const float* gcn_b = (const float*)d_in[5];
    const float* bn_g  = (const float*)d_in[6];
    const float* bn_be = (const float*)d_in[7];
    const float* bn_m  = (const float*)d_in[8];
    const float* bn_v  = (const float*)d_in[9];
    const float* c1_W  = (const float*)d_in[10];
    const float* c1_b  = (const float*)d_in[11];
    const float* c2_W  = (const float*)d_in[12];
    const float* c2_b  = (const float*)d_in[13];
    const float* c3_W  = (const float*)d_in[14];
    const float* c3_b  = (const float*)d_in[15];
    float* out = (float*)d_out;

    const int E = in_sizes[1] / 2;
    float* ws = (float*)d_ws;

    // ---- workspace layout ----
    _Float16* P   = (_Float16*)ws;              // 8 fp16 slices; dead after epi
    float*    h1  = ws;                         // residual 1 (aliases P)
    float*    h2  = ws + NPH;                   // residual 2 (aliases P)
    _Float16* hws = (_Float16*)(ws + 4 * NPH);  // NPH fp16 (gather table)
    _Float16* hh  = hws + NPH;
    _Float16* wi  = hh + NPH;         // 256x2048
    _Float16* gw  = wi + 524288;      // 768x256
    _Float16* c1w = gw + 196608;      // 128x256
    _Float16* c2w = c1w + 32768;      // 64x128
    _Float16* c3w = c2w + 8192;       // 16x64 (10 real rows)
    float*    bnA  = (float*)(c3w + 1024);      // 768
    float*    bnP2 = bnA + 768;                 // 768
    float*    dinv = bnP2 + 768;
    unsigned* cnt  = (unsigned*)(dinv + NN);
    unsigned* off  = cnt + NN;
    unsigned* cur  = off + NN + 1;
    unsigned* flag = cur + NN;
    int*      csr  = (int*)(flag + 4);

    // ---- graph prep + weight fp16 conversion + BN fold ----
    prep_split<<<3021, 256, 0, stream>>>(eidx, cnt, flag, in_W, gcn_W, c1_W, c2_W, c3_W,
                                         gcn_b, bn_g, bn_be, bn_m, bn_v,
                                         wi, gw, c1w, c2w, c3w, bnA, bnP2);
    count_edges<<<(E + 255) / 256, 256, 0, stream>>>(eidx, flag, cnt, E);
    scan_dinv<<<1, 1024, 0, stream>>>(cnt, off, cur, dinv, NN);
    fill_csr<<<(E + 255) / 256, 256, 0, stream>>>(eidx, flag, cur, csr, E);

    // ---- input projection ----
    inproj_gemm<<<dim3(NP / 64, 1, IPZ), 256, 0, stream>>>(x, wi, P);
    inproj_epi<<<(int)(NPH / 1024), 256, 0, stream>>>(P, in_b, hh);

    // ---- 3 GCN layers ----
    for (int i = 0; i < 3; ++i) {
        gemm_layer<<<dim3(NP / 64, 4), 256, 0, stream>>>(
            hh, gw + (size_t)i * 65536, dinv, hws);
        const float* res = (i == 0) ? nullptr : (i == 1 ? h1 : h2);
        float* hf = (i == 0) ? h1 : (i == 1 ? h2 : nullptr);
        gcn_aggregate<<<NN / 4, 256, 0, stream>>>(
            hws, res, dinv, off, csr,
            bnA + i * HID, bnP2 + i * HID, hf, hh);
    }

    // ---- fused classifier ----
    classifier<<<NP / 32, 256, 0, stream>>>(hh, c1w, c1_b,
                                            c2w, c2_b, c3w, c3_b, out);
}